// Round 7
// baseline (588.898 us; speedup 1.0000x reference)
//
#include <hip/hip_runtime.h>
#include <math.h>

#define BB 64
#define LATENT 256
#define ACTD 6
#define HIDD 512
#define DST 16

typedef __attribute__((ext_vector_type(8))) short bf16x8;
typedef __attribute__((ext_vector_type(4))) float f32x4;

static __device__ __forceinline__ ushort f2bf(float f) {
  unsigned u = __builtin_bit_cast(unsigned, f);
  unsigned r = (u + 0x7FFFu + ((u >> 16) & 1u)) >> 16;
  return (ushort)r;
}
static __device__ __forceinline__ float bf2f(ushort u) {
  return __builtin_bit_cast(float, ((unsigned)u) << 16);
}

// ---------------- output offsets (floats) ----------------
#define O_PRED   0
#define O_ZT     4194304
#define O_STATE  4210688
#define O_MUP    4734976
#define O_LVP    4751360
#define O_MUPO   4767744
#define O_LVPO   4784128

// ---------------- ws offsets (floats), lifetime-reused ----------------
#define W_SSMIN  0u
#define W_DELTA  32768u
#define W_BT     65536u
#define W_CT     66560u
#define W_BELIEF 67584u
#define W_CNN    100352u
#define W_ZB16   133120u      // 8192 u16
#define PW_C2    137216u      // 32768 u16
#define PW_C3    153600u      // 131072 u16
#define PW_C4    219136u      // 524288 u16
#define PW_D1    481280u      // 131072 u16
#define PW_D2    546816u      // 32768 u16
#define PW_D3    563200u      // 8192 u16
#define W_TIMG   602112u      // timg bf16, region reserved to 13185024
#define W_H1B    13185024u    // 33,554,432 u16 [dead after conv2]
#define W_H2B    29962240u    // 16,777,216 u16
#define W_H3B    38350848u    // 8,388,608 u16
#define W_H4B    42545152u    // 4,194,304 u16
// reuse (regions dead by write time):
#define W_ENCP   602112u      // 4,194,304 f   (TIMG region, dead after conv1)
#define W_DECO   8990720u     // 1,048,576 f   (TIMG region)
#define W_D1O    10039296u    // 2,097,152 f   (TIMG region)
#define W_D2O    13185024u    // 4,194,304 f   (H1B)
#define W_D3O    17379328u    // 8,388,608 f   (H1B)

#define ENC_KS 128

// ================= SSM / small dense =================

__global__ void k_ssm_in(const float* __restrict__ z_prev, const float* __restrict__ act,
                         const float* __restrict__ w, const float* __restrict__ bias,
                         float* __restrict__ out) {
  int id = blockIdx.x * blockDim.x + threadIdx.x;
  int b = id >> 9, h = id & 511;
  const float* wr = w + (size_t)h * (LATENT + ACTD);
  const float* zr = z_prev + (size_t)b * LATENT;
  float acc = bias[h];
  #pragma unroll 4
  for (int k = 0; k < LATENT; ++k) acc += zr[k] * wr[k];
  const float* ar = act + (size_t)b * ACTD;
  #pragma unroll
  for (int k = 0; k < ACTD; ++k) acc += ar[k] * wr[LATENT + k];
  out[id] = acc / (1.f + expf(-acc));
}

__global__ void k_delta(const float* __restrict__ ssm_in, const float* __restrict__ w,
                        const float* __restrict__ bias, float* __restrict__ out) {
  int id = blockIdx.x * blockDim.x + threadIdx.x;
  int b = id >> 9, h = id & 511;
  const float* xr = ssm_in + (size_t)b * HIDD;
  const float* wr = w + (size_t)h * HIDD;
  float acc = bias[h];
  #pragma unroll 4
  for (int k = 0; k < HIDD; ++k) acc += xr[k] * wr[k];
  out[id] = fmaxf(acc, 0.f) + log1pf(expf(-fabsf(acc)));
}

__global__ void k_bc(const float* __restrict__ ssm_in, const float* __restrict__ Bw,
                     const float* __restrict__ Cw, float* __restrict__ Bt,
                     float* __restrict__ Ct) {
  int id = blockIdx.x * blockDim.x + threadIdx.x;
  if (id >= BB * DST) return;
  int b = id >> 4, n = id & 15;
  const float* xr = ssm_in + (size_t)b * HIDD;
  const float* br = Bw + (size_t)n * HIDD;
  const float* cr = Cw + (size_t)n * HIDD;
  float ab = 0.f, ac = 0.f;
  #pragma unroll 4
  for (int k = 0; k < HIDD; ++k) { ab += xr[k] * br[k]; ac += xr[k] * cr[k]; }
  Bt[id] = ab; Ct[id] = ac;
}

__global__ void k_state(const float* __restrict__ Delta, const float* __restrict__ ssm_in,
                        const float* __restrict__ A_log, const float* __restrict__ Bt,
                        const float* __restrict__ Ct, const float* __restrict__ Dv,
                        const float* __restrict__ prev, float* __restrict__ state_out,
                        float* __restrict__ belief) {
  int id = blockIdx.x * blockDim.x + threadIdx.x;
  int b = id >> 9, h = id & 511;
  float d = Delta[id], si = ssm_in[id];
  float bel = Dv[h] * si;
  const float* al = A_log + (size_t)h * DST;
  const float* bt = Bt + (size_t)b * DST;
  const float* ct = Ct + (size_t)b * DST;
  const float* sp = prev + (size_t)id * DST;
  float* so = state_out + (size_t)id * DST;
  #pragma unroll
  for (int n = 0; n < DST; ++n) {
    float A = -expf(al[n]);
    float st = expf(d * A) * sp[n] + d * bt[n] * si;
    so[n] = st;
    bel += st * ct[n];
  }
  belief[id] = bel;
}

__global__ void k_prior(const float* __restrict__ belief, const float* __restrict__ w,
                        const float* __restrict__ bias, float* __restrict__ out) {
  int id = blockIdx.x * blockDim.x + threadIdx.x;
  int b = id >> 9, j = id & 511;
  const float* xr = belief + (size_t)b * HIDD;
  const float* wr = w + (size_t)j * HIDD;
  float acc = bias[j];
  #pragma unroll 4
  for (int k = 0; k < HIDD; ++k) acc += xr[k] * wr[k];
  if (j < 256) out[O_MUP + b * 256 + j] = acc;
  else         out[O_LVP + b * 256 + (j - 256)] = acc;
}

// ================= merged weight prepack (fragment order) =================

static __device__ __forceinline__ void pack_conv_elem(const float* __restrict__ w,
                                                      ushort* __restrict__ o,
                                                      int Cout, int Cin, int id) {
  int NCH = Cin / 2;
  int per = NCH * 512;
  int mt = id / per, r = id % per;
  int kcg = r >> 9, s = r & 511;
  int kg = s >> 7, m = (s >> 3) & 15, k8 = s & 7;
  int co = mt * 16 + m;
  int k = kcg * 32 + kg * 8 + k8;
  int tap = k / Cin, ci = k % Cin;
  o[id] = f2bf(w[(size_t)(co * Cin + ci) * 16 + tap]);
}

static __device__ __forceinline__ void pack_deconv_elem(const float* __restrict__ w,
                                                        ushort* __restrict__ o,
                                                        int Cout, int Cin, int id) {
  int NCH = Cin / 8;
  int perM = NCH * 512;
  int perC = (Cout / 16) * perM;
  int cls = id / perC, r = id % perC;
  int mt = r / perM, r2 = r % perM;
  int kcg = r2 >> 9, s = r2 & 511;
  int kg = s >> 7, m = (s >> 3) & 15, k8 = s & 7;
  int co = mt * 16 + m;
  int k = kcg * 32 + kg * 8 + k8;
  int t = k / Cin, ci = k % Cin;
  int p = (cls >> 1) + 2 * (t >> 1);
  int q = (cls & 1) + 2 * (t & 1);
  o[id] = f2bf(w[(size_t)(ci * Cout + co) * 16 + p * 4 + q]);
}

__global__ __launch_bounds__(256) void k_pack_all(
    const float* __restrict__ c2w, const float* __restrict__ c3w,
    const float* __restrict__ c4w, const float* __restrict__ d1w,
    const float* __restrict__ d2w, const float* __restrict__ d3w,
    ushort* __restrict__ pc2, ushort* __restrict__ pc3, ushort* __restrict__ pc4,
    ushort* __restrict__ pd1, ushort* __restrict__ pd2, ushort* __restrict__ pd3) {
  int id = blockIdx.x * 256 + threadIdx.x;
  if (id < 32768)            pack_conv_elem(c2w, pc2, 64, 32, id);
  else if (id < 163840)      pack_conv_elem(c3w, pc3, 128, 64, id - 32768);
  else if (id < 688128)      pack_conv_elem(c4w, pc4, 256, 128, id - 163840);
  else if (id < 819200)      pack_deconv_elem(d1w, pd1, 64, 128, id - 688128);
  else if (id < 851968)      pack_deconv_elem(d2w, pd2, 32, 64, id - 819200);
  else if (id < 860160)      pack_deconv_elem(d3w, pd3, 16, 32, id - 851968);
}

// ================= img transpose (bf16 out) =================
__global__ __launch_bounds__(256) void k_timg(const float* __restrict__ img,
                                              ushort* __restrict__ timg) {
  int blk = blockIdx.x;
  int c = blk >> 10, p0 = (blk & 1023) << 6;
  __shared__ float t[64 * 65];
  int tid = threadIdx.x;
  #pragma unroll
  for (int i = 0; i < 16; ++i) {
    int idx = tid + i * 256;
    int b = idx >> 6, pr = idx & 63;
    t[pr * 65 + b] = img[((size_t)b * 3 + c) * 65536 + p0 + pr];
  }
  __syncthreads();
  #pragma unroll
  for (int i = 0; i < 16; ++i) {
    int idx = tid + i * 256;
    int pr = idx >> 6, b = idx & 63;
    timg[((size_t)c * 65536 + p0 + pr) * 64 + b] = f2bf(t[pr * 65 + b]);
  }
}

// ================= conv1: direct (Cin=3), bf16 in, frag-order bf16 out =================
__global__ __launch_bounds__(256) void k_conv1(const ushort* __restrict__ in,
                                               const float* __restrict__ w,
                                               const float* __restrict__ bias,
                                               ushort* __restrict__ out) {
  int wid = __builtin_amdgcn_readfirstlane(blockIdx.x * 4 + (threadIdx.x >> 6));
  int lane = threadIdx.x & 63;
  int x4 = wid & 31; int t = wid >> 5;
  int oy = t & 127; int cg = t >> 7;      // cg 0..3
  int co0 = cg * 8;
  int ox0 = x4 << 2;
  int ixb = ox0 * 2 - 1;
  float acc[8][4];
  #pragma unroll
  for (int u = 0; u < 8; ++u) {
    float bv = bias[co0 + u];
    #pragma unroll
    for (int j = 0; j < 4; ++j) acc[u][j] = bv;
  }
  for (int ci = 0; ci < 3; ++ci) {
    const ushort* ip = in + ((size_t)ci * 65536) * 64 + lane;
    const float* wp = w + (size_t)co0 * 48 + ci * 16;
    #pragma unroll
    for (int ky = 0; ky < 4; ++ky) {
      int iy = oy * 2 - 1 + ky;
      if ((unsigned)iy >= 256u) continue;
      const ushort* rp = ip + (size_t)iy * 256 * 64;
      float x[10];
      #pragma unroll
      for (int j = 0; j < 10; ++j) {
        int ix = ixb + j;
        x[j] = ((unsigned)ix < 256u) ? bf2f(rp[(size_t)ix * 64]) : 0.f;
      }
      #pragma unroll
      for (int u = 0; u < 8; ++u) {
        const float* wq = wp + (size_t)u * 48 + ky * 4;
        float w0 = wq[0], w1 = wq[1], w2 = wq[2], w3 = wq[3];
        acc[u][0] += x[0]*w0 + x[1]*w1 + x[2]*w2 + x[3]*w3;
        acc[u][1] += x[2]*w0 + x[3]*w1 + x[4]*w2 + x[5]*w3;
        acc[u][2] += x[4]*w0 + x[5]*w1 + x[6]*w2 + x[7]*w3;
        acc[u][3] += x[6]*w0 + x[7]*w1 + x[8]*w2 + x[9]*w3;
      }
    }
  }
  #pragma unroll
  for (int j = 0; j < 4; ++j) {
    int px = oy * 128 + ox0 + j;
    size_t off = (size_t)px * 2048 + (size_t)(lane >> 4) * 512 + cg * 128 + (lane & 15) * 8;
    ushort tmp[8];
    #pragma unroll
    for (int u = 0; u < 8; ++u) tmp[u] = f2bf(fmaxf(acc[u][j], 0.f));
    uint4 pk;
    pk.x = tmp[0] | ((unsigned)tmp[1] << 16);
    pk.y = tmp[2] | ((unsigned)tmp[3] << 16);
    pk.z = tmp[4] | ((unsigned)tmp[5] << 16);
    pk.w = tmp[6] | ((unsigned)tmp[7] << 16);
    *(uint4*)(out + off) = pk;
  }
}

// ================= MFMA conv, PX=2 output pixels per wave, A-frag cached =================
// in frag-order [Hin*Win px][CIN*64]; wp [COUT/16][16*NKC][512]; out frag-order
template<int CIN, int COUT>
__global__ __launch_bounds__(256) void mfma_conv2(const ushort* __restrict__ in,
                                                  const ushort* __restrict__ wp,
                                                  const float* __restrict__ bias,
                                                  ushort* __restrict__ out,
                                                  int Hin, int Win, int Hout, int Wout) {
  constexpr int NMG = COUT / 16;
  constexpr int NKC = CIN / 32;
  constexpr int NCH = 16 * NKC;
  int wid = __builtin_amdgcn_readfirstlane(blockIdx.x * 4 + (threadIdx.x >> 6));
  int lane = threadIdx.x & 63;
  int mg = wid % NMG;
  int pairIdx = wid / NMG;
  int wp2 = Wout >> 1;
  int txp = pairIdx % wp2, oy = pairIdx / wp2;
  if (oy >= Hout) return;
  int ox0 = txp << 1;
  f32x4 zero = {0.f, 0.f, 0.f, 0.f};
  f32x4 acc[2][4];
  #pragma unroll
  for (int p = 0; p < 2; ++p)
    #pragma unroll
    for (int nt = 0; nt < 4; ++nt) acc[p][nt] = zero;
  const ushort* wb = wp + (size_t)mg * NCH * 512 + lane * 8;

  for (int kc = 0; kc < NKC; ++kc) {
    bf16x8 a[16];
    #pragma unroll
    for (int t = 0; t < 16; ++t)
      a[t] = *(const bf16x8*)(wb + (size_t)(t * NKC + kc) * 512);
    #pragma unroll
    for (int ky = 0; ky < 4; ++ky) {
      int iy = 2 * oy - 1 + ky;
      if ((unsigned)iy >= (unsigned)Hin) continue;
      const ushort* rowb = in + (size_t)iy * Win * (CIN * 64) + kc * 2048 + lane * 8;
      #pragma unroll
      for (int c = 0; c < 6; ++c) {
        int ix = 2 * ox0 - 1 + c;
        if ((unsigned)ix >= (unsigned)Win) continue;
        const ushort* ib = rowb + (size_t)ix * (CIN * 64);
        bf16x8 bb[4];
        #pragma unroll
        for (int nt = 0; nt < 4; ++nt)
          bb[nt] = *(const bf16x8*)(ib + nt * 512);
        if (c <= 3) {
          #pragma unroll
          for (int nt = 0; nt < 4; ++nt)
            acc[0][nt] = __builtin_amdgcn_mfma_f32_16x16x32_bf16(a[ky*4+c], bb[nt], acc[0][nt], 0, 0, 0);
        }
        if (c >= 2) {
          #pragma unroll
          for (int nt = 0; nt < 4; ++nt)
            acc[1][nt] = __builtin_amdgcn_mfma_f32_16x16x32_bf16(a[ky*4+c-2], bb[nt], acc[1][nt], 0, 0, 0);
        }
      }
    }
  }
  int ml = lane & 15, rb = (lane >> 4) * 4;
  int co = mg * 16 + rb;
  f32x4 bv = *(const f32x4*)(bias + co);
  #pragma unroll
  for (int p = 0; p < 2; ++p) {
    int px = oy * Wout + ox0 + p;
    #pragma unroll
    for (int nt = 0; nt < 4; ++nt) {
      float v0 = fmaxf(acc[p][nt][0] + bv[0], 0.f);
      float v1 = fmaxf(acc[p][nt][1] + bv[1], 0.f);
      float v2 = fmaxf(acc[p][nt][2] + bv[2], 0.f);
      float v3 = fmaxf(acc[p][nt][3] + bv[3], 0.f);
      uint2 pk;
      pk.x = (unsigned)f2bf(v0) | ((unsigned)f2bf(v1) << 16);
      pk.y = (unsigned)f2bf(v2) | ((unsigned)f2bf(v3) << 16);
      size_t off = (size_t)px * (COUT * 64) + (size_t)(co >> 5) * 2048 + nt * 512
                 + ((co >> 3) & 3) * 128 + ml * 8 + (co & 7);
      *(uint2*)(out + off) = pk;
    }
  }
}

// ================= MFMA transposed conv, PX=2, A-frag cached =================
template<int CIN, int COUT, bool RELU>
__global__ __launch_bounds__(256) void mfma_deconv2(const ushort* __restrict__ in,
                                                    const ushort* __restrict__ wp,
                                                    const float* __restrict__ bias,
                                                    ushort* __restrict__ out,
                                                    int Hin, int Win, int Hout, int Wout) {
  constexpr int NMG = COUT / 16;
  constexpr int NKC = CIN / 32;
  constexpr int NCH = 4 * NKC;
  constexpr int NTS = (COUT >= 32) ? 512 : (COUT * 16);
  int wid = __builtin_amdgcn_readfirstlane(blockIdx.x * 4 + (threadIdx.x >> 6));
  int lane = threadIdx.x & 63;
  int mg = wid % NMG; int r1 = wid / NMG;
  int wq = Wout >> 2;                  // tx-pairs per row in cls space
  int ppc = (Hout >> 1) * wq;          // pairs per cls
  int pairc = r1 % ppc; int cls = r1 / ppc;
  if (cls >= 4) return;
  int p0 = cls >> 1, q0 = cls & 1;
  int txp = pairc % wq, ty = pairc / wq;
  int tx = txp << 1;
  int oy = 2 * ty + 1 - p0;
  int ox = 2 * tx + 1 - q0;            // px0; px1 has ox+2
  int iy0 = ty + 1 - p0;
  int ix0 = tx + 1 - q0;
  f32x4 zero = {0.f, 0.f, 0.f, 0.f};
  f32x4 acc[2][4];
  #pragma unroll
  for (int p = 0; p < 2; ++p)
    #pragma unroll
    for (int nt = 0; nt < 4; ++nt) acc[p][nt] = zero;
  const ushort* wb = wp + ((size_t)cls * NMG + mg) * NCH * 512 + lane * 8;

  for (int kc = 0; kc < NKC; ++kc) {
    bf16x8 a[4];
    #pragma unroll
    for (int t = 0; t < 4; ++t)
      a[t] = *(const bf16x8*)(wb + (size_t)(t * NKC + kc) * 512);
    #pragma unroll
    for (int i = 0; i < 2; ++i) {
      int iy = iy0 - i;
      if ((unsigned)iy >= (unsigned)Hin) continue;
      const ushort* rowb = in + (size_t)iy * Win * (CIN * 64) + kc * 2048 + lane * 8;
      #pragma unroll
      for (int c = -1; c <= 1; ++c) {
        int ix = ix0 + c;
        if ((unsigned)ix >= (unsigned)Win) continue;
        const ushort* ib = rowb + (size_t)ix * (CIN * 64);
        bf16x8 bb[4];
        #pragma unroll
        for (int nt = 0; nt < 4; ++nt)
          bb[nt] = *(const bf16x8*)(ib + nt * 512);
        if (c <= 0) {
          int t = i * 2 - c;          // j = -c
          #pragma unroll
          for (int nt = 0; nt < 4; ++nt)
            acc[0][nt] = __builtin_amdgcn_mfma_f32_16x16x32_bf16(a[t], bb[nt], acc[0][nt], 0, 0, 0);
        }
        if (c >= 0) {
          int t = i * 2 + 1 - c;      // j = 1-c
          #pragma unroll
          for (int nt = 0; nt < 4; ++nt)
            acc[1][nt] = __builtin_amdgcn_mfma_f32_16x16x32_bf16(a[t], bb[nt], acc[1][nt], 0, 0, 0);
        }
      }
    }
  }
  int ml = lane & 15, rb = (lane >> 4) * 4;
  int co = mg * 16 + rb;
  f32x4 bv = *(const f32x4*)(bias + co);
  #pragma unroll
  for (int p = 0; p < 2; ++p) {
    int px = oy * Wout + ox + p * 2;
    #pragma unroll
    for (int nt = 0; nt < 4; ++nt) {
      float v0 = acc[p][nt][0] + bv[0];
      float v1 = acc[p][nt][1] + bv[1];
      float v2 = acc[p][nt][2] + bv[2];
      float v3 = acc[p][nt][3] + bv[3];
      if (RELU) { v0=fmaxf(v0,0.f); v1=fmaxf(v1,0.f); v2=fmaxf(v2,0.f); v3=fmaxf(v3,0.f); }
      uint2 pk;
      pk.x = (unsigned)f2bf(v0) | ((unsigned)f2bf(v1) << 16);
      pk.y = (unsigned)f2bf(v2) | ((unsigned)f2bf(v3) << 16);
      size_t off = (size_t)px * (COUT * 64) + (size_t)(co >> 5) * 2048 + (size_t)nt * NTS
                 + ((co >> 3) & 3) * 128 + ml * 8 + (co & 7);
      *(uint2*)(out + off) = pk;
    }
  }
}

// ================= enc_fc fused: LDS-transpose staging + MFMA =================
#define APXS 1032
__global__ __launch_bounds__(256) void k_encfc_fused(const ushort* __restrict__ h4,
                                                     const float* __restrict__ wE,
                                                     float* __restrict__ partial) {
  __shared__ float smem[8320];
  ushort* au = (ushort*)smem;
  int s = blockIdx.x;
  int bid = (s & 7) * 256 + (s >> 3);
  int mg = bid & 15;
  int ccf = (bid >> 4) & 7;
  int pxg = bid >> 7;
  int tid = threadIdx.x;
  int co0 = mg * 32;
  #pragma unroll 4
  for (int i = 0; i < 64; ++i) {
    int idx = tid + i * 256;
    int px_l = idx & 15;
    int ci_l = (idx >> 4) & 31;
    int co_l = idx >> 9;
    float v = wE[((size_t)(co0 + co_l) << 16) + (size_t)(ccf * 32 + ci_l) * 256 + pxg * 16 + px_l];
    int mt = co_l >> 4, m = co_l & 15;
    int kg = ci_l >> 3, k8 = ci_l & 7;
    au[px_l * APXS + mt * 512 + kg * 128 + m * 8 + k8] = f2bf(v);
  }
  __syncthreads();
  int lane = tid & 63, wv = tid >> 6;
  int ml = lane & 15, rb = (lane >> 4) * 4;
  f32x4 zero = {0.f, 0.f, 0.f, 0.f};
  f32x4 acc[2][4];
  #pragma unroll
  for (int mt = 0; mt < 2; ++mt)
    #pragma unroll
    for (int nt = 0; nt < 4; ++nt) acc[mt][nt] = zero;
  #pragma unroll
  for (int jj = 0; jj < 4; ++jj) {
    int j = wv * 4 + jj;
    int px = pxg * 16 + j;
    bf16x8 a0 = *(const bf16x8*)(au + j * APXS + lane * 8);
    bf16x8 a1 = *(const bf16x8*)(au + j * APXS + 512 + lane * 8);
    const ushort* hb = h4 + (size_t)px * 16384 + ccf * 2048 + lane * 8;
    bf16x8 bb[4];
    #pragma unroll
    for (int nt = 0; nt < 4; ++nt)
      bb[nt] = *(const bf16x8*)(hb + nt * 512);
    #pragma unroll
    for (int nt = 0; nt < 4; ++nt) {
      acc[0][nt] = __builtin_amdgcn_mfma_f32_16x16x32_bf16(a0, bb[nt], acc[0][nt], 0, 0, 0);
      acc[1][nt] = __builtin_amdgcn_mfma_f32_16x16x32_bf16(a1, bb[nt], acc[1][nt], 0, 0, 0);
    }
  }
  __syncthreads();
  #pragma unroll
  for (int mt = 0; mt < 2; ++mt)
    #pragma unroll
    for (int nt = 0; nt < 4; ++nt)
      #pragma unroll
      for (int r = 0; r < 4; ++r)
        smem[wv * 2080 + (mt * 16 + rb + r) * 65 + nt * 16 + ml] = acc[mt][nt][r];
  __syncthreads();
  int ks = pxg * 8 + ccf;
  #pragma unroll
  for (int i = 0; i < 8; ++i) {
    int e = tid + i * 256;
    int b = e & 63, co_l = e >> 6;
    float sum = smem[co_l * 65 + b] + smem[2080 + co_l * 65 + b]
              + smem[4160 + co_l * 65 + b] + smem[6240 + co_l * 65 + b];
    partial[((size_t)(co0 + co_l) * ENC_KS + ks) * 64 + b] = sum;
  }
}

__global__ void k_encfc_red(const float* __restrict__ partial, const float* __restrict__ bias,
                            float* __restrict__ cnn) {
  int id = blockIdx.x * blockDim.x + threadIdx.x;
  int o = id >> 6, b = id & 63;
  float acc = bias[o];
  #pragma unroll 8
  for (int s = 0; s < ENC_KS; ++s) acc += partial[((size_t)o * ENC_KS + s) * 64 + b];
  cnn[(size_t)b * 512 + o] = fmaxf(acc, 0.f);
}

// ================= posterior / reparam =================

__global__ void k_post(const float* __restrict__ cnn, const float* __restrict__ belief,
                       const float* __restrict__ w, const float* __restrict__ bias,
                       float* __restrict__ out) {
  int id = blockIdx.x * blockDim.x + threadIdx.x;
  int b = id >> 9, j = id & 511;
  const float* wr = w + (size_t)j * 1024;
  const float* cr = cnn + (size_t)b * HIDD;
  const float* br = belief + (size_t)b * HIDD;
  float acc = bias[j];
  #pragma unroll 4
  for (int k = 0; k < HIDD; ++k) acc += cr[k] * wr[k];
  #pragma unroll 4
  for (int k = 0; k < HIDD; ++k) acc += br[k] * wr[512 + k];
  if (j < 256) out[O_MUPO + b * 256 + j] = acc;
  else         out[O_LVPO + b * 256 + (j - 256)] = acc;
}

__global__ void k_z(const float* __restrict__ eps, float* __restrict__ out,
                    ushort* __restrict__ zb) {
  int id = blockIdx.x * blockDim.x + threadIdx.x;
  int b = id >> 8, i = id & 255;
  float mu = out[O_MUPO + b * 256 + i];
  float lv = out[O_LVPO + b * 256 + i];
  float z = mu + eps[id] * expf(0.5f * lv);
  out[O_ZT + b * 256 + i] = z;
  if (i < 128) zb[b * 128 + i] = f2bf(z);
}

// ================= dec_fc MFMA: direct f32 weights, frag-order out =================
__global__ __launch_bounds__(256) void k_decfc_mfma(const ushort* __restrict__ zb,
                                                    const float* __restrict__ dfw,
                                                    const float* __restrict__ dfb,
                                                    ushort* __restrict__ dec) {
  int wid = __builtin_amdgcn_readfirstlane(blockIdx.x * 4 + (threadIdx.x >> 6));
  int lane = threadIdx.x & 63;
  int m0 = wid * 32;
  int ml = lane & 15, kl = (lane >> 4) * 8;
  f32x4 zero = {0.f, 0.f, 0.f, 0.f};
  f32x4 acc[2][4];
  #pragma unroll
  for (int mt = 0; mt < 2; ++mt)
    #pragma unroll
    for (int nt = 0; nt < 4; ++nt) acc[mt][nt] = zero;
  #pragma unroll
  for (int kc = 0; kc < 4; ++kc) {
    bf16x8 a[2], bb[4];
    #pragma unroll
    for (int mt = 0; mt < 2; ++mt) {
      int m_r = m0 + mt * 16 + ml;
      const float* wr = dfw + (size_t)((m_r & 127) * 256 + (m_r >> 7)) * 128 + kc * 32 + kl;
      float4 u0 = *(const float4*)wr;
      float4 u1 = *(const float4*)(wr + 4);
      bf16x8 av;
      av[0] = (short)f2bf(u0.x); av[1] = (short)f2bf(u0.y);
      av[2] = (short)f2bf(u0.z); av[3] = (short)f2bf(u0.w);
      av[4] = (short)f2bf(u1.x); av[5] = (short)f2bf(u1.y);
      av[6] = (short)f2bf(u1.z); av[7] = (short)f2bf(u1.w);
      a[mt] = av;
    }
    #pragma unroll
    for (int nt = 0; nt < 4; ++nt)
      bb[nt] = *(const bf16x8*)(zb + (size_t)(nt * 16 + ml) * 128 + kc * 32 + kl);
    #pragma unroll
    for (int mt = 0; mt < 2; ++mt)
      #pragma unroll
      for (int nt = 0; nt < 4; ++nt)
        acc[mt][nt] = __builtin_amdgcn_mfma_f32_16x16x32_bf16(a[mt], bb[nt], acc[mt][nt], 0, 0, 0);
  }
  int rb = (lane >> 4) * 4;
  #pragma unroll
  for (int mt = 0; mt < 2; ++mt) {
    int m = m0 + mt * 16 + rb;
    int pix = m >> 7, co = m & 127;
    float bv0 = dfb[(size_t)(co + 0) * 256 + pix];
    float bv1 = dfb[(size_t)(co + 1) * 256 + pix];
    float bv2 = dfb[(size_t)(co + 2) * 256 + pix];
    float bv3 = dfb[(size_t)(co + 3) * 256 + pix];
    #pragma unroll
    for (int nt = 0; nt < 4; ++nt) {
      uint2 pk;
      pk.x = (unsigned)f2bf(acc[mt][nt][0] + bv0) | ((unsigned)f2bf(acc[mt][nt][1] + bv1) << 16);
      pk.y = (unsigned)f2bf(acc[mt][nt][2] + bv2) | ((unsigned)f2bf(acc[mt][nt][3] + bv3) << 16);
      size_t off = (size_t)pix * 8192 + (size_t)(co >> 5) * 2048 + nt * 512
                 + ((co >> 3) & 3) * 128 + ml * 8 + (co & 7);
      *(uint2*)(dec + off) = pk;
    }
  }
}

// ================= d4 fused with output transpose =================
__global__ __launch_bounds__(256) void k_d4t(const ushort* __restrict__ in,
                                             const float* __restrict__ w,
                                             const float* __restrict__ bias,
                                             float* __restrict__ out) {
  __shared__ float lds[64][65];
  int blk = blockIdx.x;
  int oy = blk >> 2, ox0 = (blk & 3) << 6;
  int t = threadIdx.x;
  int b = t & 63, sub = t >> 6;
  float bv = bias[0];
  for (int j = 0; j < 16; ++j) {
    int oxl = j * 4 + sub;
    int ox = ox0 + oxl;
    int p0 = (oy + 1) & 1, q0 = (ox + 1) & 1;
    int iy0 = (oy + 1 - p0) >> 1, ix0 = (ox + 1 - q0) >> 1;
    float acc = bv;
    #pragma unroll
    for (int i = 0; i < 2; ++i) {
      int iy = iy0 - i;
      if ((unsigned)iy >= 128u) continue;
      int p = p0 + 2 * i;
      #pragma unroll
      for (int jj = 0; jj < 2; ++jj) {
        int ix = ix0 - jj;
        if ((unsigned)ix >= 128u) continue;
        int q = q0 + 2 * jj;
        const ushort* base = in + (size_t)(iy * 128 + ix) * 1024 + (b >> 4) * 256 + (b & 15) * 8;
        bf16x8 v0 = *(const bf16x8*)(base);
        bf16x8 v1 = *(const bf16x8*)(base + 128);
        const float* wq = w + p * 4 + q;
        #pragma unroll
        for (int ci = 0; ci < 8; ++ci) acc += bf2f((ushort)v0[ci]) * wq[ci * 16];
        #pragma unroll
        for (int ci = 0; ci < 8; ++ci) acc += bf2f((ushort)v1[ci]) * wq[(ci + 8) * 16];
      }
    }
    lds[oxl][b] = acc;
  }
  __syncthreads();
  #pragma unroll
  for (int j = 0; j < 16; ++j) {
    int idx = t + j * 256;
    int b2 = idx >> 6, oxl = idx & 63;
    out[(size_t)b2 * 65536 + oy * 256 + ox0 + oxl] = lds[oxl][b2];
  }
}

// ================= launch =================

extern "C" void kernel_launch(void* const* d_in, const int* in_sizes, int n_in,
                              void* d_out, int out_size, void* d_ws, size_t ws_size,
                              hipStream_t stream) {
  const float* img      = (const float*)d_in[0];
  const float* act      = (const float*)d_in[1];
  const float* z_prev   = (const float*)d_in[2];
  const float* st_prev  = (const float*)d_in[3];
  const float* eps      = (const float*)d_in[4];
  const float* c1w = (const float*)d_in[5];  const float* c1b = (const float*)d_in[6];
  const float* c2w = (const float*)d_in[7];  const float* c2b = (const float*)d_in[8];
  const float* c3w = (const float*)d_in[9];  const float* c3b = (const float*)d_in[10];
  const float* c4w = (const float*)d_in[11]; const float* c4b = (const float*)d_in[12];
  const float* efw = (const float*)d_in[13]; const float* efb = (const float*)d_in[14];
  const float* pow_ = (const float*)d_in[15]; const float* pob = (const float*)d_in[16];
  const float* prw = (const float*)d_in[17]; const float* prb = (const float*)d_in[18];
  const float* siw = (const float*)d_in[19]; const float* sib = (const float*)d_in[20];
  const float* Alog = (const float*)d_in[21];
  const float* Bw = (const float*)d_in[22];  const float* Cw = (const float*)d_in[23];
  const float* Dw = (const float*)d_in[24];  const float* Db = (const float*)d_in[25];
  const float* Dv = (const float*)d_in[26];
  const float* dfw = (const float*)d_in[27]; const float* dfb = (const float*)d_in[28];
  const float* d1w = (const float*)d_in[29]; const float* d1b = (const float*)d_in[30];
  const float* d2w = (const float*)d_in[31]; const float* d2b = (const float*)d_in[32];
  const float* d3w = (const float*)d_in[33]; const float* d3b = (const float*)d_in[34];
  const float* d4w = (const float*)d_in[35]; const float* d4b = (const float*)d_in[36];

  float* ws = (float*)d_ws;
  float* out = (float*)d_out;

  ushort* pc2 = (ushort*)(ws + PW_C2);
  ushort* pc3 = (ushort*)(ws + PW_C3);
  ushort* pc4 = (ushort*)(ws + PW_C4);
  ushort* pd1 = (ushort*)(ws + PW_D1);
  ushort* pd2 = (ushort*)(ws + PW_D2);
  ushort* pd3 = (ushort*)(ws + PW_D3);
  ushort* timgb = (ushort*)(ws + W_TIMG);
  ushort* h1b = (ushort*)(ws + W_H1B);
  ushort* h2b = (ushort*)(ws + W_H2B);
  ushort* h3b = (ushort*)(ws + W_H3B);
  ushort* h4b = (ushort*)(ws + W_H4B);
  ushort* deco = (ushort*)(ws + W_DECO);
  ushort* d1o = (ushort*)(ws + W_D1O);
  ushort* d2o = (ushort*)(ws + W_D2O);
  ushort* d3o = (ushort*)(ws + W_D3O);
  ushort* zb = (ushort*)(ws + W_ZB16);

  // ---- merged weight prepack ----
  k_pack_all<<<3360, 256, 0, stream>>>(c2w, c3w, c4w, d1w, d2w, d3w,
                                       pc2, pc3, pc4, pd1, pd2, pd3);

  // ---- SSM chain ----
  k_ssm_in<<<128, 256, 0, stream>>>(z_prev, act, siw, sib, ws + W_SSMIN);
  k_delta<<<128, 256, 0, stream>>>(ws + W_SSMIN, Dw, Db, ws + W_DELTA);
  k_bc<<<4, 256, 0, stream>>>(ws + W_SSMIN, Bw, Cw, ws + W_BT, ws + W_CT);
  k_state<<<128, 256, 0, stream>>>(ws + W_DELTA, ws + W_SSMIN, Alog, ws + W_BT,
                                   ws + W_CT, Dv, st_prev, out + O_STATE, ws + W_BELIEF);
  k_prior<<<128, 256, 0, stream>>>(ws + W_BELIEF, prw, prb, out);

  // ---- encoder ----
  k_timg<<<3072, 256, 0, stream>>>(img, timgb);
  k_conv1<<<4096, 256, 0, stream>>>(timgb, c1w, c1b, h1b);
  mfma_conv2<32, 64><<<2048, 256, 0, stream>>>(h1b, pc2, c2b, h2b, 128, 128, 64, 64);
  mfma_conv2<64, 128><<<1024, 256, 0, stream>>>(h2b, pc3, c3b, h3b, 64, 64, 32, 32);
  mfma_conv2<128, 256><<<512, 256, 0, stream>>>(h3b, pc4, c4b, h4b, 32, 32, 16, 16);

  // ---- enc_fc (fused transpose+GEMM) ----
  k_encfc_fused<<<2048, 256, 0, stream>>>(h4b, efw, ws + W_ENCP);
  k_encfc_red<<<128, 256, 0, stream>>>(ws + W_ENCP, efb, ws + W_CNN);

  // ---- posterior + reparam ----
  k_post<<<128, 256, 0, stream>>>(ws + W_CNN, ws + W_BELIEF, pow_, pob, out);
  k_z<<<64, 256, 0, stream>>>(eps, out, zb);

  // ---- decoder ----
  k_decfc_mfma<<<256, 256, 0, stream>>>(zb, dfw, dfb, deco);
  mfma_deconv2<128, 64, true><<<512, 256, 0, stream>>>(deco, pd1, d1b, d1o, 16, 16, 32, 32);
  mfma_deconv2<64, 32, true><<<1024, 256, 0, stream>>>(d1o, pd2, d2b, d2o, 32, 32, 64, 64);
  mfma_deconv2<32, 16, true><<<2048, 256, 0, stream>>>(d2o, pd3, d3b, d3o, 64, 64, 128, 128);
  k_d4t<<<1024, 256, 0, stream>>>(d3o, d4w, d4b, out + O_PRED);
}

// Round 8
// 553.213 us; speedup vs baseline: 1.0645x; 1.0645x over previous
//
#include <hip/hip_runtime.h>
#include <math.h>

#define BB 64
#define LATENT 256
#define ACTD 6
#define HIDD 512
#define DST 16

typedef __attribute__((ext_vector_type(8))) short bf16x8;
typedef __attribute__((ext_vector_type(4))) float f32x4;

static __device__ __forceinline__ ushort f2bf(float f) {
  unsigned u = __builtin_bit_cast(unsigned, f);
  unsigned r = (u + 0x7FFFu + ((u >> 16) & 1u)) >> 16;
  return (ushort)r;
}
static __device__ __forceinline__ float bf2f(ushort u) {
  return __builtin_bit_cast(float, ((unsigned)u) << 16);
}

// ---------------- output offsets (floats) ----------------
#define O_PRED   0
#define O_ZT     4194304
#define O_STATE  4210688
#define O_MUP    4734976
#define O_LVP    4751360
#define O_MUPO   4767744
#define O_LVPO   4784128

// ---------------- ws offsets (floats), lifetime-reused ----------------
#define W_BELIEF 67584u
#define W_CNN    100352u
#define W_ZB16   133120u      // 8192 u16
#define PW_C2    137216u      // 32768 u16
#define PW_C3    153600u      // 131072 u16
#define PW_C4    219136u      // 524288 u16
#define PW_D1    481280u      // 131072 u16
#define PW_D2    546816u      // 32768 u16
#define PW_D3    563200u      // 8192 u16
#define W_TIMG   602112u      // timg bf16, region reserved to 13185024
#define W_H1B    13185024u    // 33,554,432 u16 [dead after conv2]
#define W_H2B    29962240u    // 16,777,216 u16
#define W_H3B    38350848u    // 8,388,608 u16
#define W_H4B    42545152u    // 4,194,304 u16
// reuse (regions dead by write time):
#define W_ENCP   602112u      // 4,194,304 f   (TIMG region, dead after conv1)
#define W_DECO   8990720u     // (TIMG region)
#define W_D1O    10039296u    // (TIMG region)
#define W_D2O    13185024u    // (H1B)
#define W_D3O    17379328u    // (H1B)

#define ENC_KS 128

// ================= fused SSM chain: one block per batch =================
__global__ __launch_bounds__(512) void k_ssm_all(
    const float* __restrict__ z_prev, const float* __restrict__ act,
    const float* __restrict__ siw, const float* __restrict__ sib,
    const float* __restrict__ Dw, const float* __restrict__ Db,
    const float* __restrict__ Bw, const float* __restrict__ Cw,
    const float* __restrict__ Alog, const float* __restrict__ Dv,
    const float* __restrict__ st_prev, float* __restrict__ state_out,
    float* __restrict__ belief_out, const float* __restrict__ prw,
    const float* __restrict__ prb, float* __restrict__ out) {
  __shared__ float si[512];
  __shared__ float bel[512];
  __shared__ float part[2][16][4];
  __shared__ float btct[2][16];
  int b = blockIdx.x;
  int h = threadIdx.x;
  // ---- ssm_in ----
  {
    const float* zr = z_prev + (size_t)b * LATENT;
    const float* wr = siw + (size_t)h * (LATENT + ACTD);
    float acc = sib[h];
    #pragma unroll 4
    for (int k = 0; k < LATENT; k += 2) {
      float2 w2 = *(const float2*)(wr + k);
      acc += zr[k] * w2.x + zr[k + 1] * w2.y;
    }
    const float* ar = act + (size_t)b * ACTD;
    #pragma unroll
    for (int k = 0; k < ACTD; ++k) acc += ar[k] * wr[LATENT + k];
    si[h] = acc / (1.f + expf(-acc));
  }
  __syncthreads();
  // ---- delta ----
  float d;
  {
    const float* wr = Dw + (size_t)h * HIDD;
    float acc = Db[h];
    #pragma unroll 4
    for (int k = 0; k < HIDD; k += 4) {
      float4 w4 = *(const float4*)(wr + k);
      acc += si[k] * w4.x + si[k+1] * w4.y + si[k+2] * w4.z + si[k+3] * w4.w;
    }
    d = fmaxf(acc, 0.f) + log1pf(expf(-fabsf(acc)));
  }
  // ---- B_t / C_t partials ----
  if (h < 128) {
    int half = h >> 6;          // 0: B, 1: C
    int l = h & 63;
    int n = l & 15, p = l >> 4; // 4 k-parts of 128
    const float* wr = (half ? Cw : Bw) + (size_t)n * HIDD + p * 128;
    const float* sr = si + p * 128;
    float acc = 0.f;
    #pragma unroll 4
    for (int k = 0; k < 128; k += 4) {
      float4 w4 = *(const float4*)(wr + k);
      acc += sr[k] * w4.x + sr[k+1] * w4.y + sr[k+2] * w4.z + sr[k+3] * w4.w;
    }
    part[half][n][p] = acc;
  }
  __syncthreads();
  if (h < 32) {
    int half = h >> 4, n = h & 15;
    btct[half][n] = part[half][n][0] + part[half][n][1] + part[half][n][2] + part[half][n][3];
  }
  __syncthreads();
  // ---- state + belief ----
  {
    float si_h = si[h];
    float belv = Dv[h] * si_h;
    const float* al = Alog + (size_t)h * DST;
    const float* sp = st_prev + ((size_t)b * 512 + h) * DST;
    float* so = state_out + ((size_t)b * 512 + h) * DST;
    #pragma unroll
    for (int n = 0; n < DST; ++n) {
      float A = -expf(al[n]);
      float st = expf(d * A) * sp[n] + d * btct[0][n] * si_h;
      so[n] = st;
      belv += st * btct[1][n];
    }
    bel[h] = belv;
    belief_out[(size_t)b * 512 + h] = belv;
  }
  __syncthreads();
  // ---- prior ----
  {
    const float* wr = prw + (size_t)h * HIDD;
    float acc = prb[h];
    #pragma unroll 4
    for (int k = 0; k < HIDD; k += 4) {
      float4 w4 = *(const float4*)(wr + k);
      acc += bel[k] * w4.x + bel[k+1] * w4.y + bel[k+2] * w4.z + bel[k+3] * w4.w;
    }
    if (h < 256) out[O_MUP + b * 256 + h] = acc;
    else         out[O_LVP + b * 256 + (h - 256)] = acc;
  }
}

// ================= merged weight prepack (fragment order) =================

static __device__ __forceinline__ void pack_conv_elem(const float* __restrict__ w,
                                                      ushort* __restrict__ o,
                                                      int Cout, int Cin, int id) {
  int NCH = Cin / 2;
  int per = NCH * 512;
  int mt = id / per, r = id % per;
  int kcg = r >> 9, s = r & 511;
  int kg = s >> 7, m = (s >> 3) & 15, k8 = s & 7;
  int co = mt * 16 + m;
  int k = kcg * 32 + kg * 8 + k8;
  int tap = k / Cin, ci = k % Cin;
  o[id] = f2bf(w[(size_t)(co * Cin + ci) * 16 + tap]);
}

static __device__ __forceinline__ void pack_deconv_elem(const float* __restrict__ w,
                                                        ushort* __restrict__ o,
                                                        int Cout, int Cin, int id) {
  int NCH = Cin / 8;
  int perM = NCH * 512;
  int perC = (Cout / 16) * perM;
  int cls = id / perC, r = id % perC;
  int mt = r / perM, r2 = r % perM;
  int kcg = r2 >> 9, s = r2 & 511;
  int kg = s >> 7, m = (s >> 3) & 15, k8 = s & 7;
  int co = mt * 16 + m;
  int k = kcg * 32 + kg * 8 + k8;
  int t = k / Cin, ci = k % Cin;
  int p = (cls >> 1) + 2 * (t >> 1);
  int q = (cls & 1) + 2 * (t & 1);
  o[id] = f2bf(w[(size_t)(ci * Cout + co) * 16 + p * 4 + q]);
}

__global__ __launch_bounds__(256) void k_pack_all(
    const float* __restrict__ c2w, const float* __restrict__ c3w,
    const float* __restrict__ c4w, const float* __restrict__ d1w,
    const float* __restrict__ d2w, const float* __restrict__ d3w,
    ushort* __restrict__ pc2, ushort* __restrict__ pc3, ushort* __restrict__ pc4,
    ushort* __restrict__ pd1, ushort* __restrict__ pd2, ushort* __restrict__ pd3) {
  int id = blockIdx.x * 256 + threadIdx.x;
  if (id < 32768)            pack_conv_elem(c2w, pc2, 64, 32, id);
  else if (id < 163840)      pack_conv_elem(c3w, pc3, 128, 64, id - 32768);
  else if (id < 688128)      pack_conv_elem(c4w, pc4, 256, 128, id - 163840);
  else if (id < 819200)      pack_deconv_elem(d1w, pd1, 64, 128, id - 688128);
  else if (id < 851968)      pack_deconv_elem(d2w, pd2, 32, 64, id - 819200);
  else if (id < 860160)      pack_deconv_elem(d3w, pd3, 16, 32, id - 851968);
}

// ================= img transpose (bf16 out) =================
__global__ __launch_bounds__(256) void k_timg(const float* __restrict__ img,
                                              ushort* __restrict__ timg) {
  int blk = blockIdx.x;
  int c = blk >> 10, p0 = (blk & 1023) << 6;
  __shared__ float t[64 * 65];
  int tid = threadIdx.x;
  #pragma unroll
  for (int i = 0; i < 16; ++i) {
    int idx = tid + i * 256;
    int b = idx >> 6, pr = idx & 63;
    t[pr * 65 + b] = img[((size_t)b * 3 + c) * 65536 + p0 + pr];
  }
  __syncthreads();
  #pragma unroll
  for (int i = 0; i < 16; ++i) {
    int idx = tid + i * 256;
    int pr = idx >> 6, b = idx & 63;
    timg[((size_t)c * 65536 + p0 + pr) * 64 + b] = f2bf(t[pr * 65 + b]);
  }
}

// ================= conv1: direct (Cin=3), interior fast path =================
__global__ __launch_bounds__(256) void k_conv1(const ushort* __restrict__ in,
                                               const float* __restrict__ w,
                                               const float* __restrict__ bias,
                                               ushort* __restrict__ out) {
  int wid = __builtin_amdgcn_readfirstlane(blockIdx.x * 4 + (threadIdx.x >> 6));
  int lane = threadIdx.x & 63;
  int x4 = wid & 31; int t = wid >> 5;
  int oy = t & 127; int cg = t >> 7;
  int co0 = cg * 8;
  int ox0 = x4 << 2;
  int ixb = ox0 * 2 - 1;
  float acc[8][4];
  #pragma unroll
  for (int u = 0; u < 8; ++u) {
    float bv = bias[co0 + u];
    #pragma unroll
    for (int j = 0; j < 4; ++j) acc[u][j] = bv;
  }
  bool interior = (oy >= 1) & (oy < 127) & (x4 >= 1) & (x4 < 31);
  if (interior) {
    for (int ci = 0; ci < 3; ++ci) {
      const ushort* ip = in + ((size_t)ci * 65536) * 64 + lane;
      const float* wp = w + (size_t)co0 * 48 + ci * 16;
      #pragma unroll
      for (int ky = 0; ky < 4; ++ky) {
        int iy = oy * 2 - 1 + ky;
        const ushort* rp = ip + (size_t)iy * 256 * 64;
        float x[10];
        #pragma unroll
        for (int j = 0; j < 10; ++j) x[j] = bf2f(rp[(size_t)(ixb + j) * 64]);
        #pragma unroll
        for (int u = 0; u < 8; ++u) {
          const float* wq = wp + (size_t)u * 48 + ky * 4;
          float w0 = wq[0], w1 = wq[1], w2 = wq[2], w3 = wq[3];
          acc[u][0] += x[0]*w0 + x[1]*w1 + x[2]*w2 + x[3]*w3;
          acc[u][1] += x[2]*w0 + x[3]*w1 + x[4]*w2 + x[5]*w3;
          acc[u][2] += x[4]*w0 + x[5]*w1 + x[6]*w2 + x[7]*w3;
          acc[u][3] += x[6]*w0 + x[7]*w1 + x[8]*w2 + x[9]*w3;
        }
      }
    }
  } else {
    for (int ci = 0; ci < 3; ++ci) {
      const ushort* ip = in + ((size_t)ci * 65536) * 64 + lane;
      const float* wp = w + (size_t)co0 * 48 + ci * 16;
      #pragma unroll
      for (int ky = 0; ky < 4; ++ky) {
        int iy = oy * 2 - 1 + ky;
        if ((unsigned)iy >= 256u) continue;
        const ushort* rp = ip + (size_t)iy * 256 * 64;
        float x[10];
        #pragma unroll
        for (int j = 0; j < 10; ++j) {
          int ix = ixb + j;
          x[j] = ((unsigned)ix < 256u) ? bf2f(rp[(size_t)ix * 64]) : 0.f;
        }
        #pragma unroll
        for (int u = 0; u < 8; ++u) {
          const float* wq = wp + (size_t)u * 48 + ky * 4;
          float w0 = wq[0], w1 = wq[1], w2 = wq[2], w3 = wq[3];
          acc[u][0] += x[0]*w0 + x[1]*w1 + x[2]*w2 + x[3]*w3;
          acc[u][1] += x[2]*w0 + x[3]*w1 + x[4]*w2 + x[5]*w3;
          acc[u][2] += x[4]*w0 + x[5]*w1 + x[6]*w2 + x[7]*w3;
          acc[u][3] += x[6]*w0 + x[7]*w1 + x[8]*w2 + x[9]*w3;
        }
      }
    }
  }
  #pragma unroll
  for (int j = 0; j < 4; ++j) {
    int px = oy * 128 + ox0 + j;
    size_t off = (size_t)px * 2048 + (size_t)(lane >> 4) * 512 + cg * 128 + (lane & 15) * 8;
    ushort tmp[8];
    #pragma unroll
    for (int u = 0; u < 8; ++u) tmp[u] = f2bf(fmaxf(acc[u][j], 0.f));
    uint4 pk;
    pk.x = tmp[0] | ((unsigned)tmp[1] << 16);
    pk.y = tmp[2] | ((unsigned)tmp[3] << 16);
    pk.z = tmp[4] | ((unsigned)tmp[5] << 16);
    pk.w = tmp[6] | ((unsigned)tmp[7] << 16);
    *(uint4*)(out + off) = pk;
  }
}

// ================= MFMA conv, interior fast path =================
template<int CIN, int COUT, int MT>
__global__ __launch_bounds__(256) void mfma_conv(const ushort* __restrict__ in,
                                                 const ushort* __restrict__ wp,
                                                 const float* __restrict__ bias,
                                                 ushort* __restrict__ out,
                                                 int Hin, int Win, int Hout, int Wout) {
  constexpr int NMG = COUT / (16 * MT);
  constexpr int NKC = CIN / 32;
  constexpr int NCH = 16 * NKC;
  int wid = __builtin_amdgcn_readfirstlane(blockIdx.x * 4 + (threadIdx.x >> 6));
  int lane = threadIdx.x & 63;
  int mg = wid % NMG;
  int px = wid / NMG;
  int ox = px % Wout, oy = px / Wout;
  if (oy >= Hout) return;
  int mtile0 = mg * MT;
  f32x4 zero = {0.f, 0.f, 0.f, 0.f};
  f32x4 acc[MT][4];
  #pragma unroll
  for (int mt = 0; mt < MT; ++mt)
    #pragma unroll
    for (int nt = 0; nt < 4; ++nt) acc[mt][nt] = zero;
  const ushort* wbase = wp + (size_t)mtile0 * NCH * 512 + lane * 8;
  const size_t mstride = (size_t)NCH * 512;
  bool interior = (oy >= 1) & (oy < Hout - 1) & (ox >= 1) & (ox < Wout - 1);

  if (interior) {
    #pragma unroll
    for (int ky = 0; ky < 4; ++ky) {
      int iy = 2 * oy - 1 + ky;
      #pragma unroll
      for (int kx = 0; kx < 4; ++kx) {
        int ix = 2 * ox - 1 + kx;
        const ushort* ib = in + (size_t)(iy * Win + ix) * (CIN * 64) + lane * 8;
        int tap = ky * 4 + kx;
        #pragma unroll
        for (int kc = 0; kc < NKC; ++kc) {
          int kcg = tap * NKC + kc;
          bf16x8 a[MT], bb[4];
          #pragma unroll
          for (int mt = 0; mt < MT; ++mt)
            a[mt] = *(const bf16x8*)(wbase + mt * mstride + (size_t)kcg * 512);
          #pragma unroll
          for (int nt = 0; nt < 4; ++nt)
            bb[nt] = *(const bf16x8*)(ib + kc * 2048 + nt * 512);
          #pragma unroll
          for (int mt = 0; mt < MT; ++mt)
            #pragma unroll
            for (int nt = 0; nt < 4; ++nt)
              acc[mt][nt] = __builtin_amdgcn_mfma_f32_16x16x32_bf16(a[mt], bb[nt], acc[mt][nt], 0, 0, 0);
        }
      }
    }
  } else {
    for (int ky = 0; ky < 4; ++ky) {
      int iy = 2 * oy - 1 + ky;
      if ((unsigned)iy >= (unsigned)Hin) continue;
      for (int kx = 0; kx < 4; ++kx) {
        int ix = 2 * ox - 1 + kx;
        if ((unsigned)ix >= (unsigned)Win) continue;
        const ushort* ib = in + (size_t)(iy * Win + ix) * (CIN * 64) + lane * 8;
        int tap = ky * 4 + kx;
        #pragma unroll
        for (int kc = 0; kc < NKC; ++kc) {
          int kcg = tap * NKC + kc;
          bf16x8 a[MT], bb[4];
          #pragma unroll
          for (int mt = 0; mt < MT; ++mt)
            a[mt] = *(const bf16x8*)(wbase + mt * mstride + (size_t)kcg * 512);
          #pragma unroll
          for (int nt = 0; nt < 4; ++nt)
            bb[nt] = *(const bf16x8*)(ib + kc * 2048 + nt * 512);
          #pragma unroll
          for (int mt = 0; mt < MT; ++mt)
            #pragma unroll
            for (int nt = 0; nt < 4; ++nt)
              acc[mt][nt] = __builtin_amdgcn_mfma_f32_16x16x32_bf16(a[mt], bb[nt], acc[mt][nt], 0, 0, 0);
        }
      }
    }
  }
  int ml = lane & 15, rb = (lane >> 4) * 4;
  #pragma unroll
  for (int mt = 0; mt < MT; ++mt) {
    int co = mtile0 * 16 + mt * 16 + rb;
    f32x4 bv = *(const f32x4*)(bias + co);
    #pragma unroll
    for (int nt = 0; nt < 4; ++nt) {
      float v0 = fmaxf(acc[mt][nt][0] + bv[0], 0.f);
      float v1 = fmaxf(acc[mt][nt][1] + bv[1], 0.f);
      float v2 = fmaxf(acc[mt][nt][2] + bv[2], 0.f);
      float v3 = fmaxf(acc[mt][nt][3] + bv[3], 0.f);
      uint2 pk;
      pk.x = (unsigned)f2bf(v0) | ((unsigned)f2bf(v1) << 16);
      pk.y = (unsigned)f2bf(v2) | ((unsigned)f2bf(v3) << 16);
      size_t off = (size_t)px * (COUT * 64) + (size_t)(co >> 5) * 2048 + nt * 512
                 + ((co >> 3) & 3) * 128 + ml * 8 + (co & 7);
      *(uint2*)(out + off) = pk;
    }
  }
}

// ================= MFMA transposed conv, interior fast path =================
template<int CIN, int COUT, int MT, bool RELU>
__global__ __launch_bounds__(256) void mfma_deconv(const ushort* __restrict__ in,
                                                   const ushort* __restrict__ wp,
                                                   const float* __restrict__ bias,
                                                   ushort* __restrict__ out,
                                                   int Hin, int Win, int Hout, int Wout) {
  constexpr int NMG = COUT / (16 * MT);
  constexpr int NKC = CIN / 32;
  constexpr int NCH = 4 * NKC;
  constexpr int NTS = (COUT >= 32) ? 512 : (COUT * 16);
  int wid = __builtin_amdgcn_readfirstlane(blockIdx.x * 4 + (threadIdx.x >> 6));
  int lane = threadIdx.x & 63;
  int mg = wid % NMG; int r1 = wid / NMG;
  int wo2 = Wout >> 1;
  int pc = (Hout >> 1) * wo2;
  int pxc = r1 % pc; int cls = r1 / pc;
  if (cls >= 4) return;
  int p0 = cls >> 1, q0 = cls & 1;
  int tx = pxc % wo2, ty = pxc / wo2;
  int oy = 2 * ty + 1 - p0, ox = 2 * tx + 1 - q0;
  int iy0 = (oy + 1 - p0) >> 1, ix0 = (ox + 1 - q0) >> 1;
  int mtile0 = mg * MT;
  f32x4 zero = {0.f, 0.f, 0.f, 0.f};
  f32x4 acc[MT][4];
  #pragma unroll
  for (int mt = 0; mt < MT; ++mt)
    #pragma unroll
    for (int nt = 0; nt < 4; ++nt) acc[mt][nt] = zero;
  const ushort* wbase = wp + ((size_t)cls * (COUT / 16) + mtile0) * NCH * 512 + lane * 8;
  const size_t mstride = (size_t)NCH * 512;
  bool interior = (iy0 >= 1) & (iy0 <= Hin - 1) & (ix0 >= 1) & (ix0 <= Win - 1);

  if (interior) {
    #pragma unroll
    for (int i = 0; i < 2; ++i) {
      int iy = iy0 - i;
      #pragma unroll
      for (int j = 0; j < 2; ++j) {
        int ix = ix0 - j;
        const ushort* ib = in + (size_t)(iy * Win + ix) * (CIN * 64) + lane * 8;
        int tap = i * 2 + j;
        #pragma unroll
        for (int kc = 0; kc < NKC; ++kc) {
          int kcg = tap * NKC + kc;
          bf16x8 a[MT], bb[4];
          #pragma unroll
          for (int mt = 0; mt < MT; ++mt)
            a[mt] = *(const bf16x8*)(wbase + mt * mstride + (size_t)kcg * 512);
          #pragma unroll
          for (int nt = 0; nt < 4; ++nt)
            bb[nt] = *(const bf16x8*)(ib + kc * 2048 + nt * 512);
          #pragma unroll
          for (int mt = 0; mt < MT; ++mt)
            #pragma unroll
            for (int nt = 0; nt < 4; ++nt)
              acc[mt][nt] = __builtin_amdgcn_mfma_f32_16x16x32_bf16(a[mt], bb[nt], acc[mt][nt], 0, 0, 0);
        }
      }
    }
  } else {
    for (int i = 0; i < 2; ++i) {
      int iy = iy0 - i;
      if ((unsigned)iy >= (unsigned)Hin) continue;
      for (int j = 0; j < 2; ++j) {
        int ix = ix0 - j;
        if ((unsigned)ix >= (unsigned)Win) continue;
        const ushort* ib = in + (size_t)(iy * Win + ix) * (CIN * 64) + lane * 8;
        int tap = i * 2 + j;
        #pragma unroll
        for (int kc = 0; kc < NKC; ++kc) {
          int kcg = tap * NKC + kc;
          bf16x8 a[MT], bb[4];
          #pragma unroll
          for (int mt = 0; mt < MT; ++mt)
            a[mt] = *(const bf16x8*)(wbase + mt * mstride + (size_t)kcg * 512);
          #pragma unroll
          for (int nt = 0; nt < 4; ++nt)
            bb[nt] = *(const bf16x8*)(ib + kc * 2048 + nt * 512);
          #pragma unroll
          for (int mt = 0; mt < MT; ++mt)
            #pragma unroll
            for (int nt = 0; nt < 4; ++nt)
              acc[mt][nt] = __builtin_amdgcn_mfma_f32_16x16x32_bf16(a[mt], bb[nt], acc[mt][nt], 0, 0, 0);
        }
      }
    }
  }
  int ml = lane & 15, rb = (lane >> 4) * 4;
  int px = oy * Wout + ox;
  #pragma unroll
  for (int mt = 0; mt < MT; ++mt) {
    int co = mtile0 * 16 + mt * 16 + rb;
    f32x4 bv = *(const f32x4*)(bias + co);
    #pragma unroll
    for (int nt = 0; nt < 4; ++nt) {
      float v0 = acc[mt][nt][0] + bv[0];
      float v1 = acc[mt][nt][1] + bv[1];
      float v2 = acc[mt][nt][2] + bv[2];
      float v3 = acc[mt][nt][3] + bv[3];
      if (RELU) { v0=fmaxf(v0,0.f); v1=fmaxf(v1,0.f); v2=fmaxf(v2,0.f); v3=fmaxf(v3,0.f); }
      uint2 pk;
      pk.x = (unsigned)f2bf(v0) | ((unsigned)f2bf(v1) << 16);
      pk.y = (unsigned)f2bf(v2) | ((unsigned)f2bf(v3) << 16);
      size_t off = (size_t)px * (COUT * 64) + (size_t)(co >> 5) * 2048 + (size_t)nt * NTS
                 + ((co >> 3) & 3) * 128 + ml * 8 + (co & 7);
      *(uint2*)(out + off) = pk;
    }
  }
}

// ================= enc_fc fused: LDS-transpose staging + MFMA =================
#define APXS 1032
__global__ __launch_bounds__(256) void k_encfc_fused(const ushort* __restrict__ h4,
                                                     const float* __restrict__ wE,
                                                     float* __restrict__ partial) {
  __shared__ float smem[8320];
  ushort* au = (ushort*)smem;
  int s = blockIdx.x;
  int bid = (s & 7) * 256 + (s >> 3);
  int mg = bid & 15;
  int ccf = (bid >> 4) & 7;
  int pxg = bid >> 7;
  int tid = threadIdx.x;
  int co0 = mg * 32;
  #pragma unroll 4
  for (int i = 0; i < 64; ++i) {
    int idx = tid + i * 256;
    int px_l = idx & 15;
    int ci_l = (idx >> 4) & 31;
    int co_l = idx >> 9;
    float v = wE[((size_t)(co0 + co_l) << 16) + (size_t)(ccf * 32 + ci_l) * 256 + pxg * 16 + px_l];
    int mt = co_l >> 4, m = co_l & 15;
    int kg = ci_l >> 3, k8 = ci_l & 7;
    au[px_l * APXS + mt * 512 + kg * 128 + m * 8 + k8] = f2bf(v);
  }
  __syncthreads();
  int lane = tid & 63, wv = tid >> 6;
  int ml = lane & 15, rb = (lane >> 4) * 4;
  f32x4 zero = {0.f, 0.f, 0.f, 0.f};
  f32x4 acc[2][4];
  #pragma unroll
  for (int mt = 0; mt < 2; ++mt)
    #pragma unroll
    for (int nt = 0; nt < 4; ++nt) acc[mt][nt] = zero;
  #pragma unroll
  for (int jj = 0; jj < 4; ++jj) {
    int j = wv * 4 + jj;
    int px = pxg * 16 + j;
    bf16x8 a0 = *(const bf16x8*)(au + j * APXS + lane * 8);
    bf16x8 a1 = *(const bf16x8*)(au + j * APXS + 512 + lane * 8);
    const ushort* hb = h4 + (size_t)px * 16384 + ccf * 2048 + lane * 8;
    bf16x8 bb[4];
    #pragma unroll
    for (int nt = 0; nt < 4; ++nt)
      bb[nt] = *(const bf16x8*)(hb + nt * 512);
    #pragma unroll
    for (int nt = 0; nt < 4; ++nt) {
      acc[0][nt] = __builtin_amdgcn_mfma_f32_16x16x32_bf16(a0, bb[nt], acc[0][nt], 0, 0, 0);
      acc[1][nt] = __builtin_amdgcn_mfma_f32_16x16x32_bf16(a1, bb[nt], acc[1][nt], 0, 0, 0);
    }
  }
  __syncthreads();
  #pragma unroll
  for (int mt = 0; mt < 2; ++mt)
    #pragma unroll
    for (int nt = 0; nt < 4; ++nt)
      #pragma unroll
      for (int r = 0; r < 4; ++r)
        smem[wv * 2080 + (mt * 16 + rb + r) * 65 + nt * 16 + ml] = acc[mt][nt][r];
  __syncthreads();
  int ks = pxg * 8 + ccf;
  #pragma unroll
  for (int i = 0; i < 8; ++i) {
    int e = tid + i * 256;
    int b = e & 63, co_l = e >> 6;
    float sum = smem[co_l * 65 + b] + smem[2080 + co_l * 65 + b]
              + smem[4160 + co_l * 65 + b] + smem[6240 + co_l * 65 + b];
    partial[((size_t)(co0 + co_l) * ENC_KS + ks) * 64 + b] = sum;
  }
}

__global__ void k_encfc_red(const float* __restrict__ partial, const float* __restrict__ bias,
                            float* __restrict__ cnn) {
  int id = blockIdx.x * blockDim.x + threadIdx.x;
  int o = id >> 6, b = id & 63;
  float acc = bias[o];
  #pragma unroll 8
  for (int s = 0; s < ENC_KS; ++s) acc += partial[((size_t)o * ENC_KS + s) * 64 + b];
  cnn[(size_t)b * 512 + o] = fmaxf(acc, 0.f);
}

// ================= fused posterior + reparam =================
__global__ __launch_bounds__(512) void k_postz(const float* __restrict__ cnn,
                                               const float* __restrict__ belief,
                                               const float* __restrict__ w,
                                               const float* __restrict__ bias,
                                               const float* __restrict__ eps,
                                               float* __restrict__ out,
                                               ushort* __restrict__ zb) {
  __shared__ float sm[512];
  int b = blockIdx.x;
  int j = threadIdx.x;
  const float* wr = w + (size_t)j * 1024;
  const float* cr = cnn + (size_t)b * HIDD;
  const float* br = belief + (size_t)b * HIDD;
  float acc = bias[j];
  #pragma unroll 4
  for (int k = 0; k < HIDD; k += 4) {
    float4 w4 = *(const float4*)(wr + k);
    acc += cr[k] * w4.x + cr[k+1] * w4.y + cr[k+2] * w4.z + cr[k+3] * w4.w;
  }
  #pragma unroll 4
  for (int k = 0; k < HIDD; k += 4) {
    float4 w4 = *(const float4*)(wr + 512 + k);
    acc += br[k] * w4.x + br[k+1] * w4.y + br[k+2] * w4.z + br[k+3] * w4.w;
  }
  sm[j] = acc;
  if (j < 256) out[O_MUPO + b * 256 + j] = acc;
  else         out[O_LVPO + b * 256 + (j - 256)] = acc;
  __syncthreads();
  if (j < 256) {
    float z = sm[j] + eps[b * 256 + j] * expf(0.5f * sm[j + 256]);
    out[O_ZT + b * 256 + j] = z;
    if (j < 128) zb[b * 128 + j] = f2bf(z);
  }
}

// ================= dec_fc MFMA: direct f32 weights, frag-order out =================
__global__ __launch_bounds__(256) void k_decfc_mfma(const ushort* __restrict__ zb,
                                                    const float* __restrict__ dfw,
                                                    const float* __restrict__ dfb,
                                                    ushort* __restrict__ dec) {
  int wid = __builtin_amdgcn_readfirstlane(blockIdx.x * 4 + (threadIdx.x >> 6));
  int lane = threadIdx.x & 63;
  int m0 = wid * 32;
  int ml = lane & 15, kl = (lane >> 4) * 8;
  f32x4 zero = {0.f, 0.f, 0.f, 0.f};
  f32x4 acc[2][4];
  #pragma unroll
  for (int mt = 0; mt < 2; ++mt)
    #pragma unroll
    for (int nt = 0; nt < 4; ++nt) acc[mt][nt] = zero;
  #pragma unroll
  for (int kc = 0; kc < 4; ++kc) {
    bf16x8 a[2], bb[4];
    #pragma unroll
    for (int mt = 0; mt < 2; ++mt) {
      int m_r = m0 + mt * 16 + ml;
      const float* wr = dfw + (size_t)((m_r & 127) * 256 + (m_r >> 7)) * 128 + kc * 32 + kl;
      float4 u0 = *(const float4*)wr;
      float4 u1 = *(const float4*)(wr + 4);
      bf16x8 av;
      av[0] = (short)f2bf(u0.x); av[1] = (short)f2bf(u0.y);
      av[2] = (short)f2bf(u0.z); av[3] = (short)f2bf(u0.w);
      av[4] = (short)f2bf(u1.x); av[5] = (short)f2bf(u1.y);
      av[6] = (short)f2bf(u1.z); av[7] = (short)f2bf(u1.w);
      a[mt] = av;
    }
    #pragma unroll
    for (int nt = 0; nt < 4; ++nt)
      bb[nt] = *(const bf16x8*)(zb + (size_t)(nt * 16 + ml) * 128 + kc * 32 + kl);
    #pragma unroll
    for (int mt = 0; mt < 2; ++mt)
      #pragma unroll
      for (int nt = 0; nt < 4; ++nt)
        acc[mt][nt] = __builtin_amdgcn_mfma_f32_16x16x32_bf16(a[mt], bb[nt], acc[mt][nt], 0, 0, 0);
  }
  int rb = (lane >> 4) * 4;
  #pragma unroll
  for (int mt = 0; mt < 2; ++mt) {
    int m = m0 + mt * 16 + rb;
    int pix = m >> 7, co = m & 127;
    float bv0 = dfb[(size_t)(co + 0) * 256 + pix];
    float bv1 = dfb[(size_t)(co + 1) * 256 + pix];
    float bv2 = dfb[(size_t)(co + 2) * 256 + pix];
    float bv3 = dfb[(size_t)(co + 3) * 256 + pix];
    #pragma unroll
    for (int nt = 0; nt < 4; ++nt) {
      uint2 pk;
      pk.x = (unsigned)f2bf(acc[mt][nt][0] + bv0) | ((unsigned)f2bf(acc[mt][nt][1] + bv1) << 16);
      pk.y = (unsigned)f2bf(acc[mt][nt][2] + bv2) | ((unsigned)f2bf(acc[mt][nt][3] + bv3) << 16);
      size_t off = (size_t)pix * 8192 + (size_t)(co >> 5) * 2048 + nt * 512
                 + ((co >> 3) & 3) * 128 + ml * 8 + (co & 7);
      *(uint2*)(dec + off) = pk;
    }
  }
}

// ================= d4 fused with output transpose =================
__global__ __launch_bounds__(256) void k_d4t(const ushort* __restrict__ in,
                                             const float* __restrict__ w,
                                             const float* __restrict__ bias,
                                             float* __restrict__ out) {
  __shared__ float lds[64][65];
  int blk = blockIdx.x;
  int oy = blk >> 2, ox0 = (blk & 3) << 6;
  int t = threadIdx.x;
  int b = t & 63, sub = t >> 6;
  float bv = bias[0];
  for (int j = 0; j < 16; ++j) {
    int oxl = j * 4 + sub;
    int ox = ox0 + oxl;
    int p0 = (oy + 1) & 1, q0 = (ox + 1) & 1;
    int iy0 = (oy + 1 - p0) >> 1, ix0 = (ox + 1 - q0) >> 1;
    float acc = bv;
    #pragma unroll
    for (int i = 0; i < 2; ++i) {
      int iy = iy0 - i;
      if ((unsigned)iy >= 128u) continue;
      int p = p0 + 2 * i;
      #pragma unroll
      for (int jj = 0; jj < 2; ++jj) {
        int ix = ix0 - jj;
        if ((unsigned)ix >= 128u) continue;
        int q = q0 + 2 * jj;
        const ushort* base = in + (size_t)(iy * 128 + ix) * 1024 + (b >> 4) * 256 + (b & 15) * 8;
        bf16x8 v0 = *(const bf16x8*)(base);
        bf16x8 v1 = *(const bf16x8*)(base + 128);
        const float* wq = w + p * 4 + q;
        #pragma unroll
        for (int ci = 0; ci < 8; ++ci) acc += bf2f((ushort)v0[ci]) * wq[ci * 16];
        #pragma unroll
        for (int ci = 0; ci < 8; ++ci) acc += bf2f((ushort)v1[ci]) * wq[(ci + 8) * 16];
      }
    }
    lds[oxl][b] = acc;
  }
  __syncthreads();
  #pragma unroll
  for (int j = 0; j < 16; ++j) {
    int idx = t + j * 256;
    int b2 = idx >> 6, oxl = idx & 63;
    out[(size_t)b2 * 65536 + oy * 256 + ox0 + oxl] = lds[oxl][b2];
  }
}

// ================= launch =================

extern "C" void kernel_launch(void* const* d_in, const int* in_sizes, int n_in,
                              void* d_out, int out_size, void* d_ws, size_t ws_size,
                              hipStream_t stream) {
  const float* img      = (const float*)d_in[0];
  const float* act      = (const float*)d_in[1];
  const float* z_prev   = (const float*)d_in[2];
  const float* st_prev  = (const float*)d_in[3];
  const float* eps      = (const float*)d_in[4];
  const float* c1w = (const float*)d_in[5];  const float* c1b = (const float*)d_in[6];
  const float* c2w = (const float*)d_in[7];  const float* c2b = (const float*)d_in[8];
  const float* c3w = (const float*)d_in[9];  const float* c3b = (const float*)d_in[10];
  const float* c4w = (const float*)d_in[11]; const float* c4b = (const float*)d_in[12];
  const float* efw = (const float*)d_in[13]; const float* efb = (const float*)d_in[14];
  const float* pow_ = (const float*)d_in[15]; const float* pob = (const float*)d_in[16];
  const float* prw = (const float*)d_in[17]; const float* prb = (const float*)d_in[18];
  const float* siw = (const float*)d_in[19]; const float* sib = (const float*)d_in[20];
  const float* Alog = (const float*)d_in[21];
  const float* Bw = (const float*)d_in[22];  const float* Cw = (const float*)d_in[23];
  const float* Dw = (const float*)d_in[24];  const float* Db = (const float*)d_in[25];
  const float* Dv = (const float*)d_in[26];
  const float* dfw = (const float*)d_in[27]; const float* dfb = (const float*)d_in[28];
  const float* d1w = (const float*)d_in[29]; const float* d1b = (const float*)d_in[30];
  const float* d2w = (const float*)d_in[31]; const float* d2b = (const float*)d_in[32];
  const float* d3w = (const float*)d_in[33]; const float* d3b = (const float*)d_in[34];
  const float* d4w = (const float*)d_in[35]; const float* d4b = (const float*)d_in[36];

  float* ws = (float*)d_ws;
  float* out = (float*)d_out;

  ushort* pc2 = (ushort*)(ws + PW_C2);
  ushort* pc3 = (ushort*)(ws + PW_C3);
  ushort* pc4 = (ushort*)(ws + PW_C4);
  ushort* pd1 = (ushort*)(ws + PW_D1);
  ushort* pd2 = (ushort*)(ws + PW_D2);
  ushort* pd3 = (ushort*)(ws + PW_D3);
  ushort* timgb = (ushort*)(ws + W_TIMG);
  ushort* h1b = (ushort*)(ws + W_H1B);
  ushort* h2b = (ushort*)(ws + W_H2B);
  ushort* h3b = (ushort*)(ws + W_H3B);
  ushort* h4b = (ushort*)(ws + W_H4B);
  ushort* deco = (ushort*)(ws + W_DECO);
  ushort* d1o = (ushort*)(ws + W_D1O);
  ushort* d2o = (ushort*)(ws + W_D2O);
  ushort* d3o = (ushort*)(ws + W_D3O);
  ushort* zb = (ushort*)(ws + W_ZB16);

  // ---- merged weight prepack ----
  k_pack_all<<<3360, 256, 0, stream>>>(c2w, c3w, c4w, d1w, d2w, d3w,
                                       pc2, pc3, pc4, pd1, pd2, pd3);

  // ---- fused SSM chain ----
  k_ssm_all<<<64, 512, 0, stream>>>(z_prev, act, siw, sib, Dw, Db, Bw, Cw,
                                    Alog, Dv, st_prev, out + O_STATE,
                                    ws + W_BELIEF, prw, prb, out);

  // ---- encoder ----
  k_timg<<<3072, 256, 0, stream>>>(img, timgb);
  k_conv1<<<4096, 256, 0, stream>>>(timgb, c1w, c1b, h1b);
  mfma_conv<32, 64, 2><<<2048, 256, 0, stream>>>(h1b, pc2, c2b, h2b, 128, 128, 64, 64);
  mfma_conv<64, 128, 2><<<1024, 256, 0, stream>>>(h2b, pc3, c3b, h3b, 64, 64, 32, 32);
  mfma_conv<128, 256, 1><<<1024, 256, 0, stream>>>(h3b, pc4, c4b, h4b, 32, 32, 16, 16);

  // ---- enc_fc (fused transpose+GEMM) ----
  k_encfc_fused<<<2048, 256, 0, stream>>>(h4b, efw, ws + W_ENCP);
  k_encfc_red<<<128, 256, 0, stream>>>(ws + W_ENCP, efb, ws + W_CNN);

  // ---- fused posterior + reparam ----
  k_postz<<<64, 512, 0, stream>>>(ws + W_CNN, ws + W_BELIEF, pow_, pob, eps, out, zb);

  // ---- decoder ----
  k_decfc_mfma<<<256, 256, 0, stream>>>(zb, dfw, dfb, deco);
  mfma_deconv<128, 64, 1, true><<<1024, 256, 0, stream>>>(deco, pd1, d1b, d1o, 16, 16, 32, 32);
  mfma_deconv<64, 32, 1, true><<<2048, 256, 0, stream>>>(d1o, pd2, d2b, d2o, 32, 32, 64, 64);
  mfma_deconv<32, 16, 1, true><<<4096, 256, 0, stream>>>(d2o, pd3, d3b, d3o, 64, 64, 128, 128);
  k_d4t<<<1024, 256, 0, stream>>>(d3o, d4w, d4b, out + O_PRED);
}

// Round 9
// 525.816 us; speedup vs baseline: 1.1200x; 1.0521x over previous
//
#include <hip/hip_runtime.h>
#include <math.h>

#define BB 64
#define LATENT 256
#define ACTD 6
#define HIDD 512
#define DST 16

typedef __attribute__((ext_vector_type(8))) short bf16x8;
typedef __attribute__((ext_vector_type(4))) float f32x4;

static __device__ __forceinline__ ushort f2bf(float f) {
  unsigned u = __builtin_bit_cast(unsigned, f);
  unsigned r = (u + 0x7FFFu + ((u >> 16) & 1u)) >> 16;
  return (ushort)r;
}
static __device__ __forceinline__ float bf2f(ushort u) {
  return __builtin_bit_cast(float, ((unsigned)u) << 16);
}

// ---------------- output offsets (floats) ----------------
#define O_PRED   0
#define O_ZT     4194304
#define O_STATE  4210688
#define O_MUP    4734976
#define O_LVP    4751360
#define O_MUPO   4767744
#define O_LVPO   4784128

// ---------------- ws offsets (floats), lifetime-reused ----------------
#define W_BELIEF 67584u
#define W_CNN    100352u
#define W_ZB16   133120u      // 8192 u16
#define PW_C2    137216u      // 32768 u16
#define PW_C3    153600u      // 131072 u16
#define PW_C4    219136u      // 524288 u16
#define PW_D1    481280u      // 131072 u16
#define PW_D2    546816u      // 32768 u16
#define PW_D3    563200u      // 8192 u16
#define W_TIMG   602112u      // timg bf16, region reserved to 13185024
#define W_H1B    13185024u    // 33,554,432 u16 [dead after conv2]
#define W_H2B    29962240u    // 16,777,216 u16
#define W_H3B    38350848u    // 8,388,608 u16
#define W_H4B    42545152u    // 4,194,304 u16 (ends 44642304 f)
// transposed dense weights (f32), after H4B:
#define W_SIWT   44642304u    // 134,144 f
#define W_DWT    44776448u    // 262,144 f
#define W_PRWT   45038592u    // 262,144 f
#define W_POWT   45300736u    // 524,288 f (ends 45825024)
// reuse (regions dead by write time):
#define W_ENCP   602112u      // (TIMG region, dead after conv1)
#define W_DECO   8990720u     // (TIMG region)
#define W_D1O    10039296u    // (TIMG region)
#define W_D2O    13185024u    // (H1B)
#define W_D3O    17379328u    // (H1B)

#define ENC_KS 128

// ================= fused SSM chain: one block per batch, coalesced wT =================
__global__ __launch_bounds__(512) void k_ssm_all(
    const float* __restrict__ z_prev, const float* __restrict__ act,
    const float* __restrict__ siwT, const float* __restrict__ sib,
    const float* __restrict__ DwT, const float* __restrict__ Db,
    const float* __restrict__ Bw, const float* __restrict__ Cw,
    const float* __restrict__ Alog, const float* __restrict__ Dv,
    const float* __restrict__ st_prev, float* __restrict__ state_out,
    float* __restrict__ belief_out, const float* __restrict__ prwT,
    const float* __restrict__ prb, float* __restrict__ out) {
  __shared__ float zs[256];
  __shared__ float as_[8];
  __shared__ float si[512];
  __shared__ float bel[512];
  __shared__ float part[2][16][4];
  __shared__ float btct[2][16];
  int b = blockIdx.x;
  int h = threadIdx.x;
  if (h < 256) zs[h] = z_prev[(size_t)b * LATENT + h];
  if (h >= 256 && h < 256 + ACTD) as_[h - 256] = act[(size_t)b * ACTD + (h - 256)];
  __syncthreads();
  // ---- ssm_in (coalesced siwT[k*512+h]) ----
  {
    float acc = sib[h];
    #pragma unroll 8
    for (int k = 0; k < LATENT; ++k) acc += zs[k] * siwT[(size_t)k * 512 + h];
    #pragma unroll
    for (int k = 0; k < ACTD; ++k) acc += as_[k] * siwT[(size_t)(LATENT + k) * 512 + h];
    si[h] = acc / (1.f + expf(-acc));
  }
  __syncthreads();
  // ---- delta ----
  float d;
  {
    float acc = Db[h];
    #pragma unroll 8
    for (int k = 0; k < HIDD; ++k) acc += si[k] * DwT[(size_t)k * 512 + h];
    d = fmaxf(acc, 0.f) + log1pf(expf(-fabsf(acc)));
  }
  // ---- B_t / C_t partials (small) ----
  if (h < 128) {
    int half = h >> 6;
    int l = h & 63;
    int n = l & 15, p = l >> 4;
    const float* wr = (half ? Cw : Bw) + (size_t)n * HIDD + p * 128;
    const float* sr = si + p * 128;
    float acc = 0.f;
    #pragma unroll 4
    for (int k = 0; k < 128; k += 4) {
      float4 w4 = *(const float4*)(wr + k);
      acc += sr[k] * w4.x + sr[k+1] * w4.y + sr[k+2] * w4.z + sr[k+3] * w4.w;
    }
    part[half][n][p] = acc;
  }
  __syncthreads();
  if (h < 32) {
    int half = h >> 4, n = h & 15;
    btct[half][n] = part[half][n][0] + part[half][n][1] + part[half][n][2] + part[half][n][3];
  }
  __syncthreads();
  // ---- state + belief ----
  {
    float si_h = si[h];
    float belv = Dv[h] * si_h;
    const float* al = Alog + (size_t)h * DST;
    const float* sp = st_prev + ((size_t)b * 512 + h) * DST;
    float* so = state_out + ((size_t)b * 512 + h) * DST;
    #pragma unroll
    for (int n = 0; n < DST; ++n) {
      float A = -expf(al[n]);
      float st = expf(d * A) * sp[n] + d * btct[0][n] * si_h;
      so[n] = st;
      belv += st * btct[1][n];
    }
    bel[h] = belv;
    belief_out[(size_t)b * 512 + h] = belv;
  }
  __syncthreads();
  // ---- prior (coalesced prwT) ----
  {
    float acc = prb[h];
    #pragma unroll 8
    for (int k = 0; k < HIDD; ++k) acc += bel[k] * prwT[(size_t)k * 512 + h];
    if (h < 256) out[O_MUP + b * 256 + h] = acc;
    else         out[O_LVP + b * 256 + (h - 256)] = acc;
  }
}

// ================= merged weight prepack =================

static __device__ __forceinline__ void pack_conv_elem(const float* __restrict__ w,
                                                      ushort* __restrict__ o,
                                                      int Cout, int Cin, int id) {
  int NCH = Cin / 2;
  int per = NCH * 512;
  int mt = id / per, r = id % per;
  int kcg = r >> 9, s = r & 511;
  int kg = s >> 7, m = (s >> 3) & 15, k8 = s & 7;
  int co = mt * 16 + m;
  int k = kcg * 32 + kg * 8 + k8;
  int tap = k / Cin, ci = k % Cin;
  o[id] = f2bf(w[(size_t)(co * Cin + ci) * 16 + tap]);
}

static __device__ __forceinline__ void pack_deconv_elem(const float* __restrict__ w,
                                                        ushort* __restrict__ o,
                                                        int Cout, int Cin, int id) {
  int NCH = Cin / 8;
  int perM = NCH * 512;
  int perC = (Cout / 16) * perM;
  int cls = id / perC, r = id % perC;
  int mt = r / perM, r2 = r % perM;
  int kcg = r2 >> 9, s = r2 & 511;
  int kg = s >> 7, m = (s >> 3) & 15, k8 = s & 7;
  int co = mt * 16 + m;
  int k = kcg * 32 + kg * 8 + k8;
  int t = k / Cin, ci = k % Cin;
  int p = (cls >> 1) + 2 * (t >> 1);
  int q = (cls & 1) + 2 * (t & 1);
  o[id] = f2bf(w[(size_t)(ci * Cout + co) * 16 + p * 4 + q]);
}

__global__ __launch_bounds__(256) void k_pack_all(
    const float* __restrict__ c2w, const float* __restrict__ c3w,
    const float* __restrict__ c4w, const float* __restrict__ d1w,
    const float* __restrict__ d2w, const float* __restrict__ d3w,
    const float* __restrict__ siw, const float* __restrict__ Dw,
    const float* __restrict__ prw, const float* __restrict__ pw,
    ushort* __restrict__ pc2, ushort* __restrict__ pc3, ushort* __restrict__ pc4,
    ushort* __restrict__ pd1, ushort* __restrict__ pd2, ushort* __restrict__ pd3,
    float* __restrict__ siwT, float* __restrict__ DwT,
    float* __restrict__ prwT, float* __restrict__ powT) {
  int id = blockIdx.x * 256 + threadIdx.x;
  if (id < 32768)            pack_conv_elem(c2w, pc2, 64, 32, id);
  else if (id < 163840)      pack_conv_elem(c3w, pc3, 128, 64, id - 32768);
  else if (id < 688128)      pack_conv_elem(c4w, pc4, 256, 128, id - 163840);
  else if (id < 819200)      pack_deconv_elem(d1w, pd1, 64, 128, id - 688128);
  else if (id < 851968)      pack_deconv_elem(d2w, pd2, 32, 64, id - 819200);
  else if (id < 860160)      pack_deconv_elem(d3w, pd3, 16, 32, id - 851968);
  else if (id < 994304) {    // siwT [262][512]
    int r = id - 860160; int k = r >> 9, h = r & 511;
    siwT[r] = siw[(size_t)h * (LATENT + ACTD) + k];
  } else if (id < 1256448) { // DwT [512][512]
    int r = id - 994304; int k = r >> 9, h = r & 511;
    DwT[r] = Dw[(size_t)h * HIDD + k];
  } else if (id < 1518592) { // prwT [512][512]
    int r = id - 1256448; int k = r >> 9, h = r & 511;
    prwT[r] = prw[(size_t)h * HIDD + k];
  } else if (id < 2042880) { // powT [1024][512]
    int r = id - 1518592; int k = r >> 9, j = r & 511;
    powT[r] = pw[(size_t)j * 1024 + k];
  }
}

// ================= img transpose (bf16 out) =================
__global__ __launch_bounds__(256) void k_timg(const float* __restrict__ img,
                                              ushort* __restrict__ timg) {
  int blk = blockIdx.x;
  int c = blk >> 10, p0 = (blk & 1023) << 6;
  __shared__ float t[64 * 65];
  int tid = threadIdx.x;
  #pragma unroll
  for (int i = 0; i < 16; ++i) {
    int idx = tid + i * 256;
    int b = idx >> 6, pr = idx & 63;
    t[pr * 65 + b] = img[((size_t)b * 3 + c) * 65536 + p0 + pr];
  }
  __syncthreads();
  #pragma unroll
  for (int i = 0; i < 16; ++i) {
    int idx = tid + i * 256;
    int pr = idx >> 6, b = idx & 63;
    timg[((size_t)c * 65536 + p0 + pr) * 64 + b] = f2bf(t[pr * 65 + b]);
  }
}

// ================= conv1: direct (Cin=3), interior fast path =================
__global__ __launch_bounds__(256) void k_conv1(const ushort* __restrict__ in,
                                               const float* __restrict__ w,
                                               const float* __restrict__ bias,
                                               ushort* __restrict__ out) {
  int wid = __builtin_amdgcn_readfirstlane(blockIdx.x * 4 + (threadIdx.x >> 6));
  int lane = threadIdx.x & 63;
  int x4 = wid & 31; int t = wid >> 5;
  int oy = t & 127; int cg = t >> 7;
  int co0 = cg * 8;
  int ox0 = x4 << 2;
  int ixb = ox0 * 2 - 1;
  float acc[8][4];
  #pragma unroll
  for (int u = 0; u < 8; ++u) {
    float bv = bias[co0 + u];
    #pragma unroll
    for (int j = 0; j < 4; ++j) acc[u][j] = bv;
  }
  bool interior = (oy >= 1) & (oy < 127) & (x4 >= 1) & (x4 < 31);
  if (interior) {
    for (int ci = 0; ci < 3; ++ci) {
      const ushort* ip = in + ((size_t)ci * 65536) * 64 + lane;
      const float* wp = w + (size_t)co0 * 48 + ci * 16;
      #pragma unroll
      for (int ky = 0; ky < 4; ++ky) {
        int iy = oy * 2 - 1 + ky;
        const ushort* rp = ip + (size_t)iy * 256 * 64;
        float x[10];
        #pragma unroll
        for (int j = 0; j < 10; ++j) x[j] = bf2f(rp[(size_t)(ixb + j) * 64]);
        #pragma unroll
        for (int u = 0; u < 8; ++u) {
          const float* wq = wp + (size_t)u * 48 + ky * 4;
          float w0 = wq[0], w1 = wq[1], w2 = wq[2], w3 = wq[3];
          acc[u][0] += x[0]*w0 + x[1]*w1 + x[2]*w2 + x[3]*w3;
          acc[u][1] += x[2]*w0 + x[3]*w1 + x[4]*w2 + x[5]*w3;
          acc[u][2] += x[4]*w0 + x[5]*w1 + x[6]*w2 + x[7]*w3;
          acc[u][3] += x[6]*w0 + x[7]*w1 + x[8]*w2 + x[9]*w3;
        }
      }
    }
  } else {
    for (int ci = 0; ci < 3; ++ci) {
      const ushort* ip = in + ((size_t)ci * 65536) * 64 + lane;
      const float* wp = w + (size_t)co0 * 48 + ci * 16;
      #pragma unroll
      for (int ky = 0; ky < 4; ++ky) {
        int iy = oy * 2 - 1 + ky;
        if ((unsigned)iy >= 256u) continue;
        const ushort* rp = ip + (size_t)iy * 256 * 64;
        float x[10];
        #pragma unroll
        for (int j = 0; j < 10; ++j) {
          int ix = ixb + j;
          x[j] = ((unsigned)ix < 256u) ? bf2f(rp[(size_t)ix * 64]) : 0.f;
        }
        #pragma unroll
        for (int u = 0; u < 8; ++u) {
          const float* wq = wp + (size_t)u * 48 + ky * 4;
          float w0 = wq[0], w1 = wq[1], w2 = wq[2], w3 = wq[3];
          acc[u][0] += x[0]*w0 + x[1]*w1 + x[2]*w2 + x[3]*w3;
          acc[u][1] += x[2]*w0 + x[3]*w1 + x[4]*w2 + x[5]*w3;
          acc[u][2] += x[4]*w0 + x[5]*w1 + x[6]*w2 + x[7]*w3;
          acc[u][3] += x[6]*w0 + x[7]*w1 + x[8]*w2 + x[9]*w3;
        }
      }
    }
  }
  #pragma unroll
  for (int j = 0; j < 4; ++j) {
    int px = oy * 128 + ox0 + j;
    size_t off = (size_t)px * 2048 + (size_t)(lane >> 4) * 512 + cg * 128 + (lane & 15) * 8;
    ushort tmp[8];
    #pragma unroll
    for (int u = 0; u < 8; ++u) tmp[u] = f2bf(fmaxf(acc[u][j], 0.f));
    uint4 pk;
    pk.x = tmp[0] | ((unsigned)tmp[1] << 16);
    pk.y = tmp[2] | ((unsigned)tmp[3] << 16);
    pk.z = tmp[4] | ((unsigned)tmp[5] << 16);
    pk.w = tmp[6] | ((unsigned)tmp[7] << 16);
    *(uint4*)(out + off) = pk;
  }
}

// ================= MFMA conv, interior fast path =================
template<int CIN, int COUT, int MT>
__global__ __launch_bounds__(256) void mfma_conv(const ushort* __restrict__ in,
                                                 const ushort* __restrict__ wp,
                                                 const float* __restrict__ bias,
                                                 ushort* __restrict__ out,
                                                 int Hin, int Win, int Hout, int Wout) {
  constexpr int NMG = COUT / (16 * MT);
  constexpr int NKC = CIN / 32;
  constexpr int NCH = 16 * NKC;
  int wid = __builtin_amdgcn_readfirstlane(blockIdx.x * 4 + (threadIdx.x >> 6));
  int lane = threadIdx.x & 63;
  int mg = wid % NMG;
  int px = wid / NMG;
  int ox = px % Wout, oy = px / Wout;
  if (oy >= Hout) return;
  int mtile0 = mg * MT;
  f32x4 zero = {0.f, 0.f, 0.f, 0.f};
  f32x4 acc[MT][4];
  #pragma unroll
  for (int mt = 0; mt < MT; ++mt)
    #pragma unroll
    for (int nt = 0; nt < 4; ++nt) acc[mt][nt] = zero;
  const ushort* wbase = wp + (size_t)mtile0 * NCH * 512 + lane * 8;
  const size_t mstride = (size_t)NCH * 512;
  bool interior = (oy >= 1) & (oy < Hout - 1) & (ox >= 1) & (ox < Wout - 1);

  if (interior) {
    #pragma unroll
    for (int ky = 0; ky < 4; ++ky) {
      int iy = 2 * oy - 1 + ky;
      #pragma unroll
      for (int kx = 0; kx < 4; ++kx) {
        int ix = 2 * ox - 1 + kx;
        const ushort* ib = in + (size_t)(iy * Win + ix) * (CIN * 64) + lane * 8;
        int tap = ky * 4 + kx;
        #pragma unroll
        for (int kc = 0; kc < NKC; ++kc) {
          int kcg = tap * NKC + kc;
          bf16x8 a[MT], bb[4];
          #pragma unroll
          for (int mt = 0; mt < MT; ++mt)
            a[mt] = *(const bf16x8*)(wbase + mt * mstride + (size_t)kcg * 512);
          #pragma unroll
          for (int nt = 0; nt < 4; ++nt)
            bb[nt] = *(const bf16x8*)(ib + kc * 2048 + nt * 512);
          #pragma unroll
          for (int mt = 0; mt < MT; ++mt)
            #pragma unroll
            for (int nt = 0; nt < 4; ++nt)
              acc[mt][nt] = __builtin_amdgcn_mfma_f32_16x16x32_bf16(a[mt], bb[nt], acc[mt][nt], 0, 0, 0);
        }
      }
    }
  } else {
    for (int ky = 0; ky < 4; ++ky) {
      int iy = 2 * oy - 1 + ky;
      if ((unsigned)iy >= (unsigned)Hin) continue;
      for (int kx = 0; kx < 4; ++kx) {
        int ix = 2 * ox - 1 + kx;
        if ((unsigned)ix >= (unsigned)Win) continue;
        const ushort* ib = in + (size_t)(iy * Win + ix) * (CIN * 64) + lane * 8;
        int tap = ky * 4 + kx;
        #pragma unroll
        for (int kc = 0; kc < NKC; ++kc) {
          int kcg = tap * NKC + kc;
          bf16x8 a[MT], bb[4];
          #pragma unroll
          for (int mt = 0; mt < MT; ++mt)
            a[mt] = *(const bf16x8*)(wbase + mt * mstride + (size_t)kcg * 512);
          #pragma unroll
          for (int nt = 0; nt < 4; ++nt)
            bb[nt] = *(const bf16x8*)(ib + kc * 2048 + nt * 512);
          #pragma unroll
          for (int mt = 0; mt < MT; ++mt)
            #pragma unroll
            for (int nt = 0; nt < 4; ++nt)
              acc[mt][nt] = __builtin_amdgcn_mfma_f32_16x16x32_bf16(a[mt], bb[nt], acc[mt][nt], 0, 0, 0);
        }
      }
    }
  }
  int ml = lane & 15, rb = (lane >> 4) * 4;
  #pragma unroll
  for (int mt = 0; mt < MT; ++mt) {
    int co = mtile0 * 16 + mt * 16 + rb;
    f32x4 bv = *(const f32x4*)(bias + co);
    #pragma unroll
    for (int nt = 0; nt < 4; ++nt) {
      float v0 = fmaxf(acc[mt][nt][0] + bv[0], 0.f);
      float v1 = fmaxf(acc[mt][nt][1] + bv[1], 0.f);
      float v2 = fmaxf(acc[mt][nt][2] + bv[2], 0.f);
      float v3 = fmaxf(acc[mt][nt][3] + bv[3], 0.f);
      uint2 pk;
      pk.x = (unsigned)f2bf(v0) | ((unsigned)f2bf(v1) << 16);
      pk.y = (unsigned)f2bf(v2) | ((unsigned)f2bf(v3) << 16);
      size_t off = (size_t)px * (COUT * 64) + (size_t)(co >> 5) * 2048 + nt * 512
                 + ((co >> 3) & 3) * 128 + ml * 8 + (co & 7);
      *(uint2*)(out + off) = pk;
    }
  }
}

// ================= MFMA transposed conv, interior fast path =================
template<int CIN, int COUT, int MT, bool RELU>
__global__ __launch_bounds__(256) void mfma_deconv(const ushort* __restrict__ in,
                                                   const ushort* __restrict__ wp,
                                                   const float* __restrict__ bias,
                                                   ushort* __restrict__ out,
                                                   int Hin, int Win, int Hout, int Wout) {
  constexpr int NMG = COUT / (16 * MT);
  constexpr int NKC = CIN / 32;
  constexpr int NCH = 4 * NKC;
  constexpr int NTS = (COUT >= 32) ? 512 : (COUT * 16);
  int wid = __builtin_amdgcn_readfirstlane(blockIdx.x * 4 + (threadIdx.x >> 6));
  int lane = threadIdx.x & 63;
  int mg = wid % NMG; int r1 = wid / NMG;
  int wo2 = Wout >> 1;
  int pc = (Hout >> 1) * wo2;
  int pxc = r1 % pc; int cls = r1 / pc;
  if (cls >= 4) return;
  int p0 = cls >> 1, q0 = cls & 1;
  int tx = pxc % wo2, ty = pxc / wo2;
  int oy = 2 * ty + 1 - p0, ox = 2 * tx + 1 - q0;
  int iy0 = (oy + 1 - p0) >> 1, ix0 = (ox + 1 - q0) >> 1;
  int mtile0 = mg * MT;
  f32x4 zero = {0.f, 0.f, 0.f, 0.f};
  f32x4 acc[MT][4];
  #pragma unroll
  for (int mt = 0; mt < MT; ++mt)
    #pragma unroll
    for (int nt = 0; nt < 4; ++nt) acc[mt][nt] = zero;
  const ushort* wbase = wp + ((size_t)cls * (COUT / 16) + mtile0) * NCH * 512 + lane * 8;
  const size_t mstride = (size_t)NCH * 512;
  bool interior = (iy0 >= 1) & (iy0 <= Hin - 1) & (ix0 >= 1) & (ix0 <= Win - 1);

  if (interior) {
    #pragma unroll
    for (int i = 0; i < 2; ++i) {
      int iy = iy0 - i;
      #pragma unroll
      for (int j = 0; j < 2; ++j) {
        int ix = ix0 - j;
        const ushort* ib = in + (size_t)(iy * Win + ix) * (CIN * 64) + lane * 8;
        int tap = i * 2 + j;
        #pragma unroll
        for (int kc = 0; kc < NKC; ++kc) {
          int kcg = tap * NKC + kc;
          bf16x8 a[MT], bb[4];
          #pragma unroll
          for (int mt = 0; mt < MT; ++mt)
            a[mt] = *(const bf16x8*)(wbase + mt * mstride + (size_t)kcg * 512);
          #pragma unroll
          for (int nt = 0; nt < 4; ++nt)
            bb[nt] = *(const bf16x8*)(ib + kc * 2048 + nt * 512);
          #pragma unroll
          for (int mt = 0; mt < MT; ++mt)
            #pragma unroll
            for (int nt = 0; nt < 4; ++nt)
              acc[mt][nt] = __builtin_amdgcn_mfma_f32_16x16x32_bf16(a[mt], bb[nt], acc[mt][nt], 0, 0, 0);
        }
      }
    }
  } else {
    for (int i = 0; i < 2; ++i) {
      int iy = iy0 - i;
      if ((unsigned)iy >= (unsigned)Hin) continue;
      for (int j = 0; j < 2; ++j) {
        int ix = ix0 - j;
        if ((unsigned)ix >= (unsigned)Win) continue;
        const ushort* ib = in + (size_t)(iy * Win + ix) * (CIN * 64) + lane * 8;
        int tap = i * 2 + j;
        #pragma unroll
        for (int kc = 0; kc < NKC; ++kc) {
          int kcg = tap * NKC + kc;
          bf16x8 a[MT], bb[4];
          #pragma unroll
          for (int mt = 0; mt < MT; ++mt)
            a[mt] = *(const bf16x8*)(wbase + mt * mstride + (size_t)kcg * 512);
          #pragma unroll
          for (int nt = 0; nt < 4; ++nt)
            bb[nt] = *(const bf16x8*)(ib + kc * 2048 + nt * 512);
          #pragma unroll
          for (int mt = 0; mt < MT; ++mt)
            #pragma unroll
            for (int nt = 0; nt < 4; ++nt)
              acc[mt][nt] = __builtin_amdgcn_mfma_f32_16x16x32_bf16(a[mt], bb[nt], acc[mt][nt], 0, 0, 0);
        }
      }
    }
  }
  int ml = lane & 15, rb = (lane >> 4) * 4;
  int px = oy * Wout + ox;
  #pragma unroll
  for (int mt = 0; mt < MT; ++mt) {
    int co = mtile0 * 16 + mt * 16 + rb;
    f32x4 bv = *(const f32x4*)(bias + co);
    #pragma unroll
    for (int nt = 0; nt < 4; ++nt) {
      float v0 = acc[mt][nt][0] + bv[0];
      float v1 = acc[mt][nt][1] + bv[1];
      float v2 = acc[mt][nt][2] + bv[2];
      float v3 = acc[mt][nt][3] + bv[3];
      if (RELU) { v0=fmaxf(v0,0.f); v1=fmaxf(v1,0.f); v2=fmaxf(v2,0.f); v3=fmaxf(v3,0.f); }
      uint2 pk;
      pk.x = (unsigned)f2bf(v0) | ((unsigned)f2bf(v1) << 16);
      pk.y = (unsigned)f2bf(v2) | ((unsigned)f2bf(v3) << 16);
      size_t off = (size_t)px * (COUT * 64) + (size_t)(co >> 5) * 2048 + (size_t)nt * NTS
                 + ((co >> 3) & 3) * 128 + ml * 8 + (co & 7);
      *(uint2*)(out + off) = pk;
    }
  }
}

// ================= enc_fc fused: LDS-transpose staging + MFMA =================
#define APXS 1032
__global__ __launch_bounds__(256) void k_encfc_fused(const ushort* __restrict__ h4,
                                                     const float* __restrict__ wE,
                                                     float* __restrict__ partial) {
  __shared__ float smem[8320];
  ushort* au = (ushort*)smem;
  int s = blockIdx.x;
  int bid = (s & 7) * 256 + (s >> 3);
  int mg = bid & 15;
  int ccf = (bid >> 4) & 7;
  int pxg = bid >> 7;
  int tid = threadIdx.x;
  int co0 = mg * 32;
  #pragma unroll 4
  for (int i = 0; i < 64; ++i) {
    int idx = tid + i * 256;
    int px_l = idx & 15;
    int ci_l = (idx >> 4) & 31;
    int co_l = idx >> 9;
    float v = wE[((size_t)(co0 + co_l) << 16) + (size_t)(ccf * 32 + ci_l) * 256 + pxg * 16 + px_l];
    int mt = co_l >> 4, m = co_l & 15;
    int kg = ci_l >> 3, k8 = ci_l & 7;
    au[px_l * APXS + mt * 512 + kg * 128 + m * 8 + k8] = f2bf(v);
  }
  __syncthreads();
  int lane = tid & 63, wv = tid >> 6;
  int ml = lane & 15, rb = (lane >> 4) * 4;
  f32x4 zero = {0.f, 0.f, 0.f, 0.f};
  f32x4 acc[2][4];
  #pragma unroll
  for (int mt = 0; mt < 2; ++mt)
    #pragma unroll
    for (int nt = 0; nt < 4; ++nt) acc[mt][nt] = zero;
  #pragma unroll
  for (int jj = 0; jj < 4; ++jj) {
    int j = wv * 4 + jj;
    int px = pxg * 16 + j;
    bf16x8 a0 = *(const bf16x8*)(au + j * APXS + lane * 8);
    bf16x8 a1 = *(const bf16x8*)(au + j * APXS + 512 + lane * 8);
    const ushort* hb = h4 + (size_t)px * 16384 + ccf * 2048 + lane * 8;
    bf16x8 bb[4];
    #pragma unroll
    for (int nt = 0; nt < 4; ++nt)
      bb[nt] = *(const bf16x8*)(hb + nt * 512);
    #pragma unroll
    for (int nt = 0; nt < 4; ++nt) {
      acc[0][nt] = __builtin_amdgcn_mfma_f32_16x16x32_bf16(a0, bb[nt], acc[0][nt], 0, 0, 0);
      acc[1][nt] = __builtin_amdgcn_mfma_f32_16x16x32_bf16(a1, bb[nt], acc[1][nt], 0, 0, 0);
    }
  }
  __syncthreads();
  #pragma unroll
  for (int mt = 0; mt < 2; ++mt)
    #pragma unroll
    for (int nt = 0; nt < 4; ++nt)
      #pragma unroll
      for (int r = 0; r < 4; ++r)
        smem[wv * 2080 + (mt * 16 + rb + r) * 65 + nt * 16 + ml] = acc[mt][nt][r];
  __syncthreads();
  int ks = pxg * 8 + ccf;
  #pragma unroll
  for (int i = 0; i < 8; ++i) {
    int e = tid + i * 256;
    int b = e & 63, co_l = e >> 6;
    float sum = smem[co_l * 65 + b] + smem[2080 + co_l * 65 + b]
              + smem[4160 + co_l * 65 + b] + smem[6240 + co_l * 65 + b];
    partial[((size_t)(co0 + co_l) * ENC_KS + ks) * 64 + b] = sum;
  }
}

__global__ void k_encfc_red(const float* __restrict__ partial, const float* __restrict__ bias,
                            float* __restrict__ cnn) {
  int id = blockIdx.x * blockDim.x + threadIdx.x;
  int o = id >> 6, b = id & 63;
  float acc = bias[o];
  #pragma unroll 8
  for (int s = 0; s < ENC_KS; ++s) acc += partial[((size_t)o * ENC_KS + s) * 64 + b];
  cnn[(size_t)b * 512 + o] = fmaxf(acc, 0.f);
}

// ================= fused posterior + reparam (coalesced powT) =================
__global__ __launch_bounds__(512) void k_postz(const float* __restrict__ cnn,
                                               const float* __restrict__ belief,
                                               const float* __restrict__ powT,
                                               const float* __restrict__ bias,
                                               const float* __restrict__ eps,
                                               float* __restrict__ out,
                                               ushort* __restrict__ zb) {
  __shared__ float cs[512];
  __shared__ float bs[512];
  __shared__ float sm[512];
  int b = blockIdx.x;
  int j = threadIdx.x;
  cs[j] = cnn[(size_t)b * HIDD + j];
  bs[j] = belief[(size_t)b * HIDD + j];
  __syncthreads();
  float acc = bias[j];
  #pragma unroll 8
  for (int k = 0; k < HIDD; ++k) acc += cs[k] * powT[(size_t)k * 512 + j];
  #pragma unroll 8
  for (int k = 0; k < HIDD; ++k) acc += bs[k] * powT[(size_t)(512 + k) * 512 + j];
  sm[j] = acc;
  if (j < 256) out[O_MUPO + b * 256 + j] = acc;
  else         out[O_LVPO + b * 256 + (j - 256)] = acc;
  __syncthreads();
  if (j < 256) {
    float z = sm[j] + eps[b * 256 + j] * expf(0.5f * sm[j + 256]);
    out[O_ZT + b * 256 + j] = z;
    if (j < 128) zb[b * 128 + j] = f2bf(z);
  }
}

// ================= dec_fc MFMA: direct f32 weights, frag-order out =================
__global__ __launch_bounds__(256) void k_decfc_mfma(const ushort* __restrict__ zb,
                                                    const float* __restrict__ dfw,
                                                    const float* __restrict__ dfb,
                                                    ushort* __restrict__ dec) {
  int wid = __builtin_amdgcn_readfirstlane(blockIdx.x * 4 + (threadIdx.x >> 6));
  int lane = threadIdx.x & 63;
  int m0 = wid * 32;
  int ml = lane & 15, kl = (lane >> 4) * 8;
  f32x4 zero = {0.f, 0.f, 0.f, 0.f};
  f32x4 acc[2][4];
  #pragma unroll
  for (int mt = 0; mt < 2; ++mt)
    #pragma unroll
    for (int nt = 0; nt < 4; ++nt) acc[mt][nt] = zero;
  #pragma unroll
  for (int kc = 0; kc < 4; ++kc) {
    bf16x8 a[2], bb[4];
    #pragma unroll
    for (int mt = 0; mt < 2; ++mt) {
      int m_r = m0 + mt * 16 + ml;
      const float* wr = dfw + (size_t)((m_r & 127) * 256 + (m_r >> 7)) * 128 + kc * 32 + kl;
      float4 u0 = *(const float4*)wr;
      float4 u1 = *(const float4*)(wr + 4);
      bf16x8 av;
      av[0] = (short)f2bf(u0.x); av[1] = (short)f2bf(u0.y);
      av[2] = (short)f2bf(u0.z); av[3] = (short)f2bf(u0.w);
      av[4] = (short)f2bf(u1.x); av[5] = (short)f2bf(u1.y);
      av[6] = (short)f2bf(u1.z); av[7] = (short)f2bf(u1.w);
      a[mt] = av;
    }
    #pragma unroll
    for (int nt = 0; nt < 4; ++nt)
      bb[nt] = *(const bf16x8*)(zb + (size_t)(nt * 16 + ml) * 128 + kc * 32 + kl);
    #pragma unroll
    for (int mt = 0; mt < 2; ++mt)
      #pragma unroll
      for (int nt = 0; nt < 4; ++nt)
        acc[mt][nt] = __builtin_amdgcn_mfma_f32_16x16x32_bf16(a[mt], bb[nt], acc[mt][nt], 0, 0, 0);
  }
  int rb = (lane >> 4) * 4;
  #pragma unroll
  for (int mt = 0; mt < 2; ++mt) {
    int m = m0 + mt * 16 + rb;
    int pix = m >> 7, co = m & 127;
    float bv0 = dfb[(size_t)(co + 0) * 256 + pix];
    float bv1 = dfb[(size_t)(co + 1) * 256 + pix];
    float bv2 = dfb[(size_t)(co + 2) * 256 + pix];
    float bv3 = dfb[(size_t)(co + 3) * 256 + pix];
    #pragma unroll
    for (int nt = 0; nt < 4; ++nt) {
      uint2 pk;
      pk.x = (unsigned)f2bf(acc[mt][nt][0] + bv0) | ((unsigned)f2bf(acc[mt][nt][1] + bv1) << 16);
      pk.y = (unsigned)f2bf(acc[mt][nt][2] + bv2) | ((unsigned)f2bf(acc[mt][nt][3] + bv3) << 16);
      size_t off = (size_t)pix * 8192 + (size_t)(co >> 5) * 2048 + nt * 512
                 + ((co >> 3) & 3) * 128 + ml * 8 + (co & 7);
      *(uint2*)(dec + off) = pk;
    }
  }
}

// ================= d4 fused with output transpose =================
__global__ __launch_bounds__(256) void k_d4t(const ushort* __restrict__ in,
                                             const float* __restrict__ w,
                                             const float* __restrict__ bias,
                                             float* __restrict__ out) {
  __shared__ float lds[64][65];
  int blk = blockIdx.x;
  int oy = blk >> 2, ox0 = (blk & 3) << 6;
  int t = threadIdx.x;
  int b = t & 63, sub = t >> 6;
  float bv = bias[0];
  for (int j = 0; j < 16; ++j) {
    int oxl = j * 4 + sub;
    int ox = ox0 + oxl;
    int p0 = (oy + 1) & 1, q0 = (ox + 1) & 1;
    int iy0 = (oy + 1 - p0) >> 1, ix0 = (ox + 1 - q0) >> 1;
    float acc = bv;
    #pragma unroll
    for (int i = 0; i < 2; ++i) {
      int iy = iy0 - i;
      if ((unsigned)iy >= 128u) continue;
      int p = p0 + 2 * i;
      #pragma unroll
      for (int jj = 0; jj < 2; ++jj) {
        int ix = ix0 - jj;
        if ((unsigned)ix >= 128u) continue;
        int q = q0 + 2 * jj;
        const ushort* base = in + (size_t)(iy * 128 + ix) * 1024 + (b >> 4) * 256 + (b & 15) * 8;
        bf16x8 v0 = *(const bf16x8*)(base);
        bf16x8 v1 = *(const bf16x8*)(base + 128);
        const float* wq = w + p * 4 + q;
        #pragma unroll
        for (int ci = 0; ci < 8; ++ci) acc += bf2f((ushort)v0[ci]) * wq[ci * 16];
        #pragma unroll
        for (int ci = 0; ci < 8; ++ci) acc += bf2f((ushort)v1[ci]) * wq[(ci + 8) * 16];
      }
    }
    lds[oxl][b] = acc;
  }
  __syncthreads();
  #pragma unroll
  for (int j = 0; j < 16; ++j) {
    int idx = t + j * 256;
    int b2 = idx >> 6, oxl = idx & 63;
    out[(size_t)b2 * 65536 + oy * 256 + ox0 + oxl] = lds[oxl][b2];
  }
}

// ================= launch =================

extern "C" void kernel_launch(void* const* d_in, const int* in_sizes, int n_in,
                              void* d_out, int out_size, void* d_ws, size_t ws_size,
                              hipStream_t stream) {
  const float* img      = (const float*)d_in[0];
  const float* act      = (const float*)d_in[1];
  const float* z_prev   = (const float*)d_in[2];
  const float* st_prev  = (const float*)d_in[3];
  const float* eps      = (const float*)d_in[4];
  const float* c1w = (const float*)d_in[5];  const float* c1b = (const float*)d_in[6];
  const float* c2w = (const float*)d_in[7];  const float* c2b = (const float*)d_in[8];
  const float* c3w = (const float*)d_in[9];  const float* c3b = (const float*)d_in[10];
  const float* c4w = (const float*)d_in[11]; const float* c4b = (const float*)d_in[12];
  const float* efw = (const float*)d_in[13]; const float* efb = (const float*)d_in[14];
  const float* pow_ = (const float*)d_in[15]; const float* pob = (const float*)d_in[16];
  const float* prw = (const float*)d_in[17]; const float* prb = (const float*)d_in[18];
  const float* siw = (const float*)d_in[19]; const float* sib = (const float*)d_in[20];
  const float* Alog = (const float*)d_in[21];
  const float* Bw = (const float*)d_in[22];  const float* Cw = (const float*)d_in[23];
  const float* Dw = (const float*)d_in[24];  const float* Db = (const float*)d_in[25];
  const float* Dv = (const float*)d_in[26];
  const float* dfw = (const float*)d_in[27]; const float* dfb = (const float*)d_in[28];
  const float* d1w = (const float*)d_in[29]; const float* d1b = (const float*)d_in[30];
  const float* d2w = (const float*)d_in[31]; const float* d2b = (const float*)d_in[32];
  const float* d3w = (const float*)d_in[33]; const float* d3b = (const float*)d_in[34];
  const float* d4w = (const float*)d_in[35]; const float* d4b = (const float*)d_in[36];

  float* ws = (float*)d_ws;
  float* out = (float*)d_out;

  ushort* pc2 = (ushort*)(ws + PW_C2);
  ushort* pc3 = (ushort*)(ws + PW_C3);
  ushort* pc4 = (ushort*)(ws + PW_C4);
  ushort* pd1 = (ushort*)(ws + PW_D1);
  ushort* pd2 = (ushort*)(ws + PW_D2);
  ushort* pd3 = (ushort*)(ws + PW_D3);
  ushort* timgb = (ushort*)(ws + W_TIMG);
  ushort* h1b = (ushort*)(ws + W_H1B);
  ushort* h2b = (ushort*)(ws + W_H2B);
  ushort* h3b = (ushort*)(ws + W_H3B);
  ushort* h4b = (ushort*)(ws + W_H4B);
  ushort* deco = (ushort*)(ws + W_DECO);
  ushort* d1o = (ushort*)(ws + W_D1O);
  ushort* d2o = (ushort*)(ws + W_D2O);
  ushort* d3o = (ushort*)(ws + W_D3O);
  ushort* zb = (ushort*)(ws + W_ZB16);
  float* siwT = ws + W_SIWT;
  float* DwT  = ws + W_DWT;
  float* prwT = ws + W_PRWT;
  float* powT = ws + W_POWT;

  // ---- merged weight prepack (+ dense transposes) ----
  k_pack_all<<<7980, 256, 0, stream>>>(c2w, c3w, c4w, d1w, d2w, d3w,
                                       siw, Dw, prw, pow_,
                                       pc2, pc3, pc4, pd1, pd2, pd3,
                                       siwT, DwT, prwT, powT);

  // ---- fused SSM chain (coalesced) ----
  k_ssm_all<<<64, 512, 0, stream>>>(z_prev, act, siwT, sib, DwT, Db, Bw, Cw,
                                    Alog, Dv, st_prev, out + O_STATE,
                                    ws + W_BELIEF, prwT, prb, out);

  // ---- encoder ----
  k_timg<<<3072, 256, 0, stream>>>(img, timgb);
  k_conv1<<<4096, 256, 0, stream>>>(timgb, c1w, c1b, h1b);
  mfma_conv<32, 64, 2><<<2048, 256, 0, stream>>>(h1b, pc2, c2b, h2b, 128, 128, 64, 64);
  mfma_conv<64, 128, 2><<<1024, 256, 0, stream>>>(h2b, pc3, c3b, h3b, 64, 64, 32, 32);
  mfma_conv<128, 256, 1><<<1024, 256, 0, stream>>>(h3b, pc4, c4b, h4b, 32, 32, 16, 16);

  // ---- enc_fc (fused transpose+GEMM) ----
  k_encfc_fused<<<2048, 256, 0, stream>>>(h4b, efw, ws + W_ENCP);
  k_encfc_red<<<128, 256, 0, stream>>>(ws + W_ENCP, efb, ws + W_CNN);

  // ---- fused posterior + reparam ----
  k_postz<<<64, 512, 0, stream>>>(ws + W_CNN, ws + W_BELIEF, powT, pob, eps, out, zb);

  // ---- decoder ----
  k_decfc_mfma<<<256, 256, 0, stream>>>(zb, dfw, dfb, deco);
  mfma_deconv<128, 64, 1, true><<<1024, 256, 0, stream>>>(deco, pd1, d1b, d1o, 16, 16, 32, 32);
  mfma_deconv<64, 32, 1, true><<<2048, 256, 0, stream>>>(d1o, pd2, d2b, d2o, 32, 32, 64, 64);
  mfma_deconv<32, 16, 1, true><<<4096, 256, 0, stream>>>(d2o, pd3, d3b, d3o, 64, 64, 128, 128);
  k_d4t<<<1024, 256, 0, stream>>>(d3o, d4w, d4b, out + O_PRED);
}

// Round 10
// 468.341 us; speedup vs baseline: 1.2574x; 1.1227x over previous
//
#include <hip/hip_runtime.h>
#include <math.h>

#define BB 64
#define LATENT 256
#define ACTD 6
#define HIDD 512
#define DST 16

typedef __attribute__((ext_vector_type(8))) short bf16x8;
typedef __attribute__((ext_vector_type(4))) float f32x4;

static __device__ __forceinline__ ushort f2bf(float f) {
  unsigned u = __builtin_bit_cast(unsigned, f);
  unsigned r = (u + 0x7FFFu + ((u >> 16) & 1u)) >> 16;
  return (ushort)r;
}
static __device__ __forceinline__ float bf2f(ushort u) {
  return __builtin_bit_cast(float, ((unsigned)u) << 16);
}

// ---------------- output offsets (floats) ----------------
#define O_PRED   0
#define O_ZT     4194304
#define O_STATE  4210688
#define O_MUP    4734976
#define O_LVP    4751360
#define O_MUPO   4767744
#define O_LVPO   4784128

// ---------------- ws offsets (floats), lifetime-reused ----------------
#define W_BELIEF 67584u
#define W_CNN    100352u
#define W_ZB16   133120u      // 8192 u16
#define PW_C2    137216u      // 32768 u16
#define PW_C3    153600u      // 131072 u16
#define PW_C4    219136u      // 524288 u16
#define PW_D1    481280u      // 131072 u16
#define PW_D2    546816u      // 32768 u16
#define PW_D3    563200u      // 8192 u16
#define PW_C1    567296u      // 2048 u16
#define W_TIMG   602112u      // timg4 bf16 [65536][64][4] = 16,777,216 u16 (ends 8990720 f)
#define W_H1B    13185024u    // 33,554,432 u16 [dead after conv2]
#define W_H2B    29962240u    // 16,777,216 u16
#define W_H3B    38350848u    // 8,388,608 u16
#define W_H4B    42545152u    // 4,194,304 u16 (ends 44642304 f)
// transposed dense weights (f32), after H4B:
#define W_SIWT   44642304u    // 134,144 f
#define W_DWT    44776448u    // 262,144 f
#define W_PRWT   45038592u    // 262,144 f
#define W_POWT   45300736u    // 524,288 f (ends 45825024)
// reuse (regions dead by write time):
#define W_ENCP   602112u      // (TIMG region, dead after conv1)
#define W_DECO   8990720u     // (TIMG region, after timg4 end)
#define W_D1O    10039296u    // (TIMG region)
#define W_D2O    13185024u    // (H1B)
#define W_D3O    17379328u    // (H1B)

#define ENC_KS 128

// ================= fused SSM chain: one block per batch, coalesced wT =================
__global__ __launch_bounds__(512) void k_ssm_all(
    const float* __restrict__ z_prev, const float* __restrict__ act,
    const float* __restrict__ siwT, const float* __restrict__ sib,
    const float* __restrict__ DwT, const float* __restrict__ Db,
    const float* __restrict__ Bw, const float* __restrict__ Cw,
    const float* __restrict__ Alog, const float* __restrict__ Dv,
    const float* __restrict__ st_prev, float* __restrict__ state_out,
    float* __restrict__ belief_out, const float* __restrict__ prwT,
    const float* __restrict__ prb, float* __restrict__ out) {
  __shared__ float zs[256];
  __shared__ float as_[8];
  __shared__ float si[512];
  __shared__ float bel[512];
  __shared__ float part[2][16][4];
  __shared__ float btct[2][16];
  int b = blockIdx.x;
  int h = threadIdx.x;
  if (h < 256) zs[h] = z_prev[(size_t)b * LATENT + h];
  if (h >= 256 && h < 256 + ACTD) as_[h - 256] = act[(size_t)b * ACTD + (h - 256)];
  __syncthreads();
  {
    float acc = sib[h];
    #pragma unroll 8
    for (int k = 0; k < LATENT; ++k) acc += zs[k] * siwT[(size_t)k * 512 + h];
    #pragma unroll
    for (int k = 0; k < ACTD; ++k) acc += as_[k] * siwT[(size_t)(LATENT + k) * 512 + h];
    si[h] = acc / (1.f + expf(-acc));
  }
  __syncthreads();
  float d;
  {
    float acc = Db[h];
    #pragma unroll 8
    for (int k = 0; k < HIDD; ++k) acc += si[k] * DwT[(size_t)k * 512 + h];
    d = fmaxf(acc, 0.f) + log1pf(expf(-fabsf(acc)));
  }
  if (h < 128) {
    int half = h >> 6;
    int l = h & 63;
    int n = l & 15, p = l >> 4;
    const float* wr = (half ? Cw : Bw) + (size_t)n * HIDD + p * 128;
    const float* sr = si + p * 128;
    float acc = 0.f;
    #pragma unroll 4
    for (int k = 0; k < 128; k += 4) {
      float4 w4 = *(const float4*)(wr + k);
      acc += sr[k] * w4.x + sr[k+1] * w4.y + sr[k+2] * w4.z + sr[k+3] * w4.w;
    }
    part[half][n][p] = acc;
  }
  __syncthreads();
  if (h < 32) {
    int half = h >> 4, n = h & 15;
    btct[half][n] = part[half][n][0] + part[half][n][1] + part[half][n][2] + part[half][n][3];
  }
  __syncthreads();
  {
    float si_h = si[h];
    float belv = Dv[h] * si_h;
    const float* al = Alog + (size_t)h * DST;
    const float* sp = st_prev + ((size_t)b * 512 + h) * DST;
    float* so = state_out + ((size_t)b * 512 + h) * DST;
    #pragma unroll
    for (int n = 0; n < DST; ++n) {
      float A = -expf(al[n]);
      float st = expf(d * A) * sp[n] + d * btct[0][n] * si_h;
      so[n] = st;
      belv += st * btct[1][n];
    }
    bel[h] = belv;
    belief_out[(size_t)b * 512 + h] = belv;
  }
  __syncthreads();
  {
    float acc = prb[h];
    #pragma unroll 8
    for (int k = 0; k < HIDD; ++k) acc += bel[k] * prwT[(size_t)k * 512 + h];
    if (h < 256) out[O_MUP + b * 256 + h] = acc;
    else         out[O_LVP + b * 256 + (h - 256)] = acc;
  }
}

// ================= merged weight prepack =================

static __device__ __forceinline__ void pack_conv_elem(const float* __restrict__ w,
                                                      ushort* __restrict__ o,
                                                      int Cout, int Cin, int id) {
  int NCH = Cin / 2;
  int per = NCH * 512;
  int mt = id / per, r = id % per;
  int kcg = r >> 9, s = r & 511;
  int kg = s >> 7, m = (s >> 3) & 15, k8 = s & 7;
  int co = mt * 16 + m;
  int k = kcg * 32 + kg * 8 + k8;
  int tap = k / Cin, ci = k % Cin;
  o[id] = f2bf(w[(size_t)(co * Cin + ci) * 16 + tap]);
}

static __device__ __forceinline__ void pack_deconv_elem(const float* __restrict__ w,
                                                        ushort* __restrict__ o,
                                                        int Cout, int Cin, int id) {
  int NCH = Cin / 8;
  int perM = NCH * 512;
  int perC = (Cout / 16) * perM;
  int cls = id / perC, r = id % perC;
  int mt = r / perM, r2 = r % perM;
  int kcg = r2 >> 9, s = r2 & 511;
  int kg = s >> 7, m = (s >> 3) & 15, k8 = s & 7;
  int co = mt * 16 + m;
  int k = kcg * 32 + kg * 8 + k8;
  int t = k / Cin, ci = k % Cin;
  int p = (cls >> 1) + 2 * (t >> 1);
  int q = (cls & 1) + 2 * (t & 1);
  o[id] = f2bf(w[(size_t)(ci * Cout + co) * 16 + p * 4 + q]);
}

// conv1: Cin padded 3->4; k = tap*4+ci; layout [mt2][kcg2][512]
static __device__ __forceinline__ void pack_conv1_elem(const float* __restrict__ w,
                                                       ushort* __restrict__ o, int id) {
  int mt = id >> 10, r = id & 1023;
  int kcg = r >> 9, s = r & 511;
  int kg = s >> 7, m = (s >> 3) & 15, k8 = s & 7;
  int co = mt * 16 + m;
  int k = kcg * 32 + kg * 8 + k8;
  int tap = k >> 2, ci = k & 3;
  o[id] = (ci < 3) ? f2bf(w[(size_t)(co * 3 + ci) * 16 + tap]) : (ushort)0;
}

__global__ __launch_bounds__(256) void k_pack_all(
    const float* __restrict__ c2w, const float* __restrict__ c3w,
    const float* __restrict__ c4w, const float* __restrict__ d1w,
    const float* __restrict__ d2w, const float* __restrict__ d3w,
    const float* __restrict__ c1w,
    const float* __restrict__ siw, const float* __restrict__ Dw,
    const float* __restrict__ prw, const float* __restrict__ pw,
    ushort* __restrict__ pc2, ushort* __restrict__ pc3, ushort* __restrict__ pc4,
    ushort* __restrict__ pd1, ushort* __restrict__ pd2, ushort* __restrict__ pd3,
    ushort* __restrict__ pc1,
    float* __restrict__ siwT, float* __restrict__ DwT,
    float* __restrict__ prwT, float* __restrict__ powT) {
  int id = blockIdx.x * 256 + threadIdx.x;
  if (id < 32768)            pack_conv_elem(c2w, pc2, 64, 32, id);
  else if (id < 163840)      pack_conv_elem(c3w, pc3, 128, 64, id - 32768);
  else if (id < 688128)      pack_conv_elem(c4w, pc4, 256, 128, id - 163840);
  else if (id < 819200)      pack_deconv_elem(d1w, pd1, 64, 128, id - 688128);
  else if (id < 851968)      pack_deconv_elem(d2w, pd2, 32, 64, id - 819200);
  else if (id < 860160)      pack_deconv_elem(d3w, pd3, 16, 32, id - 851968);
  else if (id < 862208)      pack_conv1_elem(c1w, pc1, id - 860160);
  else if (id < 996352) {    // siwT [262][512]
    int r = id - 862208; int k = r >> 9, h = r & 511;
    siwT[r] = siw[(size_t)h * (LATENT + ACTD) + k];
  } else if (id < 1258496) { // DwT [512][512]
    int r = id - 996352; int k = r >> 9, h = r & 511;
    DwT[r] = Dw[(size_t)h * HIDD + k];
  } else if (id < 1520640) { // prwT [512][512]
    int r = id - 1258496; int k = r >> 9, h = r & 511;
    prwT[r] = prw[(size_t)h * HIDD + k];
  } else if (id < 2044928) { // powT [1024][512]
    int r = id - 1520640; int k = r >> 9, j = r & 511;
    powT[r] = pw[(size_t)j * 1024 + k];
  }
}

// ================= img -> [px][64b][4ci] bf16 (ci padded) =================
__global__ __launch_bounds__(256) void k_timg4(const float* __restrict__ img,
                                               ushort* __restrict__ timg4) {
  __shared__ float ts[3][64][65];
  int p0 = blockIdx.x << 6;
  int tid = threadIdx.x;
  #pragma unroll
  for (int c = 0; c < 3; ++c) {
    #pragma unroll
    for (int i = 0; i < 16; ++i) {
      int idx = tid + i * 256;
      int b = idx >> 6, pr = idx & 63;
      ts[c][pr][b] = img[((size_t)b * 3 + c) * 65536 + p0 + pr];
    }
  }
  __syncthreads();
  #pragma unroll
  for (int i = 0; i < 16; ++i) {
    int idx = tid + i * 256;
    int pr = idx >> 6, b = idx & 63;
    uint2 pk;
    pk.x = (unsigned)f2bf(ts[0][pr][b]) | ((unsigned)f2bf(ts[1][pr][b]) << 16);
    pk.y = (unsigned)f2bf(ts[2][pr][b]);
    *(uint2*)(timg4 + ((size_t)(p0 + pr) * 64 + b) * 4) = pk;
  }
}

// ================= conv1 MFMA: Cin=4(padded), one wave per output pixel =================
// in timg4 [65536][64][4]; wp pc1 [2mt][2kc][512]; out h1b frag-order 32ch x 64b
__global__ __launch_bounds__(256) void k_conv1_mfma(const ushort* __restrict__ in,
                                                    const ushort* __restrict__ wp,
                                                    const float* __restrict__ bias,
                                                    ushort* __restrict__ out) {
  int wid = __builtin_amdgcn_readfirstlane(blockIdx.x * 4 + (threadIdx.x >> 6));
  int lane = threadIdx.x & 63;
  int ox = wid & 127, oy = wid >> 7;
  int ml = lane & 15, khi = lane >> 4;
  f32x4 zero = {0.f, 0.f, 0.f, 0.f};
  f32x4 acc[2][4];
  #pragma unroll
  for (int mt = 0; mt < 2; ++mt)
    #pragma unroll
    for (int nt = 0; nt < 4; ++nt) acc[mt][nt] = zero;
  int by = 2 * oy - 1, bx = 2 * ox - 1;
  bool interior = (oy >= 1) & (oy <= 126) & (ox >= 1) & (ox <= 126);

  #pragma unroll
  for (int kc = 0; kc < 2; ++kc) {
    bf16x8 a0 = *(const bf16x8*)(wp + kc * 512 + lane * 8);
    bf16x8 a1 = *(const bf16x8*)(wp + 1024 + kc * 512 + lane * 8);
    int t0 = kc * 8 + khi * 2;
    int ky0 = t0 >> 2, kx0 = t0 & 3;
    int ky1 = (t0 + 1) >> 2, kx1 = (t0 + 1) & 3;
    int iy0 = by + ky0, ix0 = bx + kx0;
    int iy1 = by + ky1, ix1 = bx + kx1;
    const ushort* pA = in + ((size_t)(iy0 * 256 + ix0) * 64 + ml) * 4;
    const ushort* pB = in + ((size_t)(iy1 * 256 + ix1) * 64 + ml) * 4;
    if (interior) {
      #pragma unroll
      for (int nt = 0; nt < 4; ++nt) {
        uint2 lo = *(const uint2*)(pA + nt * 64);
        uint2 hi = *(const uint2*)(pB + nt * 64);
        uint4 u; u.x = lo.x; u.y = lo.y; u.z = hi.x; u.w = hi.y;
        bf16x8 bb = __builtin_bit_cast(bf16x8, u);
        acc[0][nt] = __builtin_amdgcn_mfma_f32_16x16x32_bf16(a0, bb, acc[0][nt], 0, 0, 0);
        acc[1][nt] = __builtin_amdgcn_mfma_f32_16x16x32_bf16(a1, bb, acc[1][nt], 0, 0, 0);
      }
    } else {
      bool ok0 = ((unsigned)iy0 < 256u) & ((unsigned)ix0 < 256u);
      bool ok1 = ((unsigned)iy1 < 256u) & ((unsigned)ix1 < 256u);
      #pragma unroll
      for (int nt = 0; nt < 4; ++nt) {
        uint2 z2; z2.x = 0u; z2.y = 0u;
        uint2 lo = ok0 ? *(const uint2*)(pA + nt * 64) : z2;
        uint2 hi = ok1 ? *(const uint2*)(pB + nt * 64) : z2;
        uint4 u; u.x = lo.x; u.y = lo.y; u.z = hi.x; u.w = hi.y;
        bf16x8 bb = __builtin_bit_cast(bf16x8, u);
        acc[0][nt] = __builtin_amdgcn_mfma_f32_16x16x32_bf16(a0, bb, acc[0][nt], 0, 0, 0);
        acc[1][nt] = __builtin_amdgcn_mfma_f32_16x16x32_bf16(a1, bb, acc[1][nt], 0, 0, 0);
      }
    }
  }
  int px = oy * 128 + ox;
  int rb = khi * 4;
  #pragma unroll
  for (int mt = 0; mt < 2; ++mt) {
    int co = mt * 16 + rb;
    f32x4 bv = *(const f32x4*)(bias + co);
    #pragma unroll
    for (int nt = 0; nt < 4; ++nt) {
      float v0 = fmaxf(acc[mt][nt][0] + bv[0], 0.f);
      float v1 = fmaxf(acc[mt][nt][1] + bv[1], 0.f);
      float v2 = fmaxf(acc[mt][nt][2] + bv[2], 0.f);
      float v3 = fmaxf(acc[mt][nt][3] + bv[3], 0.f);
      uint2 pk;
      pk.x = (unsigned)f2bf(v0) | ((unsigned)f2bf(v1) << 16);
      pk.y = (unsigned)f2bf(v2) | ((unsigned)f2bf(v3) << 16);
      size_t off = (size_t)px * 2048 + nt * 512 + ((co >> 3) & 3) * 128 + ml * 8 + (co & 7);
      *(uint2*)(out + off) = pk;
    }
  }
}

// ================= MFMA conv, interior fast path =================
template<int CIN, int COUT, int MT>
__global__ __launch_bounds__(256) void mfma_conv(const ushort* __restrict__ in,
                                                 const ushort* __restrict__ wp,
                                                 const float* __restrict__ bias,
                                                 ushort* __restrict__ out,
                                                 int Hin, int Win, int Hout, int Wout) {
  constexpr int NMG = COUT / (16 * MT);
  constexpr int NKC = CIN / 32;
  constexpr int NCH = 16 * NKC;
  int wid = __builtin_amdgcn_readfirstlane(blockIdx.x * 4 + (threadIdx.x >> 6));
  int lane = threadIdx.x & 63;
  int mg = wid % NMG;
  int px = wid / NMG;
  int ox = px % Wout, oy = px / Wout;
  if (oy >= Hout) return;
  int mtile0 = mg * MT;
  f32x4 zero = {0.f, 0.f, 0.f, 0.f};
  f32x4 acc[MT][4];
  #pragma unroll
  for (int mt = 0; mt < MT; ++mt)
    #pragma unroll
    for (int nt = 0; nt < 4; ++nt) acc[mt][nt] = zero;
  const ushort* wbase = wp + (size_t)mtile0 * NCH * 512 + lane * 8;
  const size_t mstride = (size_t)NCH * 512;
  bool interior = (oy >= 1) & (oy < Hout - 1) & (ox >= 1) & (ox < Wout - 1);

  if (interior) {
    #pragma unroll
    for (int ky = 0; ky < 4; ++ky) {
      int iy = 2 * oy - 1 + ky;
      #pragma unroll
      for (int kx = 0; kx < 4; ++kx) {
        int ix = 2 * ox - 1 + kx;
        const ushort* ib = in + (size_t)(iy * Win + ix) * (CIN * 64) + lane * 8;
        int tap = ky * 4 + kx;
        #pragma unroll
        for (int kc = 0; kc < NKC; ++kc) {
          int kcg = tap * NKC + kc;
          bf16x8 a[MT], bb[4];
          #pragma unroll
          for (int mt = 0; mt < MT; ++mt)
            a[mt] = *(const bf16x8*)(wbase + mt * mstride + (size_t)kcg * 512);
          #pragma unroll
          for (int nt = 0; nt < 4; ++nt)
            bb[nt] = *(const bf16x8*)(ib + kc * 2048 + nt * 512);
          #pragma unroll
          for (int mt = 0; mt < MT; ++mt)
            #pragma unroll
            for (int nt = 0; nt < 4; ++nt)
              acc[mt][nt] = __builtin_amdgcn_mfma_f32_16x16x32_bf16(a[mt], bb[nt], acc[mt][nt], 0, 0, 0);
        }
      }
    }
  } else {
    for (int ky = 0; ky < 4; ++ky) {
      int iy = 2 * oy - 1 + ky;
      if ((unsigned)iy >= (unsigned)Hin) continue;
      for (int kx = 0; kx < 4; ++kx) {
        int ix = 2 * ox - 1 + kx;
        if ((unsigned)ix >= (unsigned)Win) continue;
        const ushort* ib = in + (size_t)(iy * Win + ix) * (CIN * 64) + lane * 8;
        int tap = ky * 4 + kx;
        #pragma unroll
        for (int kc = 0; kc < NKC; ++kc) {
          int kcg = tap * NKC + kc;
          bf16x8 a[MT], bb[4];
          #pragma unroll
          for (int mt = 0; mt < MT; ++mt)
            a[mt] = *(const bf16x8*)(wbase + mt * mstride + (size_t)kcg * 512);
          #pragma unroll
          for (int nt = 0; nt < 4; ++nt)
            bb[nt] = *(const bf16x8*)(ib + kc * 2048 + nt * 512);
          #pragma unroll
          for (int mt = 0; mt < MT; ++mt)
            #pragma unroll
            for (int nt = 0; nt < 4; ++nt)
              acc[mt][nt] = __builtin_amdgcn_mfma_f32_16x16x32_bf16(a[mt], bb[nt], acc[mt][nt], 0, 0, 0);
        }
      }
    }
  }
  int ml = lane & 15, rb = (lane >> 4) * 4;
  #pragma unroll
  for (int mt = 0; mt < MT; ++mt) {
    int co = mtile0 * 16 + mt * 16 + rb;
    f32x4 bv = *(const f32x4*)(bias + co);
    #pragma unroll
    for (int nt = 0; nt < 4; ++nt) {
      float v0 = fmaxf(acc[mt][nt][0] + bv[0], 0.f);
      float v1 = fmaxf(acc[mt][nt][1] + bv[1], 0.f);
      float v2 = fmaxf(acc[mt][nt][2] + bv[2], 0.f);
      float v3 = fmaxf(acc[mt][nt][3] + bv[3], 0.f);
      uint2 pk;
      pk.x = (unsigned)f2bf(v0) | ((unsigned)f2bf(v1) << 16);
      pk.y = (unsigned)f2bf(v2) | ((unsigned)f2bf(v3) << 16);
      size_t off = (size_t)px * (COUT * 64) + (size_t)(co >> 5) * 2048 + nt * 512
                 + ((co >> 3) & 3) * 128 + ml * 8 + (co & 7);
      *(uint2*)(out + off) = pk;
    }
  }
}

// ================= MFMA transposed conv, interior fast path =================
template<int CIN, int COUT, int MT, bool RELU>
__global__ __launch_bounds__(256) void mfma_deconv(const ushort* __restrict__ in,
                                                   const ushort* __restrict__ wp,
                                                   const float* __restrict__ bias,
                                                   ushort* __restrict__ out,
                                                   int Hin, int Win, int Hout, int Wout) {
  constexpr int NMG = COUT / (16 * MT);
  constexpr int NKC = CIN / 32;
  constexpr int NCH = 4 * NKC;
  constexpr int NTS = (COUT >= 32) ? 512 : (COUT * 16);
  int wid = __builtin_amdgcn_readfirstlane(blockIdx.x * 4 + (threadIdx.x >> 6));
  int lane = threadIdx.x & 63;
  int mg = wid % NMG; int r1 = wid / NMG;
  int wo2 = Wout >> 1;
  int pc = (Hout >> 1) * wo2;
  int pxc = r1 % pc; int cls = r1 / pc;
  if (cls >= 4) return;
  int p0 = cls >> 1, q0 = cls & 1;
  int tx = pxc % wo2, ty = pxc / wo2;
  int oy = 2 * ty + 1 - p0, ox = 2 * tx + 1 - q0;
  int iy0 = (oy + 1 - p0) >> 1, ix0 = (ox + 1 - q0) >> 1;
  int mtile0 = mg * MT;
  f32x4 zero = {0.f, 0.f, 0.f, 0.f};
  f32x4 acc[MT][4];
  #pragma unroll
  for (int mt = 0; mt < MT; ++mt)
    #pragma unroll
    for (int nt = 0; nt < 4; ++nt) acc[mt][nt] = zero;
  const ushort* wbase = wp + ((size_t)cls * (COUT / 16) + mtile0) * NCH * 512 + lane * 8;
  const size_t mstride = (size_t)NCH * 512;
  bool interior = (iy0 >= 1) & (iy0 <= Hin - 1) & (ix0 >= 1) & (ix0 <= Win - 1);

  if (interior) {
    #pragma unroll
    for (int i = 0; i < 2; ++i) {
      int iy = iy0 - i;
      #pragma unroll
      for (int j = 0; j < 2; ++j) {
        int ix = ix0 - j;
        const ushort* ib = in + (size_t)(iy * Win + ix) * (CIN * 64) + lane * 8;
        int tap = i * 2 + j;
        #pragma unroll
        for (int kc = 0; kc < NKC; ++kc) {
          int kcg = tap * NKC + kc;
          bf16x8 a[MT], bb[4];
          #pragma unroll
          for (int mt = 0; mt < MT; ++mt)
            a[mt] = *(const bf16x8*)(wbase + mt * mstride + (size_t)kcg * 512);
          #pragma unroll
          for (int nt = 0; nt < 4; ++nt)
            bb[nt] = *(const bf16x8*)(ib + kc * 2048 + nt * 512);
          #pragma unroll
          for (int mt = 0; mt < MT; ++mt)
            #pragma unroll
            for (int nt = 0; nt < 4; ++nt)
              acc[mt][nt] = __builtin_amdgcn_mfma_f32_16x16x32_bf16(a[mt], bb[nt], acc[mt][nt], 0, 0, 0);
        }
      }
    }
  } else {
    for (int i = 0; i < 2; ++i) {
      int iy = iy0 - i;
      if ((unsigned)iy >= (unsigned)Hin) continue;
      for (int j = 0; j < 2; ++j) {
        int ix = ix0 - j;
        if ((unsigned)ix >= (unsigned)Win) continue;
        const ushort* ib = in + (size_t)(iy * Win + ix) * (CIN * 64) + lane * 8;
        int tap = i * 2 + j;
        #pragma unroll
        for (int kc = 0; kc < NKC; ++kc) {
          int kcg = tap * NKC + kc;
          bf16x8 a[MT], bb[4];
          #pragma unroll
          for (int mt = 0; mt < MT; ++mt)
            a[mt] = *(const bf16x8*)(wbase + mt * mstride + (size_t)kcg * 512);
          #pragma unroll
          for (int nt = 0; nt < 4; ++nt)
            bb[nt] = *(const bf16x8*)(ib + kc * 2048 + nt * 512);
          #pragma unroll
          for (int mt = 0; mt < MT; ++mt)
            #pragma unroll
            for (int nt = 0; nt < 4; ++nt)
              acc[mt][nt] = __builtin_amdgcn_mfma_f32_16x16x32_bf16(a[mt], bb[nt], acc[mt][nt], 0, 0, 0);
        }
      }
    }
  }
  int ml = lane & 15, rb = (lane >> 4) * 4;
  int px = oy * Wout + ox;
  #pragma unroll
  for (int mt = 0; mt < MT; ++mt) {
    int co = mtile0 * 16 + mt * 16 + rb;
    f32x4 bv = *(const f32x4*)(bias + co);
    #pragma unroll
    for (int nt = 0; nt < 4; ++nt) {
      float v0 = acc[mt][nt][0] + bv[0];
      float v1 = acc[mt][nt][1] + bv[1];
      float v2 = acc[mt][nt][2] + bv[2];
      float v3 = acc[mt][nt][3] + bv[3];
      if (RELU) { v0=fmaxf(v0,0.f); v1=fmaxf(v1,0.f); v2=fmaxf(v2,0.f); v3=fmaxf(v3,0.f); }
      uint2 pk;
      pk.x = (unsigned)f2bf(v0) | ((unsigned)f2bf(v1) << 16);
      pk.y = (unsigned)f2bf(v2) | ((unsigned)f2bf(v3) << 16);
      size_t off = (size_t)px * (COUT * 64) + (size_t)(co >> 5) * 2048 + (size_t)nt * NTS
                 + ((co >> 3) & 3) * 128 + ml * 8 + (co & 7);
      *(uint2*)(out + off) = pk;
    }
  }
}

// ================= enc_fc fused: LDS-transpose staging + MFMA =================
#define APXS 1032
__global__ __launch_bounds__(256) void k_encfc_fused(const ushort* __restrict__ h4,
                                                     const float* __restrict__ wE,
                                                     float* __restrict__ partial) {
  __shared__ float smem[8320];
  ushort* au = (ushort*)smem;
  int s = blockIdx.x;
  int bid = (s & 7) * 256 + (s >> 3);
  int mg = bid & 15;
  int ccf = (bid >> 4) & 7;
  int pxg = bid >> 7;
  int tid = threadIdx.x;
  int co0 = mg * 32;
  #pragma unroll 4
  for (int i = 0; i < 64; ++i) {
    int idx = tid + i * 256;
    int px_l = idx & 15;
    int ci_l = (idx >> 4) & 31;
    int co_l = idx >> 9;
    float v = wE[((size_t)(co0 + co_l) << 16) + (size_t)(ccf * 32 + ci_l) * 256 + pxg * 16 + px_l];
    int mt = co_l >> 4, m = co_l & 15;
    int kg = ci_l >> 3, k8 = ci_l & 7;
    au[px_l * APXS + mt * 512 + kg * 128 + m * 8 + k8] = f2bf(v);
  }
  __syncthreads();
  int lane = tid & 63, wv = tid >> 6;
  int ml = lane & 15, rb = (lane >> 4) * 4;
  f32x4 zero = {0.f, 0.f, 0.f, 0.f};
  f32x4 acc[2][4];
  #pragma unroll
  for (int mt = 0; mt < 2; ++mt)
    #pragma unroll
    for (int nt = 0; nt < 4; ++nt) acc[mt][nt] = zero;
  #pragma unroll
  for (int jj = 0; jj < 4; ++jj) {
    int j = wv * 4 + jj;
    int px = pxg * 16 + j;
    bf16x8 a0 = *(const bf16x8*)(au + j * APXS + lane * 8);
    bf16x8 a1 = *(const bf16x8*)(au + j * APXS + 512 + lane * 8);
    const ushort* hb = h4 + (size_t)px * 16384 + ccf * 2048 + lane * 8;
    bf16x8 bb[4];
    #pragma unroll
    for (int nt = 0; nt < 4; ++nt)
      bb[nt] = *(const bf16x8*)(hb + nt * 512);
    #pragma unroll
    for (int nt = 0; nt < 4; ++nt) {
      acc[0][nt] = __builtin_amdgcn_mfma_f32_16x16x32_bf16(a0, bb[nt], acc[0][nt], 0, 0, 0);
      acc[1][nt] = __builtin_amdgcn_mfma_f32_16x16x32_bf16(a1, bb[nt], acc[1][nt], 0, 0, 0);
    }
  }
  __syncthreads();
  #pragma unroll
  for (int mt = 0; mt < 2; ++mt)
    #pragma unroll
    for (int nt = 0; nt < 4; ++nt)
      #pragma unroll
      for (int r = 0; r < 4; ++r)
        smem[wv * 2080 + (mt * 16 + rb + r) * 65 + nt * 16 + ml] = acc[mt][nt][r];
  __syncthreads();
  int ks = pxg * 8 + ccf;
  #pragma unroll
  for (int i = 0; i < 8; ++i) {
    int e = tid + i * 256;
    int b = e & 63, co_l = e >> 6;
    float sum = smem[co_l * 65 + b] + smem[2080 + co_l * 65 + b]
              + smem[4160 + co_l * 65 + b] + smem[6240 + co_l * 65 + b];
    partial[((size_t)(co0 + co_l) * ENC_KS + ks) * 64 + b] = sum;
  }
}

__global__ void k_encfc_red(const float* __restrict__ partial, const float* __restrict__ bias,
                            float* __restrict__ cnn) {
  int id = blockIdx.x * blockDim.x + threadIdx.x;
  int o = id >> 6, b = id & 63;
  float acc = bias[o];
  #pragma unroll 8
  for (int s = 0; s < ENC_KS; ++s) acc += partial[((size_t)o * ENC_KS + s) * 64 + b];
  cnn[(size_t)b * 512 + o] = fmaxf(acc, 0.f);
}

// ================= fused posterior + reparam (coalesced powT) =================
__global__ __launch_bounds__(512) void k_postz(const float* __restrict__ cnn,
                                               const float* __restrict__ belief,
                                               const float* __restrict__ powT,
                                               const float* __restrict__ bias,
                                               const float* __restrict__ eps,
                                               float* __restrict__ out,
                                               ushort* __restrict__ zb) {
  __shared__ float cs[512];
  __shared__ float bs[512];
  __shared__ float sm[512];
  int b = blockIdx.x;
  int j = threadIdx.x;
  cs[j] = cnn[(size_t)b * HIDD + j];
  bs[j] = belief[(size_t)b * HIDD + j];
  __syncthreads();
  float acc = bias[j];
  #pragma unroll 8
  for (int k = 0; k < HIDD; ++k) acc += cs[k] * powT[(size_t)k * 512 + j];
  #pragma unroll 8
  for (int k = 0; k < HIDD; ++k) acc += bs[k] * powT[(size_t)(512 + k) * 512 + j];
  sm[j] = acc;
  if (j < 256) out[O_MUPO + b * 256 + j] = acc;
  else         out[O_LVPO + b * 256 + (j - 256)] = acc;
  __syncthreads();
  if (j < 256) {
    float z = sm[j] + eps[b * 256 + j] * expf(0.5f * sm[j + 256]);
    out[O_ZT + b * 256 + j] = z;
    if (j < 128) zb[b * 128 + j] = f2bf(z);
  }
}

// ================= dec_fc MFMA: direct f32 weights, frag-order out =================
__global__ __launch_bounds__(256) void k_decfc_mfma(const ushort* __restrict__ zb,
                                                    const float* __restrict__ dfw,
                                                    const float* __restrict__ dfb,
                                                    ushort* __restrict__ dec) {
  int wid = __builtin_amdgcn_readfirstlane(blockIdx.x * 4 + (threadIdx.x >> 6));
  int lane = threadIdx.x & 63;
  int m0 = wid * 32;
  int ml = lane & 15, kl = (lane >> 4) * 8;
  f32x4 zero = {0.f, 0.f, 0.f, 0.f};
  f32x4 acc[2][4];
  #pragma unroll
  for (int mt = 0; mt < 2; ++mt)
    #pragma unroll
    for (int nt = 0; nt < 4; ++nt) acc[mt][nt] = zero;
  #pragma unroll
  for (int kc = 0; kc < 4; ++kc) {
    bf16x8 a[2], bb[4];
    #pragma unroll
    for (int mt = 0; mt < 2; ++mt) {
      int m_r = m0 + mt * 16 + ml;
      const float* wr = dfw + (size_t)((m_r & 127) * 256 + (m_r >> 7)) * 128 + kc * 32 + kl;
      float4 u0 = *(const float4*)wr;
      float4 u1 = *(const float4*)(wr + 4);
      bf16x8 av;
      av[0] = (short)f2bf(u0.x); av[1] = (short)f2bf(u0.y);
      av[2] = (short)f2bf(u0.z); av[3] = (short)f2bf(u0.w);
      av[4] = (short)f2bf(u1.x); av[5] = (short)f2bf(u1.y);
      av[6] = (short)f2bf(u1.z); av[7] = (short)f2bf(u1.w);
      a[mt] = av;
    }
    #pragma unroll
    for (int nt = 0; nt < 4; ++nt)
      bb[nt] = *(const bf16x8*)(zb + (size_t)(nt * 16 + ml) * 128 + kc * 32 + kl);
    #pragma unroll
    for (int mt = 0; mt < 2; ++mt)
      #pragma unroll
      for (int nt = 0; nt < 4; ++nt)
        acc[mt][nt] = __builtin_amdgcn_mfma_f32_16x16x32_bf16(a[mt], bb[nt], acc[mt][nt], 0, 0, 0);
  }
  int rb = (lane >> 4) * 4;
  #pragma unroll
  for (int mt = 0; mt < 2; ++mt) {
    int m = m0 + mt * 16 + rb;
    int pix = m >> 7, co = m & 127;
    float bv0 = dfb[(size_t)(co + 0) * 256 + pix];
    float bv1 = dfb[(size_t)(co + 1) * 256 + pix];
    float bv2 = dfb[(size_t)(co + 2) * 256 + pix];
    float bv3 = dfb[(size_t)(co + 3) * 256 + pix];
    #pragma unroll
    for (int nt = 0; nt < 4; ++nt) {
      uint2 pk;
      pk.x = (unsigned)f2bf(acc[mt][nt][0] + bv0) | ((unsigned)f2bf(acc[mt][nt][1] + bv1) << 16);
      pk.y = (unsigned)f2bf(acc[mt][nt][2] + bv2) | ((unsigned)f2bf(acc[mt][nt][3] + bv3) << 16);
      size_t off = (size_t)pix * 8192 + (size_t)(co >> 5) * 2048 + nt * 512
                 + ((co >> 3) & 3) * 128 + ml * 8 + (co & 7);
      *(uint2*)(dec + off) = pk;
    }
  }
}

// ================= d4 fused with output transpose =================
__global__ __launch_bounds__(256) void k_d4t(const ushort* __restrict__ in,
                                             const float* __restrict__ w,
                                             const float* __restrict__ bias,
                                             float* __restrict__ out) {
  __shared__ float lds[64][65];
  int blk = blockIdx.x;
  int oy = blk >> 2, ox0 = (blk & 3) << 6;
  int t = threadIdx.x;
  int b = t & 63, sub = t >> 6;
  float bv = bias[0];
  for (int j = 0; j < 16; ++j) {
    int oxl = j * 4 + sub;
    int ox = ox0 + oxl;
    int p0 = (oy + 1) & 1, q0 = (ox + 1) & 1;
    int iy0 = (oy + 1 - p0) >> 1, ix0 = (ox + 1 - q0) >> 1;
    float acc = bv;
    #pragma unroll
    for (int i = 0; i < 2; ++i) {
      int iy = iy0 - i;
      if ((unsigned)iy >= 128u) continue;
      int p = p0 + 2 * i;
      #pragma unroll
      for (int jj = 0; jj < 2; ++jj) {
        int ix = ix0 - jj;
        if ((unsigned)ix >= 128u) continue;
        int q = q0 + 2 * jj;
        const ushort* base = in + (size_t)(iy * 128 + ix) * 1024 + (b >> 4) * 256 + (b & 15) * 8;
        bf16x8 v0 = *(const bf16x8*)(base);
        bf16x8 v1 = *(const bf16x8*)(base + 128);
        const float* wq = w + p * 4 + q;
        #pragma unroll
        for (int ci = 0; ci < 8; ++ci) acc += bf2f((ushort)v0[ci]) * wq[ci * 16];
        #pragma unroll
        for (int ci = 0; ci < 8; ++ci) acc += bf2f((ushort)v1[ci]) * wq[(ci + 8) * 16];
      }
    }
    lds[oxl][b] = acc;
  }
  __syncthreads();
  #pragma unroll
  for (int j = 0; j < 16; ++j) {
    int idx = t + j * 256;
    int b2 = idx >> 6, oxl = idx & 63;
    out[(size_t)b2 * 65536 + oy * 256 + ox0 + oxl] = lds[oxl][b2];
  }
}

// ================= launch =================

extern "C" void kernel_launch(void* const* d_in, const int* in_sizes, int n_in,
                              void* d_out, int out_size, void* d_ws, size_t ws_size,
                              hipStream_t stream) {
  const float* img      = (const float*)d_in[0];
  const float* act      = (const float*)d_in[1];
  const float* z_prev   = (const float*)d_in[2];
  const float* st_prev  = (const float*)d_in[3];
  const float* eps      = (const float*)d_in[4];
  const float* c1w = (const float*)d_in[5];  const float* c1b = (const float*)d_in[6];
  const float* c2w = (const float*)d_in[7];  const float* c2b = (const float*)d_in[8];
  const float* c3w = (const float*)d_in[9];  const float* c3b = (const float*)d_in[10];
  const float* c4w = (const float*)d_in[11]; const float* c4b = (const float*)d_in[12];
  const float* efw = (const float*)d_in[13]; const float* efb = (const float*)d_in[14];
  const float* pow_ = (const float*)d_in[15]; const float* pob = (const float*)d_in[16];
  const float* prw = (const float*)d_in[17]; const float* prb = (const float*)d_in[18];
  const float* siw = (const float*)d_in[19]; const float* sib = (const float*)d_in[20];
  const float* Alog = (const float*)d_in[21];
  const float* Bw = (const float*)d_in[22];  const float* Cw = (const float*)d_in[23];
  const float* Dw = (const float*)d_in[24];  const float* Db = (const float*)d_in[25];
  const float* Dv = (const float*)d_in[26];
  const float* dfw = (const float*)d_in[27]; const float* dfb = (const float*)d_in[28];
  const float* d1w = (const float*)d_in[29]; const float* d1b = (const float*)d_in[30];
  const float* d2w = (const float*)d_in[31]; const float* d2b = (const float*)d_in[32];
  const float* d3w = (const float*)d_in[33]; const float* d3b = (const float*)d_in[34];
  const float* d4w = (const float*)d_in[35]; const float* d4b = (const float*)d_in[36];

  float* ws = (float*)d_ws;
  float* out = (float*)d_out;

  ushort* pc2 = (ushort*)(ws + PW_C2);
  ushort* pc3 = (ushort*)(ws + PW_C3);
  ushort* pc4 = (ushort*)(ws + PW_C4);
  ushort* pd1 = (ushort*)(ws + PW_D1);
  ushort* pd2 = (ushort*)(ws + PW_D2);
  ushort* pd3 = (ushort*)(ws + PW_D3);
  ushort* pc1 = (ushort*)(ws + PW_C1);
  ushort* timg4 = (ushort*)(ws + W_TIMG);
  ushort* h1b = (ushort*)(ws + W_H1B);
  ushort* h2b = (ushort*)(ws + W_H2B);
  ushort* h3b = (ushort*)(ws + W_H3B);
  ushort* h4b = (ushort*)(ws + W_H4B);
  ushort* deco = (ushort*)(ws + W_DECO);
  ushort* d1o = (ushort*)(ws + W_D1O);
  ushort* d2o = (ushort*)(ws + W_D2O);
  ushort* d3o = (ushort*)(ws + W_D3O);
  ushort* zb = (ushort*)(ws + W_ZB16);
  float* siwT = ws + W_SIWT;
  float* DwT  = ws + W_DWT;
  float* prwT = ws + W_PRWT;
  float* powT = ws + W_POWT;

  // ---- merged weight prepack (+ conv1 pack + dense transposes) ----
  k_pack_all<<<7988, 256, 0, stream>>>(c2w, c3w, c4w, d1w, d2w, d3w, c1w,
                                       siw, Dw, prw, pow_,
                                       pc2, pc3, pc4, pd1, pd2, pd3, pc1,
                                       siwT, DwT, prwT, powT);

  // ---- fused SSM chain (coalesced) ----
  k_ssm_all<<<64, 512, 0, stream>>>(z_prev, act, siwT, sib, DwT, Db, Bw, Cw,
                                    Alog, Dv, st_prev, out + O_STATE,
                                    ws + W_BELIEF, prwT, prb, out);

  // ---- encoder ----
  k_timg4<<<1024, 256, 0, stream>>>(img, timg4);
  k_conv1_mfma<<<4096, 256, 0, stream>>>(timg4, pc1, c1b, h1b);
  mfma_conv<32, 64, 2><<<2048, 256, 0, stream>>>(h1b, pc2, c2b, h2b, 128, 128, 64, 64);
  mfma_conv<64, 128, 2><<<1024, 256, 0, stream>>>(h2b, pc3, c3b, h3b, 64, 64, 32, 32);
  mfma_conv<128, 256, 1><<<1024, 256, 0, stream>>>(h3b, pc4, c4b, h4b, 32, 32, 16, 16);

  // ---- enc_fc (fused transpose+GEMM) ----
  k_encfc_fused<<<2048, 256, 0, stream>>>(h4b, efw, ws + W_ENCP);
  k_encfc_red<<<128, 256, 0, stream>>>(ws + W_ENCP, efb, ws + W_CNN);

  // ---- fused posterior + reparam ----
  k_postz<<<64, 512, 0, stream>>>(ws + W_CNN, ws + W_BELIEF, powT, pob, eps, out, zb);

  // ---- decoder ----
  k_decfc_mfma<<<256, 256, 0, stream>>>(zb, dfw, dfb, deco);
  mfma_deconv<128, 64, 1, true><<<1024, 256, 0, stream>>>(deco, pd1, d1b, d1o, 16, 16, 32, 32);
  mfma_deconv<64, 32, 1, true><<<2048, 256, 0, stream>>>(d1o, pd2, d2b, d2o, 32, 32, 64, 64);
  mfma_deconv<32, 16, 1, true><<<4096, 256, 0, stream>>>(d2o, pd3, d3b, d3o, 64, 64, 128, 128);
  k_d4t<<<1024, 256, 0, stream>>>(d3o, d4w, d4b, out + O_PRED);
}

// Round 11
// 444.907 us; speedup vs baseline: 1.3236x; 1.0527x over previous
//
#include <hip/hip_runtime.h>
#include <math.h>

#define BB 64
#define LATENT 256
#define ACTD 6
#define HIDD 512
#define DST 16

typedef __attribute__((ext_vector_type(8))) short bf16x8;
typedef __attribute__((ext_vector_type(4))) float f32x4;

static __device__ __forceinline__ ushort f2bf(float f) {
  unsigned u = __builtin_bit_cast(unsigned, f);
  unsigned r = (u + 0x7FFFu + ((u >> 16) & 1u)) >> 16;
  return (ushort)r;
}
static __device__ __forceinline__ float bf2f(ushort u) {
  return __builtin_bit_cast(float, ((unsigned)u) << 16);
}

// ---------------- output offsets (floats) ----------------
#define O_PRED   0
#define O_ZT     4194304
#define O_STATE  4210688
#define O_MUP    4734976
#define O_LVP    4751360
#define O_MUPO   4767744
#define O_LVPO   4784128

// ---------------- ws offsets (floats), lifetime-reused ----------------
#define W_BELIEF 67584u
#define W_CNN    100352u
#define W_ZB16   133120u      // 8192 u16
#define PW_C2    137216u      // 32768 u16
#define PW_C3    153600u      // 131072 u16
#define PW_C4    219136u      // 524288 u16
#define PW_D1    481280u      // 131072 u16
#define PW_D2    546816u      // 32768 u16
#define PW_D3    563200u      // 8192 u16
#define PW_C1    567296u      // 2048 u16
#define W_TIMG   602112u      // timg4 bf16 [65536][64][4] = 16,777,216 u16 (ends 8990720 f)
#define W_H1B    13185024u    // 33,554,432 u16 [dead after conv2]
#define W_H2B    29962240u    // 16,777,216 u16
#define W_H3B    38350848u    // 8,388,608 u16
#define W_H4B    42545152u    // 4,194,304 u16 (ends 44642304 f)
// transposed dense weights (f32), after H4B:
#define W_SIWT   44642304u    // 134,144 f
#define W_DWT    44776448u    // 262,144 f
#define W_PRWT   45038592u    // 262,144 f
#define W_POWT   45300736u    // 524,288 f (ends 45825024)
// reuse (regions dead by write time):
#define W_ENCP   602112u      // (TIMG region, dead after conv1)
#define W_DECO   8990720u     // (TIMG region, after timg4 end)
#define W_D1O    10039296u    // (TIMG region)
#define W_D2O    13185024u    // (H1B)
#define W_D3O    17379328u    // (H1B)

#define ENC_KS 128

// ================= fused SSM chain: one block per batch, coalesced wT =================
__global__ __launch_bounds__(512) void k_ssm_all(
    const float* __restrict__ z_prev, const float* __restrict__ act,
    const float* __restrict__ siwT, const float* __restrict__ sib,
    const float* __restrict__ DwT, const float* __restrict__ Db,
    const float* __restrict__ Bw, const float* __restrict__ Cw,
    const float* __restrict__ Alog, const float* __restrict__ Dv,
    const float* __restrict__ st_prev, float* __restrict__ state_out,
    float* __restrict__ belief_out, const float* __restrict__ prwT,
    const float* __restrict__ prb, float* __restrict__ out) {
  __shared__ float zs[256];
  __shared__ float as_[8];
  __shared__ float si[512];
  __shared__ float bel[512];
  __shared__ float part[2][16][4];
  __shared__ float btct[2][16];
  int b = blockIdx.x;
  int h = threadIdx.x;
  if (h < 256) zs[h] = z_prev[(size_t)b * LATENT + h];
  if (h >= 256 && h < 256 + ACTD) as_[h - 256] = act[(size_t)b * ACTD + (h - 256)];
  __syncthreads();
  {
    float acc = sib[h];
    #pragma unroll 8
    for (int k = 0; k < LATENT; ++k) acc += zs[k] * siwT[(size_t)k * 512 + h];
    #pragma unroll
    for (int k = 0; k < ACTD; ++k) acc += as_[k] * siwT[(size_t)(LATENT + k) * 512 + h];
    si[h] = acc / (1.f + expf(-acc));
  }
  __syncthreads();
  float d;
  {
    float acc = Db[h];
    #pragma unroll 8
    for (int k = 0; k < HIDD; ++k) acc += si[k] * DwT[(size_t)k * 512 + h];
    d = fmaxf(acc, 0.f) + log1pf(expf(-fabsf(acc)));
  }
  if (h < 128) {
    int half = h >> 6;
    int l = h & 63;
    int n = l & 15, p = l >> 4;
    const float* wr = (half ? Cw : Bw) + (size_t)n * HIDD + p * 128;
    const float* sr = si + p * 128;
    float acc = 0.f;
    #pragma unroll 4
    for (int k = 0; k < 128; k += 4) {
      float4 w4 = *(const float4*)(wr + k);
      acc += sr[k] * w4.x + sr[k+1] * w4.y + sr[k+2] * w4.z + sr[k+3] * w4.w;
    }
    part[half][n][p] = acc;
  }
  __syncthreads();
  if (h < 32) {
    int half = h >> 4, n = h & 15;
    btct[half][n] = part[half][n][0] + part[half][n][1] + part[half][n][2] + part[half][n][3];
  }
  __syncthreads();
  {
    float si_h = si[h];
    float belv = Dv[h] * si_h;
    const float* al = Alog + (size_t)h * DST;
    const float* sp = st_prev + ((size_t)b * 512 + h) * DST;
    float* so = state_out + ((size_t)b * 512 + h) * DST;
    #pragma unroll
    for (int n = 0; n < DST; ++n) {
      float A = -expf(al[n]);
      float st = expf(d * A) * sp[n] + d * btct[0][n] * si_h;
      so[n] = st;
      belv += st * btct[1][n];
    }
    bel[h] = belv;
    belief_out[(size_t)b * 512 + h] = belv;
  }
  __syncthreads();
  {
    float acc = prb[h];
    #pragma unroll 8
    for (int k = 0; k < HIDD; ++k) acc += bel[k] * prwT[(size_t)k * 512 + h];
    if (h < 256) out[O_MUP + b * 256 + h] = acc;
    else         out[O_LVP + b * 256 + (h - 256)] = acc;
  }
}

// ================= merged weight prepack =================

static __device__ __forceinline__ void pack_conv_elem(const float* __restrict__ w,
                                                      ushort* __restrict__ o,
                                                      int Cout, int Cin, int id) {
  int NCH = Cin / 2;
  int per = NCH * 512;
  int mt = id / per, r = id % per;
  int kcg = r >> 9, s = r & 511;
  int kg = s >> 7, m = (s >> 3) & 15, k8 = s & 7;
  int co = mt * 16 + m;
  int k = kcg * 32 + kg * 8 + k8;
  int tap = k / Cin, ci = k % Cin;
  o[id] = f2bf(w[(size_t)(co * Cin + ci) * 16 + tap]);
}

static __device__ __forceinline__ void pack_deconv_elem(const float* __restrict__ w,
                                                        ushort* __restrict__ o,
                                                        int Cout, int Cin, int id) {
  int NCH = Cin / 8;
  int perM = NCH * 512;
  int perC = (Cout / 16) * perM;
  int cls = id / perC, r = id % perC;
  int mt = r / perM, r2 = r % perM;
  int kcg = r2 >> 9, s = r2 & 511;
  int kg = s >> 7, m = (s >> 3) & 15, k8 = s & 7;
  int co = mt * 16 + m;
  int k = kcg * 32 + kg * 8 + k8;
  int t = k / Cin, ci = k % Cin;
  int p = (cls >> 1) + 2 * (t >> 1);
  int q = (cls & 1) + 2 * (t & 1);
  o[id] = f2bf(w[(size_t)(ci * Cout + co) * 16 + p * 4 + q]);
}

// conv1: Cin padded 3->4; k = tap*4+ci; layout [mt2][kcg2][512]
static __device__ __forceinline__ void pack_conv1_elem(const float* __restrict__ w,
                                                       ushort* __restrict__ o, int id) {
  int mt = id >> 10, r = id & 1023;
  int kcg = r >> 9, s = r & 511;
  int kg = s >> 7, m = (s >> 3) & 15, k8 = s & 7;
  int co = mt * 16 + m;
  int k = kcg * 32 + kg * 8 + k8;
  int tap = k >> 2, ci = k & 3;
  o[id] = (ci < 3) ? f2bf(w[(size_t)(co * 3 + ci) * 16 + tap]) : (ushort)0;
}

__global__ __launch_bounds__(256) void k_pack_all(
    const float* __restrict__ c2w, const float* __restrict__ c3w,
    const float* __restrict__ c4w, const float* __restrict__ d1w,
    const float* __restrict__ d2w, const float* __restrict__ d3w,
    const float* __restrict__ c1w,
    const float* __restrict__ siw, const float* __restrict__ Dw,
    const float* __restrict__ prw, const float* __restrict__ pw,
    ushort* __restrict__ pc2, ushort* __restrict__ pc3, ushort* __restrict__ pc4,
    ushort* __restrict__ pd1, ushort* __restrict__ pd2, ushort* __restrict__ pd3,
    ushort* __restrict__ pc1,
    float* __restrict__ siwT, float* __restrict__ DwT,
    float* __restrict__ prwT, float* __restrict__ powT) {
  int id = blockIdx.x * 256 + threadIdx.x;
  if (id < 32768)            pack_conv_elem(c2w, pc2, 64, 32, id);
  else if (id < 163840)      pack_conv_elem(c3w, pc3, 128, 64, id - 32768);
  else if (id < 688128)      pack_conv_elem(c4w, pc4, 256, 128, id - 163840);
  else if (id < 819200)      pack_deconv_elem(d1w, pd1, 64, 128, id - 688128);
  else if (id < 851968)      pack_deconv_elem(d2w, pd2, 32, 64, id - 819200);
  else if (id < 860160)      pack_deconv_elem(d3w, pd3, 16, 32, id - 851968);
  else if (id < 862208)      pack_conv1_elem(c1w, pc1, id - 860160);
  else if (id < 996352) {    // siwT [262][512]
    int r = id - 862208; int k = r >> 9, h = r & 511;
    siwT[r] = siw[(size_t)h * (LATENT + ACTD) + k];
  } else if (id < 1258496) { // DwT [512][512]
    int r = id - 996352; int k = r >> 9, h = r & 511;
    DwT[r] = Dw[(size_t)h * HIDD + k];
  } else if (id < 1520640) { // prwT [512][512]
    int r = id - 1258496; int k = r >> 9, h = r & 511;
    prwT[r] = prw[(size_t)h * HIDD + k];
  } else if (id < 2044928) { // powT [1024][512]
    int r = id - 1520640; int k = r >> 9, j = r & 511;
    powT[r] = pw[(size_t)j * 1024 + k];
  }
}

// ================= img -> [px][64b][4ci] bf16 (ci padded) =================
__global__ __launch_bounds__(256) void k_timg4(const float* __restrict__ img,
                                               ushort* __restrict__ timg4) {
  __shared__ float ts[3][64][65];
  int p0 = blockIdx.x << 6;
  int tid = threadIdx.x;
  #pragma unroll
  for (int c = 0; c < 3; ++c) {
    #pragma unroll
    for (int i = 0; i < 16; ++i) {
      int idx = tid + i * 256;
      int b = idx >> 6, pr = idx & 63;
      ts[c][pr][b] = img[((size_t)b * 3 + c) * 65536 + p0 + pr];
    }
  }
  __syncthreads();
  #pragma unroll
  for (int i = 0; i < 16; ++i) {
    int idx = tid + i * 256;
    int pr = idx >> 6, b = idx & 63;
    uint2 pk;
    pk.x = (unsigned)f2bf(ts[0][pr][b]) | ((unsigned)f2bf(ts[1][pr][b]) << 16);
    pk.y = (unsigned)f2bf(ts[2][pr][b]);
    *(uint2*)(timg4 + ((size_t)(p0 + pr) * 64 + b) * 4) = pk;
  }
}

// ================= conv1 MFMA: Cin=4(padded), one wave per output pixel =================
__global__ __launch_bounds__(256) void k_conv1_mfma(const ushort* __restrict__ in,
                                                    const ushort* __restrict__ wp,
                                                    const float* __restrict__ bias,
                                                    ushort* __restrict__ out) {
  int wid = __builtin_amdgcn_readfirstlane(blockIdx.x * 4 + (threadIdx.x >> 6));
  int lane = threadIdx.x & 63;
  int ox = wid & 127, oy = wid >> 7;
  int ml = lane & 15, khi = lane >> 4;
  f32x4 zero = {0.f, 0.f, 0.f, 0.f};
  f32x4 acc[2][4];
  #pragma unroll
  for (int mt = 0; mt < 2; ++mt)
    #pragma unroll
    for (int nt = 0; nt < 4; ++nt) acc[mt][nt] = zero;
  int by = 2 * oy - 1, bx = 2 * ox - 1;
  bool interior = (oy >= 1) & (oy <= 126) & (ox >= 1) & (ox <= 126);

  #pragma unroll
  for (int kc = 0; kc < 2; ++kc) {
    bf16x8 a0 = *(const bf16x8*)(wp + kc * 512 + lane * 8);
    bf16x8 a1 = *(const bf16x8*)(wp + 1024 + kc * 512 + lane * 8);
    int t0 = kc * 8 + khi * 2;
    int ky0 = t0 >> 2, kx0 = t0 & 3;
    int ky1 = (t0 + 1) >> 2, kx1 = (t0 + 1) & 3;
    int iy0 = by + ky0, ix0 = bx + kx0;
    int iy1 = by + ky1, ix1 = bx + kx1;
    const ushort* pA = in + ((size_t)(iy0 * 256 + ix0) * 64 + ml) * 4;
    const ushort* pB = in + ((size_t)(iy1 * 256 + ix1) * 64 + ml) * 4;
    if (interior) {
      #pragma unroll
      for (int nt = 0; nt < 4; ++nt) {
        uint2 lo = *(const uint2*)(pA + nt * 64);
        uint2 hi = *(const uint2*)(pB + nt * 64);
        uint4 u; u.x = lo.x; u.y = lo.y; u.z = hi.x; u.w = hi.y;
        bf16x8 bb = __builtin_bit_cast(bf16x8, u);
        acc[0][nt] = __builtin_amdgcn_mfma_f32_16x16x32_bf16(a0, bb, acc[0][nt], 0, 0, 0);
        acc[1][nt] = __builtin_amdgcn_mfma_f32_16x16x32_bf16(a1, bb, acc[1][nt], 0, 0, 0);
      }
    } else {
      bool ok0 = ((unsigned)iy0 < 256u) & ((unsigned)ix0 < 256u);
      bool ok1 = ((unsigned)iy1 < 256u) & ((unsigned)ix1 < 256u);
      #pragma unroll
      for (int nt = 0; nt < 4; ++nt) {
        uint2 z2; z2.x = 0u; z2.y = 0u;
        uint2 lo = ok0 ? *(const uint2*)(pA + nt * 64) : z2;
        uint2 hi = ok1 ? *(const uint2*)(pB + nt * 64) : z2;
        uint4 u; u.x = lo.x; u.y = lo.y; u.z = hi.x; u.w = hi.y;
        bf16x8 bb = __builtin_bit_cast(bf16x8, u);
        acc[0][nt] = __builtin_amdgcn_mfma_f32_16x16x32_bf16(a0, bb, acc[0][nt], 0, 0, 0);
        acc[1][nt] = __builtin_amdgcn_mfma_f32_16x16x32_bf16(a1, bb, acc[1][nt], 0, 0, 0);
      }
    }
  }
  int px = oy * 128 + ox;
  int rb = khi * 4;
  #pragma unroll
  for (int mt = 0; mt < 2; ++mt) {
    int co = mt * 16 + rb;
    f32x4 bv = *(const f32x4*)(bias + co);
    #pragma unroll
    for (int nt = 0; nt < 4; ++nt) {
      float v0 = fmaxf(acc[mt][nt][0] + bv[0], 0.f);
      float v1 = fmaxf(acc[mt][nt][1] + bv[1], 0.f);
      float v2 = fmaxf(acc[mt][nt][2] + bv[2], 0.f);
      float v3 = fmaxf(acc[mt][nt][3] + bv[3], 0.f);
      uint2 pk;
      pk.x = (unsigned)f2bf(v0) | ((unsigned)f2bf(v1) << 16);
      pk.y = (unsigned)f2bf(v2) | ((unsigned)f2bf(v3) << 16);
      size_t off = (size_t)px * 2048 + nt * 512 + ((co >> 3) & 3) * 128 + ml * 8 + (co & 7);
      *(uint2*)(out + off) = pk;
    }
  }
}

// ================= MFMA conv, interior fast path =================
template<int CIN, int COUT, int MT>
__global__ __launch_bounds__(256) void mfma_conv(const ushort* __restrict__ in,
                                                 const ushort* __restrict__ wp,
                                                 const float* __restrict__ bias,
                                                 ushort* __restrict__ out,
                                                 int Hin, int Win, int Hout, int Wout) {
  constexpr int NMG = COUT / (16 * MT);
  constexpr int NKC = CIN / 32;
  constexpr int NCH = 16 * NKC;
  int wid = __builtin_amdgcn_readfirstlane(blockIdx.x * 4 + (threadIdx.x >> 6));
  int lane = threadIdx.x & 63;
  int mg = wid % NMG;
  int px = wid / NMG;
  int ox = px % Wout, oy = px / Wout;
  if (oy >= Hout) return;
  int mtile0 = mg * MT;
  f32x4 zero = {0.f, 0.f, 0.f, 0.f};
  f32x4 acc[MT][4];
  #pragma unroll
  for (int mt = 0; mt < MT; ++mt)
    #pragma unroll
    for (int nt = 0; nt < 4; ++nt) acc[mt][nt] = zero;
  const ushort* wbase = wp + (size_t)mtile0 * NCH * 512 + lane * 8;
  const size_t mstride = (size_t)NCH * 512;
  bool interior = (oy >= 1) & (oy < Hout - 1) & (ox >= 1) & (ox < Wout - 1);

  if (interior) {
    #pragma unroll
    for (int ky = 0; ky < 4; ++ky) {
      int iy = 2 * oy - 1 + ky;
      #pragma unroll
      for (int kx = 0; kx < 4; ++kx) {
        int ix = 2 * ox - 1 + kx;
        const ushort* ib = in + (size_t)(iy * Win + ix) * (CIN * 64) + lane * 8;
        int tap = ky * 4 + kx;
        #pragma unroll
        for (int kc = 0; kc < NKC; ++kc) {
          int kcg = tap * NKC + kc;
          bf16x8 a[MT], bb[4];
          #pragma unroll
          for (int mt = 0; mt < MT; ++mt)
            a[mt] = *(const bf16x8*)(wbase + mt * mstride + (size_t)kcg * 512);
          #pragma unroll
          for (int nt = 0; nt < 4; ++nt)
            bb[nt] = *(const bf16x8*)(ib + kc * 2048 + nt * 512);
          #pragma unroll
          for (int mt = 0; mt < MT; ++mt)
            #pragma unroll
            for (int nt = 0; nt < 4; ++nt)
              acc[mt][nt] = __builtin_amdgcn_mfma_f32_16x16x32_bf16(a[mt], bb[nt], acc[mt][nt], 0, 0, 0);
        }
      }
    }
  } else {
    for (int ky = 0; ky < 4; ++ky) {
      int iy = 2 * oy - 1 + ky;
      if ((unsigned)iy >= (unsigned)Hin) continue;
      for (int kx = 0; kx < 4; ++kx) {
        int ix = 2 * ox - 1 + kx;
        if ((unsigned)ix >= (unsigned)Win) continue;
        const ushort* ib = in + (size_t)(iy * Win + ix) * (CIN * 64) + lane * 8;
        int tap = ky * 4 + kx;
        #pragma unroll
        for (int kc = 0; kc < NKC; ++kc) {
          int kcg = tap * NKC + kc;
          bf16x8 a[MT], bb[4];
          #pragma unroll
          for (int mt = 0; mt < MT; ++mt)
            a[mt] = *(const bf16x8*)(wbase + mt * mstride + (size_t)kcg * 512);
          #pragma unroll
          for (int nt = 0; nt < 4; ++nt)
            bb[nt] = *(const bf16x8*)(ib + kc * 2048 + nt * 512);
          #pragma unroll
          for (int mt = 0; mt < MT; ++mt)
            #pragma unroll
            for (int nt = 0; nt < 4; ++nt)
              acc[mt][nt] = __builtin_amdgcn_mfma_f32_16x16x32_bf16(a[mt], bb[nt], acc[mt][nt], 0, 0, 0);
        }
      }
    }
  }
  int ml = lane & 15, rb = (lane >> 4) * 4;
  #pragma unroll
  for (int mt = 0; mt < MT; ++mt) {
    int co = mtile0 * 16 + mt * 16 + rb;
    f32x4 bv = *(const f32x4*)(bias + co);
    #pragma unroll
    for (int nt = 0; nt < 4; ++nt) {
      float v0 = fmaxf(acc[mt][nt][0] + bv[0], 0.f);
      float v1 = fmaxf(acc[mt][nt][1] + bv[1], 0.f);
      float v2 = fmaxf(acc[mt][nt][2] + bv[2], 0.f);
      float v3 = fmaxf(acc[mt][nt][3] + bv[3], 0.f);
      uint2 pk;
      pk.x = (unsigned)f2bf(v0) | ((unsigned)f2bf(v1) << 16);
      pk.y = (unsigned)f2bf(v2) | ((unsigned)f2bf(v3) << 16);
      size_t off = (size_t)px * (COUT * 64) + (size_t)(co >> 5) * 2048 + nt * 512
                 + ((co >> 3) & 3) * 128 + ml * 8 + (co & 7);
      *(uint2*)(out + off) = pk;
    }
  }
}

// ================= MFMA transposed conv, interior fast path =================
template<int CIN, int COUT, int MT, bool RELU>
__global__ __launch_bounds__(256) void mfma_deconv(const ushort* __restrict__ in,
                                                   const ushort* __restrict__ wp,
                                                   const float* __restrict__ bias,
                                                   ushort* __restrict__ out,
                                                   int Hin, int Win, int Hout, int Wout) {
  constexpr int NMG = COUT / (16 * MT);
  constexpr int NKC = CIN / 32;
  constexpr int NCH = 4 * NKC;
  constexpr int NTS = (COUT >= 32) ? 512 : (COUT * 16);
  int wid = __builtin_amdgcn_readfirstlane(blockIdx.x * 4 + (threadIdx.x >> 6));
  int lane = threadIdx.x & 63;
  int mg = wid % NMG; int r1 = wid / NMG;
  int wo2 = Wout >> 1;
  int pc = (Hout >> 1) * wo2;
  int pxc = r1 % pc; int cls = r1 / pc;
  if (cls >= 4) return;
  int p0 = cls >> 1, q0 = cls & 1;
  int tx = pxc % wo2, ty = pxc / wo2;
  int oy = 2 * ty + 1 - p0, ox = 2 * tx + 1 - q0;
  int iy0 = (oy + 1 - p0) >> 1, ix0 = (ox + 1 - q0) >> 1;
  int mtile0 = mg * MT;
  f32x4 zero = {0.f, 0.f, 0.f, 0.f};
  f32x4 acc[MT][4];
  #pragma unroll
  for (int mt = 0; mt < MT; ++mt)
    #pragma unroll
    for (int nt = 0; nt < 4; ++nt) acc[mt][nt] = zero;
  const ushort* wbase = wp + ((size_t)cls * (COUT / 16) + mtile0) * NCH * 512 + lane * 8;
  const size_t mstride = (size_t)NCH * 512;
  bool interior = (iy0 >= 1) & (iy0 <= Hin - 1) & (ix0 >= 1) & (ix0 <= Win - 1);

  if (interior) {
    #pragma unroll
    for (int i = 0; i < 2; ++i) {
      int iy = iy0 - i;
      #pragma unroll
      for (int j = 0; j < 2; ++j) {
        int ix = ix0 - j;
        const ushort* ib = in + (size_t)(iy * Win + ix) * (CIN * 64) + lane * 8;
        int tap = i * 2 + j;
        #pragma unroll
        for (int kc = 0; kc < NKC; ++kc) {
          int kcg = tap * NKC + kc;
          bf16x8 a[MT], bb[4];
          #pragma unroll
          for (int mt = 0; mt < MT; ++mt)
            a[mt] = *(const bf16x8*)(wbase + mt * mstride + (size_t)kcg * 512);
          #pragma unroll
          for (int nt = 0; nt < 4; ++nt)
            bb[nt] = *(const bf16x8*)(ib + kc * 2048 + nt * 512);
          #pragma unroll
          for (int mt = 0; mt < MT; ++mt)
            #pragma unroll
            for (int nt = 0; nt < 4; ++nt)
              acc[mt][nt] = __builtin_amdgcn_mfma_f32_16x16x32_bf16(a[mt], bb[nt], acc[mt][nt], 0, 0, 0);
        }
      }
    }
  } else {
    for (int i = 0; i < 2; ++i) {
      int iy = iy0 - i;
      if ((unsigned)iy >= (unsigned)Hin) continue;
      for (int j = 0; j < 2; ++j) {
        int ix = ix0 - j;
        if ((unsigned)ix >= (unsigned)Win) continue;
        const ushort* ib = in + (size_t)(iy * Win + ix) * (CIN * 64) + lane * 8;
        int tap = i * 2 + j;
        #pragma unroll
        for (int kc = 0; kc < NKC; ++kc) {
          int kcg = tap * NKC + kc;
          bf16x8 a[MT], bb[4];
          #pragma unroll
          for (int mt = 0; mt < MT; ++mt)
            a[mt] = *(const bf16x8*)(wbase + mt * mstride + (size_t)kcg * 512);
          #pragma unroll
          for (int nt = 0; nt < 4; ++nt)
            bb[nt] = *(const bf16x8*)(ib + kc * 2048 + nt * 512);
          #pragma unroll
          for (int mt = 0; mt < MT; ++mt)
            #pragma unroll
            for (int nt = 0; nt < 4; ++nt)
              acc[mt][nt] = __builtin_amdgcn_mfma_f32_16x16x32_bf16(a[mt], bb[nt], acc[mt][nt], 0, 0, 0);
        }
      }
    }
  }
  int ml = lane & 15, rb = (lane >> 4) * 4;
  int px = oy * Wout + ox;
  #pragma unroll
  for (int mt = 0; mt < MT; ++mt) {
    int co = mtile0 * 16 + mt * 16 + rb;
    f32x4 bv = *(const f32x4*)(bias + co);
    #pragma unroll
    for (int nt = 0; nt < 4; ++nt) {
      float v0 = acc[mt][nt][0] + bv[0];
      float v1 = acc[mt][nt][1] + bv[1];
      float v2 = acc[mt][nt][2] + bv[2];
      float v3 = acc[mt][nt][3] + bv[3];
      if (RELU) { v0=fmaxf(v0,0.f); v1=fmaxf(v1,0.f); v2=fmaxf(v2,0.f); v3=fmaxf(v3,0.f); }
      uint2 pk;
      pk.x = (unsigned)f2bf(v0) | ((unsigned)f2bf(v1) << 16);
      pk.y = (unsigned)f2bf(v2) | ((unsigned)f2bf(v3) << 16);
      size_t off = (size_t)px * (COUT * 64) + (size_t)(co >> 5) * 2048 + (size_t)nt * NTS
                 + ((co >> 3) & 3) * 128 + ml * 8 + (co & 7);
      *(uint2*)(out + off) = pk;
    }
  }
}

// ================= enc_fc fused: LDS-transpose staging + MFMA =================
#define APXS 1032
__global__ __launch_bounds__(256) void k_encfc_fused(const ushort* __restrict__ h4,
                                                     const float* __restrict__ wE,
                                                     float* __restrict__ partial) {
  __shared__ float smem[8320];
  ushort* au = (ushort*)smem;
  int s = blockIdx.x;
  int bid = (s & 7) * 256 + (s >> 3);
  int mg = bid & 15;
  int ccf = (bid >> 4) & 7;
  int pxg = bid >> 7;
  int tid = threadIdx.x;
  int co0 = mg * 32;
  #pragma unroll 4
  for (int i = 0; i < 64; ++i) {
    int idx = tid + i * 256;
    int px_l = idx & 15;
    int ci_l = (idx >> 4) & 31;
    int co_l = idx >> 9;
    float v = wE[((size_t)(co0 + co_l) << 16) + (size_t)(ccf * 32 + ci_l) * 256 + pxg * 16 + px_l];
    int mt = co_l >> 4, m = co_l & 15;
    int kg = ci_l >> 3, k8 = ci_l & 7;
    au[px_l * APXS + mt * 512 + kg * 128 + m * 8 + k8] = f2bf(v);
  }
  __syncthreads();
  int lane = tid & 63, wv = tid >> 6;
  int ml = lane & 15, rb = (lane >> 4) * 4;
  f32x4 zero = {0.f, 0.f, 0.f, 0.f};
  f32x4 acc[2][4];
  #pragma unroll
  for (int mt = 0; mt < 2; ++mt)
    #pragma unroll
    for (int nt = 0; nt < 4; ++nt) acc[mt][nt] = zero;
  #pragma unroll
  for (int jj = 0; jj < 4; ++jj) {
    int j = wv * 4 + jj;
    int px = pxg * 16 + j;
    bf16x8 a0 = *(const bf16x8*)(au + j * APXS + lane * 8);
    bf16x8 a1 = *(const bf16x8*)(au + j * APXS + 512 + lane * 8);
    const ushort* hb = h4 + (size_t)px * 16384 + ccf * 2048 + lane * 8;
    bf16x8 bb[4];
    #pragma unroll
    for (int nt = 0; nt < 4; ++nt)
      bb[nt] = *(const bf16x8*)(hb + nt * 512);
    #pragma unroll
    for (int nt = 0; nt < 4; ++nt) {
      acc[0][nt] = __builtin_amdgcn_mfma_f32_16x16x32_bf16(a0, bb[nt], acc[0][nt], 0, 0, 0);
      acc[1][nt] = __builtin_amdgcn_mfma_f32_16x16x32_bf16(a1, bb[nt], acc[1][nt], 0, 0, 0);
    }
  }
  __syncthreads();
  #pragma unroll
  for (int mt = 0; mt < 2; ++mt)
    #pragma unroll
    for (int nt = 0; nt < 4; ++nt)
      #pragma unroll
      for (int r = 0; r < 4; ++r)
        smem[wv * 2080 + (mt * 16 + rb + r) * 65 + nt * 16 + ml] = acc[mt][nt][r];
  __syncthreads();
  int ks = pxg * 8 + ccf;
  #pragma unroll
  for (int i = 0; i < 8; ++i) {
    int e = tid + i * 256;
    int b = e & 63, co_l = e >> 6;
    float sum = smem[co_l * 65 + b] + smem[2080 + co_l * 65 + b]
              + smem[4160 + co_l * 65 + b] + smem[6240 + co_l * 65 + b];
    partial[((size_t)(co0 + co_l) * ENC_KS + ks) * 64 + b] = sum;
  }
}

__global__ void k_encfc_red(const float* __restrict__ partial, const float* __restrict__ bias,
                            float* __restrict__ cnn) {
  int id = blockIdx.x * blockDim.x + threadIdx.x;
  int o = id >> 6, b = id & 63;
  float acc = bias[o];
  #pragma unroll 8
  for (int s = 0; s < ENC_KS; ++s) acc += partial[((size_t)o * ENC_KS + s) * 64 + b];
  cnn[(size_t)b * 512 + o] = fmaxf(acc, 0.f);
}

// ================= fused posterior + reparam (coalesced powT) =================
__global__ __launch_bounds__(512) void k_postz(const float* __restrict__ cnn,
                                               const float* __restrict__ belief,
                                               const float* __restrict__ powT,
                                               const float* __restrict__ bias,
                                               const float* __restrict__ eps,
                                               float* __restrict__ out,
                                               ushort* __restrict__ zb) {
  __shared__ float cs[512];
  __shared__ float bs[512];
  __shared__ float sm[512];
  int b = blockIdx.x;
  int j = threadIdx.x;
  cs[j] = cnn[(size_t)b * HIDD + j];
  bs[j] = belief[(size_t)b * HIDD + j];
  __syncthreads();
  float acc = bias[j];
  #pragma unroll 8
  for (int k = 0; k < HIDD; ++k) acc += cs[k] * powT[(size_t)k * 512 + j];
  #pragma unroll 8
  for (int k = 0; k < HIDD; ++k) acc += bs[k] * powT[(size_t)(512 + k) * 512 + j];
  sm[j] = acc;
  if (j < 256) out[O_MUPO + b * 256 + j] = acc;
  else         out[O_LVPO + b * 256 + (j - 256)] = acc;
  __syncthreads();
  if (j < 256) {
    float z = sm[j] + eps[b * 256 + j] * expf(0.5f * sm[j + 256]);
    out[O_ZT + b * 256 + j] = z;
    if (j < 128) zb[b * 128 + j] = f2bf(z);
  }
}

// ================= dec_fc MFMA: direct f32 weights, frag-order out =================
__global__ __launch_bounds__(256) void k_decfc_mfma(const ushort* __restrict__ zb,
                                                    const float* __restrict__ dfw,
                                                    const float* __restrict__ dfb,
                                                    ushort* __restrict__ dec) {
  int wid = __builtin_amdgcn_readfirstlane(blockIdx.x * 4 + (threadIdx.x >> 6));
  int lane = threadIdx.x & 63;
  int m0 = wid * 32;
  int ml = lane & 15, kl = (lane >> 4) * 8;
  f32x4 zero = {0.f, 0.f, 0.f, 0.f};
  f32x4 acc[2][4];
  #pragma unroll
  for (int mt = 0; mt < 2; ++mt)
    #pragma unroll
    for (int nt = 0; nt < 4; ++nt) acc[mt][nt] = zero;
  #pragma unroll
  for (int kc = 0; kc < 4; ++kc) {
    bf16x8 a[2], bb[4];
    #pragma unroll
    for (int mt = 0; mt < 2; ++mt) {
      int m_r = m0 + mt * 16 + ml;
      const float* wr = dfw + (size_t)((m_r & 127) * 256 + (m_r >> 7)) * 128 + kc * 32 + kl;
      float4 u0 = *(const float4*)wr;
      float4 u1 = *(const float4*)(wr + 4);
      bf16x8 av;
      av[0] = (short)f2bf(u0.x); av[1] = (short)f2bf(u0.y);
      av[2] = (short)f2bf(u0.z); av[3] = (short)f2bf(u0.w);
      av[4] = (short)f2bf(u1.x); av[5] = (short)f2bf(u1.y);
      av[6] = (short)f2bf(u1.z); av[7] = (short)f2bf(u1.w);
      a[mt] = av;
    }
    #pragma unroll
    for (int nt = 0; nt < 4; ++nt)
      bb[nt] = *(const bf16x8*)(zb + (size_t)(nt * 16 + ml) * 128 + kc * 32 + kl);
    #pragma unroll
    for (int mt = 0; mt < 2; ++mt)
      #pragma unroll
      for (int nt = 0; nt < 4; ++nt)
        acc[mt][nt] = __builtin_amdgcn_mfma_f32_16x16x32_bf16(a[mt], bb[nt], acc[mt][nt], 0, 0, 0);
  }
  int rb = (lane >> 4) * 4;
  #pragma unroll
  for (int mt = 0; mt < 2; ++mt) {
    int m = m0 + mt * 16 + rb;
    int pix = m >> 7, co = m & 127;
    float bv0 = dfb[(size_t)(co + 0) * 256 + pix];
    float bv1 = dfb[(size_t)(co + 1) * 256 + pix];
    float bv2 = dfb[(size_t)(co + 2) * 256 + pix];
    float bv3 = dfb[(size_t)(co + 3) * 256 + pix];
    #pragma unroll
    for (int nt = 0; nt < 4; ++nt) {
      uint2 pk;
      pk.x = (unsigned)f2bf(acc[mt][nt][0] + bv0) | ((unsigned)f2bf(acc[mt][nt][1] + bv1) << 16);
      pk.y = (unsigned)f2bf(acc[mt][nt][2] + bv2) | ((unsigned)f2bf(acc[mt][nt][3] + bv3) << 16);
      size_t off = (size_t)pix * 8192 + (size_t)(co >> 5) * 2048 + nt * 512
                 + ((co >> 3) & 3) * 128 + ml * 8 + (co & 7);
      *(uint2*)(dec + off) = pk;
    }
  }
}

// ================= d4 fused with output transpose =================
__global__ __launch_bounds__(256) void k_d4t(const ushort* __restrict__ in,
                                             const float* __restrict__ w,
                                             const float* __restrict__ bias,
                                             float* __restrict__ out) {
  __shared__ float lds[64][65];
  int blk = blockIdx.x;
  int oy = blk >> 2, ox0 = (blk & 3) << 6;
  int t = threadIdx.x;
  int b = t & 63, sub = t >> 6;
  float bv = bias[0];
  for (int j = 0; j < 16; ++j) {
    int oxl = j * 4 + sub;
    int ox = ox0 + oxl;
    int p0 = (oy + 1) & 1, q0 = (ox + 1) & 1;
    int iy0 = (oy + 1 - p0) >> 1, ix0 = (ox + 1 - q0) >> 1;
    float acc = bv;
    #pragma unroll
    for (int i = 0; i < 2; ++i) {
      int iy = iy0 - i;
      if ((unsigned)iy >= 128u) continue;
      int p = p0 + 2 * i;
      #pragma unroll
      for (int jj = 0; jj < 2; ++jj) {
        int ix = ix0 - jj;
        if ((unsigned)ix >= 128u) continue;
        int q = q0 + 2 * jj;
        const ushort* base = in + (size_t)(iy * 128 + ix) * 1024 + (b >> 4) * 256 + (b & 15) * 8;
        bf16x8 v0 = *(const bf16x8*)(base);
        bf16x8 v1 = *(const bf16x8*)(base + 128);
        const float* wq = w + p * 4 + q;
        #pragma unroll
        for (int ci = 0; ci < 8; ++ci) acc += bf2f((ushort)v0[ci]) * wq[ci * 16];
        #pragma unroll
        for (int ci = 0; ci < 8; ++ci) acc += bf2f((ushort)v1[ci]) * wq[(ci + 8) * 16];
      }
    }
    lds[oxl][b] = acc;
  }
  __syncthreads();
  #pragma unroll
  for (int j = 0; j < 16; ++j) {
    int idx = t + j * 256;
    int b2 = idx >> 6, oxl = idx & 63;
    out[(size_t)b2 * 65536 + oy * 256 + ox0 + oxl] = lds[oxl][b2];
  }
}

// ================= launch =================

extern "C" void kernel_launch(void* const* d_in, const int* in_sizes, int n_in,
                              void* d_out, int out_size, void* d_ws, size_t ws_size,
                              hipStream_t stream) {
  const float* img      = (const float*)d_in[0];
  const float* act      = (const float*)d_in[1];
  const float* z_prev   = (const float*)d_in[2];
  const float* st_prev  = (const float*)d_in[3];
  const float* eps      = (const float*)d_in[4];
  const float* c1w = (const float*)d_in[5];  const float* c1b = (const float*)d_in[6];
  const float* c2w = (const float*)d_in[7];  const float* c2b = (const float*)d_in[8];
  const float* c3w = (const float*)d_in[9];  const float* c3b = (const float*)d_in[10];
  const float* c4w = (const float*)d_in[11]; const float* c4b = (const float*)d_in[12];
  const float* efw = (const float*)d_in[13]; const float* efb = (const float*)d_in[14];
  const float* pow_ = (const float*)d_in[15]; const float* pob = (const float*)d_in[16];
  const float* prw = (const float*)d_in[17]; const float* prb = (const float*)d_in[18];
  const float* siw = (const float*)d_in[19]; const float* sib = (const float*)d_in[20];
  const float* Alog = (const float*)d_in[21];
  const float* Bw = (const float*)d_in[22];  const float* Cw = (const float*)d_in[23];
  const float* Dw = (const float*)d_in[24];  const float* Db = (const float*)d_in[25];
  const float* Dv = (const float*)d_in[26];
  const float* dfw = (const float*)d_in[27]; const float* dfb = (const float*)d_in[28];
  const float* d1w = (const float*)d_in[29]; const float* d1b = (const float*)d_in[30];
  const float* d2w = (const float*)d_in[31]; const float* d2b = (const float*)d_in[32];
  const float* d3w = (const float*)d_in[33]; const float* d3b = (const float*)d_in[34];
  const float* d4w = (const float*)d_in[35]; const float* d4b = (const float*)d_in[36];

  float* ws = (float*)d_ws;
  float* out = (float*)d_out;

  ushort* pc2 = (ushort*)(ws + PW_C2);
  ushort* pc3 = (ushort*)(ws + PW_C3);
  ushort* pc4 = (ushort*)(ws + PW_C4);
  ushort* pd1 = (ushort*)(ws + PW_D1);
  ushort* pd2 = (ushort*)(ws + PW_D2);
  ushort* pd3 = (ushort*)(ws + PW_D3);
  ushort* pc1 = (ushort*)(ws + PW_C1);
  ushort* timg4 = (ushort*)(ws + W_TIMG);
  ushort* h1b = (ushort*)(ws + W_H1B);
  ushort* h2b = (ushort*)(ws + W_H2B);
  ushort* h3b = (ushort*)(ws + W_H3B);
  ushort* h4b = (ushort*)(ws + W_H4B);
  ushort* deco = (ushort*)(ws + W_DECO);
  ushort* d1o = (ushort*)(ws + W_D1O);
  ushort* d2o = (ushort*)(ws + W_D2O);
  ushort* d3o = (ushort*)(ws + W_D3O);
  ushort* zb = (ushort*)(ws + W_ZB16);
  float* siwT = ws + W_SIWT;
  float* DwT  = ws + W_DWT;
  float* prwT = ws + W_PRWT;
  float* powT = ws + W_POWT;

  // ---- merged weight prepack (+ conv1 pack + dense transposes) ----
  k_pack_all<<<7988, 256, 0, stream>>>(c2w, c3w, c4w, d1w, d2w, d3w, c1w,
                                       siw, Dw, prw, pow_,
                                       pc2, pc3, pc4, pd1, pd2, pd3, pc1,
                                       siwT, DwT, prwT, powT);

  // ---- fused SSM chain (coalesced) ----
  k_ssm_all<<<64, 512, 0, stream>>>(z_prev, act, siwT, sib, DwT, Db, Bw, Cw,
                                    Alog, Dv, st_prev, out + O_STATE,
                                    ws + W_BELIEF, prwT, prb, out);

  // ---- encoder ----
  k_timg4<<<1024, 256, 0, stream>>>(img, timg4);
  k_conv1_mfma<<<4096, 256, 0, stream>>>(timg4, pc1, c1b, h1b);
  mfma_conv<32, 64, 4><<<1024, 256, 0, stream>>>(h1b, pc2, c2b, h2b, 128, 128, 64, 64);
  mfma_conv<64, 128, 4><<<512, 256, 0, stream>>>(h2b, pc3, c3b, h3b, 64, 64, 32, 32);
  mfma_conv<128, 256, 2><<<512, 256, 0, stream>>>(h3b, pc4, c4b, h4b, 32, 32, 16, 16);

  // ---- enc_fc (fused transpose+GEMM) ----
  k_encfc_fused<<<2048, 256, 0, stream>>>(h4b, efw, ws + W_ENCP);
  k_encfc_red<<<128, 256, 0, stream>>>(ws + W_ENCP, efb, ws + W_CNN);

  // ---- fused posterior + reparam ----
  k_postz<<<64, 512, 0, stream>>>(ws + W_CNN, ws + W_BELIEF, powT, pob, eps, out, zb);

  // ---- decoder ----
  k_decfc_mfma<<<256, 256, 0, stream>>>(zb, dfw, dfb, deco);
  mfma_deconv<128, 64, 2, true><<<512, 256, 0, stream>>>(deco, pd1, d1b, d1o, 16, 16, 32, 32);
  mfma_deconv<64, 32, 2, true><<<1024, 256, 0, stream>>>(d1o, pd2, d2b, d2o, 32, 32, 64, 64);
  mfma_deconv<32, 16, 1, true><<<2048, 256, 0, stream>>>(d2o, pd3, d3b, d3o, 64, 64, 128, 128);
  k_d4t<<<1024, 256, 0, stream>>>(d3o, d4w, d4b, out + O_PRED);
}